// Round 9
// baseline (2404.827 us; speedup 1.0000x reference)
//
#include <hip/hip_runtime.h>
#include <cstddef>
#include <cstdint>
#include <math.h>

#define EPSF 1e-8f

// Model dims (fixed): T=64, B=128, D=300, H=300, L=20, AH=300, N2=2B=256

typedef _Float16 half8v __attribute__((ext_vector_type(8)));
typedef float f32x4v __attribute__((ext_vector_type(4)));
union U4H8 { uint4 u; half8v h; _Float16 e[8]; };

// fast device math: v_exp_f32 + v_rcp_f32 (rel err ~1e-7, fine for 3e-3 budget)
__device__ __forceinline__ float fsig(float x) {
  float e = __expf(-x);
  return __builtin_amdgcn_rcpf(1.f + e);
}
__device__ __forceinline__ float ftanh(float x) {
  float e = __expf(-2.f * fabsf(x));
  float r = (1.f - e) * __builtin_amdgcn_rcpf(1.f + e);
  return copysignf(r, x);
}

// asm-opaque 16B load: result cannot be re-materialized by the compiler ->
// forces true register residency. SAFE ONLY at low register pressure: the
// compiler can't model the asm's vmcnt, so a spill of the result placed
// before our explicit vmcnt(0) stores garbage (round-7 failure with 3
// tiles/wave = 120 pinned VGPR). Keep to 2 tiles/wave (80 VGPR).
__device__ __forceinline__ uint4 gld16(const uint4* p) {
  uint4 r;
  asm volatile("global_load_dwordx4 %0, %1, off" : "=v"(r) : "v"(p));
  return r;
}

// ---------------------------------------------------------------------------
// Split-f16 MFMA NT GEMM (round-6 WIN): C = bias + A*B^T, fp32-grade via
// A=Ah+Al, B=Bh+Bl, C ~= AhBh+AlBh+AhBl (dropped AlBl ~2^-22).
// Tile 128x240, N=1200=5x240; 512 thr; LDS pitch-72 hi/lo staging.
// ---------------------------------------------------------------------------
#define GMM_LDS_BYTES (2 * (128 * 72 * 2) + 2 * (240 * 72 * 2))  // 105,984

__global__ __launch_bounds__(512, 1) void gemm_mfma_nt(
    const float* __restrict__ A, const float* __restrict__ B,
    const float* __restrict__ bias, float* __restrict__ C,
    int M, int K)
{
  extern __shared__ char smem[];
  _Float16* Ah = (_Float16*)smem;                       // [128][72]
  _Float16* Al = (_Float16*)(smem + 18432);             // [128][72]
  _Float16* Bh = (_Float16*)(smem + 36864);             // [240][72]
  _Float16* Bl = (_Float16*)(smem + 36864 + 34560);     // [240][72]

  const int tid = threadIdx.x;
  const int wv = tid >> 6, lane = tid & 63;
  const int lm = lane & 15, lg = lane >> 4;
  const int mbase = blockIdx.y << 7;
  const int nbase = blockIdx.x * 240;

  f32x4v acc[15];
#pragma unroll
  for (int nt = 0; nt < 15; nt++) acc[nt] = (f32x4v){0.f, 0.f, 0.f, 0.f};

  const int nchunk = (K + 63) >> 6;
  for (int c = 0; c < nchunk; c++) {
    const int kc = c << 6;
    // stage A 128x64 -> hi/lo f16
    for (int e = tid; e < 2048; e += 512) {
      int row = e >> 4, q = e & 15;
      int k = kc + q * 4;
      const float* src = A + (size_t)(mbase + row) * K;
      float4 v = make_float4(0.f, 0.f, 0.f, 0.f);
      if (k + 4 <= K) {
        v = *(const float4*)(src + k);
      } else {
        if (k + 0 < K) v.x = src[k + 0];
        if (k + 1 < K) v.y = src[k + 1];
        if (k + 2 < K) v.z = src[k + 2];
        if (k + 3 < K) v.w = src[k + 3];
      }
      _Float16 hx = (_Float16)v.x, hy = (_Float16)v.y,
               hz = (_Float16)v.z, hw = (_Float16)v.w;
      _Float16* d = &Ah[row * 72 + q * 4];
      d[0] = hx; d[1] = hy; d[2] = hz; d[3] = hw;
      _Float16* dl = &Al[row * 72 + q * 4];
      dl[0] = (_Float16)(v.x - (float)hx); dl[1] = (_Float16)(v.y - (float)hy);
      dl[2] = (_Float16)(v.z - (float)hz); dl[3] = (_Float16)(v.w - (float)hw);
    }
    // stage B 240x64 -> hi/lo f16
    for (int e = tid; e < 3840; e += 512) {
      int row = e >> 4, q = e & 15;
      int k = kc + q * 4;
      const float* src = B + (size_t)(nbase + row) * K;
      float4 v = make_float4(0.f, 0.f, 0.f, 0.f);
      if (k + 4 <= K) {
        v = *(const float4*)(src + k);
      } else {
        if (k + 0 < K) v.x = src[k + 0];
        if (k + 1 < K) v.y = src[k + 1];
        if (k + 2 < K) v.z = src[k + 2];
        if (k + 3 < K) v.w = src[k + 3];
      }
      _Float16 hx = (_Float16)v.x, hy = (_Float16)v.y,
               hz = (_Float16)v.z, hw = (_Float16)v.w;
      _Float16* d = &Bh[row * 72 + q * 4];
      d[0] = hx; d[1] = hy; d[2] = hz; d[3] = hw;
      _Float16* dl = &Bl[row * 72 + q * 4];
      dl[0] = (_Float16)(v.x - (float)hx); dl[1] = (_Float16)(v.y - (float)hy);
      dl[2] = (_Float16)(v.z - (float)hz); dl[3] = (_Float16)(v.w - (float)hw);
    }
    __syncthreads();

#pragma unroll
    for (int kt = 0; kt < 2; kt++) {
      U4H8 ah, al;
      ah.u = *(const uint4*)&Ah[(wv * 16 + lm) * 72 + kt * 32 + lg * 8];
      al.u = *(const uint4*)&Al[(wv * 16 + lm) * 72 + kt * 32 + lg * 8];
#pragma unroll
      for (int nt = 0; nt < 15; nt++) {
        U4H8 bh, bl;
        bh.u = *(const uint4*)&Bh[(nt * 16 + lm) * 72 + kt * 32 + lg * 8];
        bl.u = *(const uint4*)&Bl[(nt * 16 + lm) * 72 + kt * 32 + lg * 8];
        acc[nt] = __builtin_amdgcn_mfma_f32_16x16x32_f16(ah.h, bh.h, acc[nt], 0, 0, 0);
        acc[nt] = __builtin_amdgcn_mfma_f32_16x16x32_f16(al.h, bh.h, acc[nt], 0, 0, 0);
        acc[nt] = __builtin_amdgcn_mfma_f32_16x16x32_f16(ah.h, bl.h, acc[nt], 0, 0, 0);
      }
    }
    __syncthreads();
  }

  // epilogue: D col = nbase+nt*16+lm, row m = mbase+wv*16+lg*4+r
#pragma unroll
  for (int nt = 0; nt < 15; nt++) {
    int col = nbase + nt * 16 + lm;
    float bv = bias[col];
#pragma unroll
    for (int r = 0; r < 4; r++) {
      int m = mbase + wv * 16 + lg * 4 + r;
      C[(size_t)m * 1200 + col] = acc[nt][r] + bv;
    }
  }
}

// ---------------------------------------------------------------------------
// permW: permute Wih rows to gate-interleaved order (row' = 4u+gate).
// ---------------------------------------------------------------------------
__global__ __launch_bounds__(256) void permW_kernel(
    const float* __restrict__ W, const float* __restrict__ bias,
    float* __restrict__ Wp, float* __restrict__ bp, int K)
{
  int r = blockIdx.x;              // 0..1199 = col' = 4u+gate
  int gate = r & 3, u = r >> 2;
  int src = gate * 300 + u;
  const float* s = W + (size_t)src * K;
  float* d = Wp + (size_t)r * K;
  for (int c = threadIdx.x; c < K; c += 256) d[c] = s[c];
  if (threadIdx.x == 0) bp[r] = bias[src];
}

// ---------------------------------------------------------------------------
// packB: W (1200,300) fp32 -> MFMA B-fragment stream for 16x16x32_f16.
// Gate-interleaved column order col' = 4*u + gate  (orig n = gate*300+u).
// Item i = (nt*10+kt)*64 + lane.
// ---------------------------------------------------------------------------
__global__ __launch_bounds__(256) void packB_kernel(
    const float* __restrict__ W0, const float* __restrict__ W1,
    const float* __restrict__ W2,
    uint4* __restrict__ T0, uint4* __restrict__ T1, uint4* __restrict__ T2)
{
  int i = blockIdx.x * 256 + threadIdx.x;
  if (i >= 48000) return;
  const float* W = (blockIdx.y == 0) ? W0 : (blockIdx.y == 1) ? W1 : W2;
  uint4* T = (blockIdx.y == 0) ? T0 : (blockIdx.y == 1) ? T1 : T2;
  int lane = i & 63;
  int tile = i >> 6;               // nt*10 + kt
  int nt = tile / 10, kt = tile - nt * 10;
  int lm = lane & 15, lg = lane >> 4;
  int colp = nt * 16 + lm;
  int u = colp >> 2, gate = colp & 3;
  int n = gate * 300 + u;
  U4H8 v;
#pragma unroll
  for (int j = 0; j < 8; j++) {
    int k = kt * 32 + lg * 8 + j;
    float x = (k < 300) ? W[(size_t)n * 300 + k] : 0.f;
    v.e[j] = (_Float16)x;
  }
  T[i] = v.u;
}

// ---------------------------------------------------------------------------
// Persistent LSTM via MFMA, partial weight residency (round-6 verified):
//   - 16 tiles in REGISTERS (2/wave) via asm-opaque gld16;
//   - 11 tiles in dynamic LDS (nt = 16..26);
//   - 48 tiles streamed (nt = 27+wv+8i, 6/wave).
// Round-7 lesson: 3 tiles/wave (120 pinned VGPR) forces spills that land
// BEFORE the explicit vmcnt(0) (compiler can't model the asm load) ->
// garbage weights. Stay at 2 tiles/wave.
// LDS: hA8 5.25KB + gsh 38.5KB + bls 112.6KB = 156.4KB.
// ---------------------------------------------------------------------------
#define LSTM_LDS_BYTES (5248 + 38528 + 11 * 10240)   // 156,416

__global__ __launch_bounds__(512, 2) void lstm_res(
    const uint4* WB0, const uint4* WB1,   // packed B-frags; no __restrict__
    const float* __restrict__ gx0, const float* __restrict__ gx1, // (64,NB,1200) interleaved
    float* hist0, float* hist1,           // (64,NB,300) or null; no __restrict__
    float* hfin,                          // (2,NB,300) or null
    int NB)
{
  extern __shared__ char smem[];
  _Float16* hA8 = (_Float16*)smem;                    // [8][328]
  float* gsh = (float*)(smem + 5248);                 // [8][1204]
  uint4* bls = (uint4*)(smem + 5248 + 38528);         // [11][640]

  const int b = blockIdx.x;
  const int xcd = b & 7;
  const int grp = b >> 3;
  const int dirb = xcd >> 2;
  const int n0 = (grp * 4 + (xcd & 3)) * 8;
  const int tid = threadIdx.x;
  const int wv = tid >> 6, lane = tid & 63;
  const int lm = lane & 15, lg = lane >> 4;

  const uint4* WB = dirb ? WB1 : WB0;
  const float* gx = dirb ? gx1 : gx0;
  float* hist = dirb ? hist1 : hist0;

  // --- register-resident tiles nt = wv, wv+8 (asm-opaque, pinned) ---
  U4H8 br0[10], br1[10];
  {
    const uint4* p0 = WB + (size_t)(wv * 10) * 64 + lane;
    const uint4* p1 = WB + (size_t)((wv + 8) * 10) * 64 + lane;
#pragma unroll
    for (int kt = 0; kt < 10; kt++) br0[kt].u = gld16(p0 + kt * 64);
#pragma unroll
    for (int kt = 0; kt < 10; kt++) br1[kt].u = gld16(p1 + kt * 64);
  }
  // --- LDS-resident tiles 16..26 (contiguous in WB): 11*640 uint4 ---
  for (int e = tid; e < 7040; e += 512) bls[e] = WB[16 * 640 + e];
  for (int e = tid; e < 8 * 328; e += 512) hA8[e] = (_Float16)0.f;
  asm volatile("s_waitcnt vmcnt(0)" ::: "memory");
  __builtin_amdgcn_sched_barrier(0);
  __syncthreads();

  // --- t-invariant elementwise indices: e = tid + q*512 -> (m,u) ---
  int gxo[5], gsho[5], hAo[5], ho[5];
  bool act[5];
#pragma unroll
  for (int q = 0; q < 5; q++) {
    int e = tid + q * 512;
    act[q] = (e < 2400);
    int m = act[q] ? (e / 300) : 0;
    int u = act[q] ? (e - m * 300) : 0;
    gxo[q] = (n0 + m) * 1200 + 4 * u;
    gsho[q] = m * 1204 + 4 * u;
    hAo[q] = m * 328 + u;
    ho[q] = (n0 + m) * 300 + u;
  }

  float crs[5] = {0.f, 0.f, 0.f, 0.f, 0.f};

  for (int t = 0; t < 64; t++) {
    const int tg = dirb ? (63 - t) : t;
    const size_t gxstep = (size_t)tg * NB * 1200;

    // prefetch x-gates (interleaved i,f,g,o), consumed post-barrier
    float4 gxv[5];
#pragma unroll
    for (int q = 0; q < 5; q++) {
      gxv[q] = make_float4(0.f, 0.f, 0.f, 0.f);
      if (act[q]) gxv[q] = *(const float4*)(gx + gxstep + gxo[q]);
    }

    // stream preload: first half of first streamed tile (nt = 27+wv)
    uint4 bA[5], bB[5];
#pragma unroll
    for (int kt = 0; kt < 5; kt++)
      bA[kt] = WB[(size_t)((27 + wv) * 10 + kt) * 64 + lane];

    // A fragments (rows 8-15 are zero: no LDS read for lm>=8)
    U4H8 af[10];
#pragma unroll
    for (int kt = 0; kt < 10; kt++) {
      uint4 v = make_uint4(0u, 0u, 0u, 0u);
      if (lm < 8) v = *(const uint4*)&hA8[lm * 328 + kt * 32 + lg * 8];
      af[kt].u = v;
    }

    // register-resident tiles (pure MFMA, hides in-flight stream loads)
    {
      f32x4v a0 = {0.f, 0.f, 0.f, 0.f};
      f32x4v a1 = {0.f, 0.f, 0.f, 0.f};
#pragma unroll
      for (int kt = 0; kt < 5; kt++)
        a0 = __builtin_amdgcn_mfma_f32_16x16x32_f16(af[kt].h, br0[kt].h, a0, 0, 0, 0);
#pragma unroll
      for (int kt = 5; kt < 10; kt++)
        a1 = __builtin_amdgcn_mfma_f32_16x16x32_f16(af[kt].h, br0[kt].h, a1, 0, 0, 0);
      if (lg < 2) {
        int col = wv * 16 + lm;
#pragma unroll
        for (int r = 0; r < 4; r++)
          gsh[(lg * 4 + r) * 1204 + col] = a0[r] + a1[r];
      }
    }
    {
      f32x4v a0 = {0.f, 0.f, 0.f, 0.f};
      f32x4v a1 = {0.f, 0.f, 0.f, 0.f};
#pragma unroll
      for (int kt = 0; kt < 5; kt++)
        a0 = __builtin_amdgcn_mfma_f32_16x16x32_f16(af[kt].h, br1[kt].h, a0, 0, 0, 0);
#pragma unroll
      for (int kt = 5; kt < 10; kt++)
        a1 = __builtin_amdgcn_mfma_f32_16x16x32_f16(af[kt].h, br1[kt].h, a1, 0, 0, 0);
      if (lg < 2) {
        int col = (wv + 8) * 16 + lm;
#pragma unroll
        for (int r = 0; r < 4; r++)
          gsh[(lg * 4 + r) * 1204 + col] = a0[r] + a1[r];
      }
    }

    // streamed tiles nt = 27+wv+8i (6 per wave), half-tile-ahead prefetch
#pragma unroll 1
    for (int i = 0; i < 6; i++) {
      int nt = 27 + wv + 8 * i;
#pragma unroll
      for (int kt = 0; kt < 5; kt++)
        bB[kt] = WB[(size_t)(nt * 10 + 5 + kt) * 64 + lane];
      f32x4v a0 = {0.f, 0.f, 0.f, 0.f};
#pragma unroll
      for (int kt = 0; kt < 5; kt++) {
        U4H8 bb; bb.u = bA[kt];
        a0 = __builtin_amdgcn_mfma_f32_16x16x32_f16(af[kt].h, bb.h, a0, 0, 0, 0);
      }
      if (i + 1 < 6) {
#pragma unroll
        for (int kt = 0; kt < 5; kt++)
          bA[kt] = WB[(size_t)((nt + 8) * 10 + kt) * 64 + lane];
      }
      f32x4v a1 = {0.f, 0.f, 0.f, 0.f};
#pragma unroll
      for (int kt = 0; kt < 5; kt++) {
        U4H8 bb; bb.u = bB[kt];
        a1 = __builtin_amdgcn_mfma_f32_16x16x32_f16(af[5 + kt].h, bb.h, a1, 0, 0, 0);
      }
      if (lg < 2) {
        int col = nt * 16 + lm;
#pragma unroll
        for (int r = 0; r < 4; r++)
          gsh[(lg * 4 + r) * 1204 + col] = a0[r] + a1[r];
      }
    }

    // LDS-resident tiles: nt = 16+wv (all waves) and 24+wv (waves 0-2)
#pragma unroll 1
    for (int li = 0; li < 2; li++) {
      int idxL = li == 0 ? wv : (8 + wv);
      if (li == 1 && wv >= 3) break;
      const uint4* bt = &bls[idxL * 640];
      f32x4v a0 = {0.f, 0.f, 0.f, 0.f};
      f32x4v a1 = {0.f, 0.f, 0.f, 0.f};
#pragma unroll
      for (int kt = 0; kt < 5; kt++) {
        U4H8 bb; bb.u = bt[kt * 64 + lane];
        a0 = __builtin_amdgcn_mfma_f32_16x16x32_f16(af[kt].h, bb.h, a0, 0, 0, 0);
      }
#pragma unroll
      for (int kt = 5; kt < 10; kt++) {
        U4H8 bb; bb.u = bt[kt * 64 + lane];
        a1 = __builtin_amdgcn_mfma_f32_16x16x32_f16(af[kt].h, bb.h, a1, 0, 0, 0);
      }
      if (lg < 2) {
        int col = (16 + idxL) * 16 + lm;
#pragma unroll
        for (int r = 0; r < 4; r++)
          gsh[(lg * 4 + r) * 1204 + col] = a0[r] + a1[r];
      }
    }
    __syncthreads();

    // elementwise: gates contiguous in gsh & gx (col' = 4u+gate)
#pragma unroll
    for (int q = 0; q < 5; q++) {
      if (act[q]) {
        const float4 gs = *(const float4*)&gsh[gsho[q]];
        float gi = gxv[q].x + gs.x;
        float gf = gxv[q].y + gs.y;
        float gg = gxv[q].z + gs.z;
        float go = gxv[q].w + gs.w;
        float si = fsig(gi);
        float sf = fsig(gf);
        float so = fsig(go);
        float cc = sf * crs[q] + si * ftanh(gg);
        float h = so * ftanh(cc);
        crs[q] = cc;
        hA8[hAo[q]] = (_Float16)h;
        if (hist) hist[(size_t)tg * NB * 300 + ho[q]] = h;
        if (hfin && t == 63) hfin[(size_t)dirb * NB * 300 + ho[q]] = h;
      }
    }
    __syncthreads();
  }
}

// ---------------------------------------------------------------------------
__global__ void embed_kernel(
    const int* __restrict__ prem, const int* __restrict__ hyp,
    const float* __restrict__ embW, float* __restrict__ comb)
{
  size_t i = (size_t)blockIdx.x * 256 + threadIdx.x;
  if (i >= (size_t)64 * 256 * 75) return;
  int d4 = (int)(i % 75);
  size_t r = i / 75;
  int n = (int)(r % 256);
  int t = (int)(r / 256);
  int id = (n < 128) ? prem[t * 128 + n] : hyp[t * 128 + (n - 128)];
  float4 v = *(const float4*)(embW + (size_t)id * 300 + d4 * 4);
  *(float4*)(comb + ((size_t)t * 256 + n) * 300 + d4 * 4) = v;
}

// ---------------------------------------------------------------------------
// norm4 v2: one persistent block per (n,dir); W^2 for all 4 sets staged ONCE
// in 96KB dynamic LDS (old version re-read 96KB of mp_W per (t,n,dir) block
// = 3.1GB of L2 traffic ~= 90us at the 34.5 TB/s L2 ceiling; now 49MB).
// Math identical per element modulo (x*x)*(w*w) vs ((x*x)*w)*w association.
// ---------------------------------------------------------------------------
#define NORM4_LDS_BYTES (96000 + 1216)

__global__ __launch_bounds__(320) void norm4_kernel(
    const float* __restrict__ hs_fw, const float* __restrict__ hs_bw,
    const float* __restrict__ mp_W,
    float* __restrict__ nm4, float* __restrict__ pnorm)
{
  extern __shared__ char nsm[];
  float* w2sh = (float*)nsm;              // [4][6000]
  float* sh = (float*)(nsm + 96000);      // [304]

  const int n = blockIdx.x, dir = blockIdx.y;
  const float* HS = dir ? hs_bw : hs_fw;
  const int tid = threadIdx.x, g = tid >> 4, lane = tid & 15;

  const float* Wd = mp_W + dir * 24000;
  for (int e = tid; e < 24000; e += 320) {
    float w = Wd[e];
    w2sh[e] = w * w;
  }
  __syncthreads();

  for (int t = 0; t < 64; t++) {
    for (int k = tid; k < 300; k += 320)
      sh[k] = HS[((size_t)t * 256 + n) * 300 + k];
    __syncthreads();
    if (g == 0) {
      float s2 = 0.f;
      for (int k = lane; k < 300; k += 16) { float x = sh[k]; s2 += x * x; }
      for (int o = 8; o; o >>= 1) s2 += __shfl_down(s2, o, 16);
      if (lane == 0) pnorm[((size_t)dir * 64 + t) * 256 + n] = sqrtf(s2);
    }
#pragma unroll
    for (int wset = 0; wset < 4; wset++) {
      const float* W2 = w2sh + wset * 6000 + g * 300;
      float s1 = 0.f;
      for (int k = lane; k < 300; k += 16) {
        float x = sh[k];
        s1 += x * x * W2[k];
      }
      for (int o = 8; o; o >>= 1) s1 += __shfl_down(s1, o, 16);
      if (lane == 0)
        nm4[((((size_t)dir * 4 + wset) * 64 + t) * 256 + n) * 20 + g] = sqrtf(s1);
    }
    __syncthreads();
  }
}

// ---------------------------------------------------------------------------
// att: per (b,z), att[64,64] cosine GEMM -> normalized w (watt) + argmax idx.
// ---------------------------------------------------------------------------
__global__ __launch_bounds__(256) void att_kernel(
    const float* __restrict__ hs_fw, const float* __restrict__ hs_bw,
    const float* __restrict__ pnorm,
    float* __restrict__ watt, int* __restrict__ idxbuf)
{
  const int b = blockIdx.x, z = blockIdx.y;
  const int dir = z & 1;
  const float* HS = dir ? hs_bw : hs_fw;
  const int p_n = (z < 2) ? b : 128 + b;
  const int h_n = (z < 2) ? 128 + b : b;
  const float* pnD = pnorm + (size_t)dir * 16384;

  __shared__ float pch[64 * 100];
  __shared__ float hch[64 * 100];
  __shared__ float att[64 * 65];
  __shared__ float winv_sh[64];

  const int tid = threadIdx.x;
  const int i = tid >> 4, j = tid & 15;
  float acc[4][4];
#pragma unroll
  for (int a = 0; a < 4; a++)
#pragma unroll
    for (int c = 0; c < 4; c++) acc[a][c] = 0.f;

  for (int kc = 0; kc < 300; kc += 100) {
    for (int e = tid; e < 1600; e += 256) {
      int row = e / 25, kq = e - row * 25;
      float4 v = *(const float4*)(HS + ((size_t)row * 256 + p_n) * 300 + kc + kq * 4);
      *(float4*)&pch[row * 100 + kq * 4] = v;
      float4 w = *(const float4*)(HS + ((size_t)row * 256 + h_n) * 300 + kc + kq * 4);
      *(float4*)&hch[row * 100 + kq * 4] = w;
    }
    __syncthreads();
#pragma unroll 5
    for (int kq = 0; kq < 25; kq++) {
      float4 av[4], bv[4];
#pragma unroll
      for (int a = 0; a < 4; a++) av[a] = *(const float4*)&pch[(i + 16 * a) * 100 + kq * 4];
#pragma unroll
      for (int c = 0; c < 4; c++) bv[c] = *(const float4*)&hch[(j + 16 * c) * 100 + kq * 4];
#pragma unroll
      for (int a = 0; a < 4; a++)
#pragma unroll
        for (int c = 0; c < 4; c++)
          acc[a][c] += av[a].x * bv[c].x + av[a].y * bv[c].y + av[a].z * bv[c].z + av[a].w * bv[c].w;
    }
    __syncthreads();
  }

#pragma unroll
  for (int a = 0; a < 4; a++) {
    int t = i + 16 * a;
    float pn = pnD[t * 256 + p_n] + EPSF;
#pragma unroll
    for (int c = 0; c < 4; c++) {
      int s = j + 16 * c;
      float hn = pnD[s * 256 + h_n] + EPSF;
      att[t * 65 + s] = acc[a][c] / (pn * hn);
    }
  }
  __syncthreads();
  if (tid < 64) {
    int t = tid;
    float ssum = 0.f, mx = -1e30f; int mi = 0;
    for (int s = 0; s < 64; s++) {
      float a = att[t * 65 + s];
      ssum += a;
      if (a > mx) { mx = a; mi = s; }
    }
    winv_sh[t] = 1.f / (ssum + EPSF);
    idxbuf[((size_t)z * 128 + b) * 64 + t] = mi;
  }
  __syncthreads();
  for (int e = tid; e < 4096; e += 256) {
    int t = e >> 6, s = e & 63;
    watt[((size_t)z * 128 + b) * 4096 + t * 64 + s] = att[t * 65 + s] * winv_sh[t];
  }
}

// ---------------------------------------------------------------------------
// hmean: per (b,z): hmean[t,k] = sum_s w[t,s]*h[s,k]
// ---------------------------------------------------------------------------
__global__ __launch_bounds__(256) void hmean_kernel(
    const float* __restrict__ hs_fw, const float* __restrict__ hs_bw,
    const float* __restrict__ watt, float* __restrict__ hmeanbuf)
{
  const int b = blockIdx.x, z = blockIdx.y;
  const int dir = z & 1;
  const float* HS = dir ? hs_bw : hs_fw;
  const int h_n = (z < 2) ? 128 + b : b;

  __shared__ float wsh[64 * 65];
  __shared__ float hch[64 * 128];

  const int tid = threadIdx.x;
  const int ti = tid >> 4, kj = tid & 15;
  const float* wsrc = watt + ((size_t)z * 128 + b) * 4096;
  for (int e = tid; e < 4096; e += 256) {
    int t = e >> 6, s = e & 63;
    wsh[t * 65 + s] = wsrc[t * 64 + s];
  }

  for (int kbase = 0; kbase < 300; kbase += 128) {
    int kw = min(128, 300 - kbase);
    int nf4 = kw >> 2;  // 32,32,11
    __syncthreads();
    for (int e = tid; e < 64 * nf4; e += 256) {
      int row = e / nf4, q = e - row * nf4;
      float4 v = *(const float4*)(HS + ((size_t)row * 256 + h_n) * 300 + kbase + q * 4);
      *(float4*)&hch[row * 128 + q * 4] = v;
    }
    __syncthreads();
    float acc[4][8];
#pragma unroll
    for (int a = 0; a < 4; a++)
#pragma unroll
      for (int c = 0; c < 8; c++) acc[a][c] = 0.f;
    for (int s = 0; s < 64; s++) {
      float4 h0 = *(const float4*)&hch[s * 128 + 4 * kj];
      float4 h1 = *(const float4*)&hch[s * 128 + 4 * (kj + 16)];
#pragma unroll
      for (int a = 0; a < 4; a++) {
        float w = wsh[(4 * ti + a) * 65 + s];
        acc[a][0] += w * h0.x; acc[a][1] += w * h0.y; acc[a][2] += w * h0.z; acc[a][3] += w * h0.w;
        acc[a][4] += w * h1.x; acc[a][5] += w * h1.y; acc[a][6] += w * h1.z; acc[a][7] += w * h1.w;
      }
    }
#pragma unroll
    for (int a = 0; a < 4; a++) {
      int t = 4 * ti + a;
#pragma unroll
      for (int c = 0; c < 2; c++) {
        int kq = kj + 16 * c;
        if (kq * 4 < kw) {
          int k = kbase + kq * 4;
          float4 v = make_float4(acc[a][4 * c], acc[a][4 * c + 1], acc[a][4 * c + 2], acc[a][4 * c + 3]);
          *(float4*)&hmeanbuf[(((size_t)z * 128 + b) * 64 + t) * 300 + k] = v;
        }
      }
    }
  }
}

// ---------------------------------------------------------------------------
// maxp via MFMA f16 (round-5 WIN): per (b,z) ONE block; x = l*64+t tiling;
// A-frag = p-frag (*) w2[l]-frag; h-frags reg-cached per st-pair.
// ---------------------------------------------------------------------------
#define MAXP_LDS_BYTES (41984 + 41984 + 13120 + 5120 + 5120)  // 107,328

__global__ __launch_bounds__(512, 2) void maxp_mfma(
    const float* __restrict__ hs_fw, const float* __restrict__ hs_bw,
    const float* __restrict__ mp_W, const float* __restrict__ nm4,
    float* __restrict__ m_out)
{
  extern __shared__ char smem[];
  _Float16* pA = (_Float16*)smem;                     // [64][328]
  _Float16* hB = (_Float16*)(smem + 41984);           // [64][328]
  _Float16* w2h = (_Float16*)(smem + 83968);          // [20][328]
  float* pn_sh = (float*)(smem + 97088);              // [64][20]
  float* hn_sh = (float*)(smem + 102208);             // [64][20]

  const int b = blockIdx.x, z = blockIdx.y;
  const int dir = z & 1;
  const float* HS = dir ? hs_bw : hs_fw;
  const int p_n = (z < 2) ? b : 128 + b;
  const int h_n = (z < 2) ? 128 + b : b;
  const float* Wm = mp_W + dir * 24000 + 6000;
  const float* nmD = nm4 + ((size_t)dir * 4 + 1) * 327680;

  const int tid = threadIdx.x;
  const int wv = tid >> 6, lane = tid & 63;
  const int lm = lane & 15, lg = lane >> 4;

  // ---- stage p, h (f32->f16), w2 (squared f16), pn, hn ----
  for (int e = tid; e < 4800; e += 512) {
    int row = e / 75, q = e - row * 75;
    float4 v = *(const float4*)(HS + ((size_t)row * 256 + p_n) * 300 + q * 4);
    float4 w = *(const float4*)(HS + ((size_t)row * 256 + h_n) * 300 + q * 4);
    _Float16* pd = &pA[row * 328 + q * 4];
    pd[0] = (_Float16)v.x; pd[1] = (_Float16)v.y; pd[2] = (_Float16)v.z; pd[3] = (_Float16)v.w;
    _Float16* hd = &hB[row * 328 + q * 4];
    hd[0] = (_Float16)w.x; hd[1] = (_Float16)w.y; hd[2] = (_Float16)w.z; hd[3] = (_Float16)w.w;
  }
  for (int e = tid; e < 64 * 28; e += 512) {
    int row = e / 28, c = 300 + (e - row * 28);
    pA[row * 328 + c] = (_Float16)0.f;
    hB[row * 328 + c] = (_Float16)0.f;
  }
  for (int e = tid; e < 1500; e += 512) {
    int row = e / 75, q = e - row * 75;
    float4 w = *(const float4*)(Wm + (size_t)row * 300 + q * 4);
    _Float16* d = &w2h[row * 328 + q * 4];
    d[0] = (_Float16)(w.x * w.x); d[1] = (_Float16)(w.y * w.y);
    d[2] = (_Float16)(w.z * w.z); d[3] = (_Float16)(w.w * w.w);
  }
  for (int e = tid; e < 20 * 28; e += 512) {
    int row = e / 28, c = 300 + (e - row * 28);
    w2h[row * 328 + c] = (_Float16)0.f;
  }
  for (int e = tid; e < 1280; e += 512) {
    int tq = e / 20, l = e - tq * 20;
    pn_sh[e] = nmD[((size_t)tq * 256 + p_n) * 20 + l];
    hn_sh[e] = nmD[((size_t)tq * 256 + h_n) * 20 + l];
  }
  __syncthreads();

  // ---- compute: wave wv owns x-tiles xt = wv + 8i (10 tiles) ----
  float rmax[10][4];
#pragma unroll
  for (int i = 0; i < 10; i++)
#pragma unroll
    for (int r = 0; r < 4; r++) rmax[i][r] = -1e30f;

#pragma unroll
  for (int sp = 0; sp < 2; sp++) {       // st pairs {0,1},{2,3}
    U4H8 hf[2][10];
#pragma unroll
    for (int hh = 0; hh < 2; hh++)
#pragma unroll
      for (int kt = 0; kt < 10; kt++)
        hf[hh][kt].u = *(const uint4*)&hB[(sp * 32 + hh * 16 + lm) * 328 + kt * 32 + lg * 8];

#pragma unroll
    for (int i = 0; i < 10; i++) {
      int xt = wv + 8 * i;               // 0..79
      int l = xt >> 2, t0 = (xt & 3) << 4;
      U4H8 af[10];
#pragma unroll
      for (int kt = 0; kt < 10; kt++) {
        U4H8 pf, wf;
        pf.u = *(const uint4*)&pA[(t0 + lm) * 328 + kt * 32 + lg * 8];
        wf.u = *(const uint4*)&w2h[l * 328 + kt * 32 + lg * 8];
        af[kt].h = pf.h * wf.h;          // v_pk_mul_f16
      }
      float pnv[4];
#pragma unroll
      for (int r = 0; r < 4; r++) pnv[r] = pn_sh[(t0 + lg * 4 + r) * 20 + l];
#pragma unroll
      for (int hh = 0; hh < 2; hh++) {
        int st = sp * 2 + hh;
        f32x4v acc = {0.f, 0.f, 0.f, 0.f};
#pragma unroll
        for (int kt = 0; kt < 10; kt++)
          acc = __builtin_amdgcn_mfma_f32_16x16x32_f16(af[kt].h, hf[hh][kt].h, acc, 0, 0, 0);
        float hn = hn_sh[(st * 16 + lm) * 20 + l];
#pragma unroll
        for (int r = 0; r < 4; r++) {
          float val = acc[r] * __builtin_amdgcn_rcpf(pnv[r] * hn + EPSF);
          rmax[i][r] = fmaxf(rmax[i][r], val);
        }
      }
    }
  }

  // ---- cross-lane max over s (16-lane groups) + write ----
#pragma unroll
  for (int i = 0; i < 10; i++) {
    int xt = wv + 8 * i;
    int l = xt >> 2, t0 = (xt & 3) << 4;
#pragma unroll
    for (int r = 0; r < 4; r++) {
      float v = rmax[i][r];
#pragma unroll
      for (int off = 8; off; off >>= 1) v = fmaxf(v, __shfl_down(v, off, 16));
      if (lm == 0) {
        int t = t0 + lg * 4 + r;
        m_out[((size_t)t * 128 + b) * 320 + z * 80 + 20 + l] = v;
      }
    }
  }
}

// ---------------------------------------------------------------------------
// rest: per (b,z): full / attm / maxattm for all t. W^2 staged once in LDS.
// ---------------------------------------------------------------------------
__global__ __launch_bounds__(320) void rest_kernel(
    const float* __restrict__ hs_fw, const float* __restrict__ hs_bw,
    const float* __restrict__ mp_W, const float* __restrict__ nm4,
    const float* __restrict__ hmeanbuf, const int* __restrict__ idxbuf,
    float* __restrict__ m_out)
{
  const int b = blockIdx.x, z = blockIdx.y;
  const int dir = z & 1;
  const float* HS = dir ? hs_bw : hs_fw;
  const int p_n = (z < 2) ? b : 128 + b;
  const int h_n = (z < 2) ? 128 + b : b;
  const int v_t = dir ? 0 : 63;

  __shared__ float w2f[6000], w2a[6000], w2m[6000];
  __shared__ float vsh[300], psh[300], hmsh[300], hxsh[300];

  const int tid = threadIdx.x;
  const int g = tid >> 4, lane = tid & 15;
  const float* Wf = mp_W + dir * 24000;
  const float* Wa = Wf + 12000;
  const float* Wma = Wf + 18000;
  for (int e = tid; e < 6000; e += 320) {
    float a = Wf[e], bb = Wa[e], c = Wma[e];
    w2f[e] = a * a; w2a[e] = bb * bb; w2m[e] = c * c;
  }
  for (int e = tid; e < 300; e += 320)
    vsh[e] = HS[((size_t)v_t * 256 + h_n) * 300 + e];
  __syncthreads();

  const float* base0 = nm4 + ((size_t)dir * 4 + 0) * 327680;
  const float* base2 = nm4 + ((size_t)dir * 4 + 2) * 327680;
  const float* base3 = nm4 + ((size_t)dir * 4 + 3) * 327680;
  const float vnf = base0[((size_t)v_t * 256 + h_n) * 20 + g];

  for (int t = 0; t < 64; t++) {
    int idx = idxbuf[((size_t)z * 128 + b) * 64 + t];
    __syncthreads();
    for (int e = tid; e < 300; e += 320) {
      psh[e] = HS[((size_t)t * 256 + p_n) * 300 + e];
      hmsh[e] = hmeanbuf[(((size_t)z * 128 + b) * 64 + t) * 300 + e];
      hxsh[e] = HS[((size_t)idx * 256 + h_n) * 300 + e];
    }
    __syncthreads();
    float nf = 0.f, na = 0.f, qa = 0.f, nm = 0.f;
#pragma unroll
    for (int c = 0; c < 5; c++) {
      int k4 = lane + 16 * c;
      if (k4 < 75) {
        float4 p = *(const float4*)&psh[4 * k4];
        float4 v = *(const float4*)&vsh[4 * k4];
        float4 hm = *(const float4*)&hmsh[4 * k4];
        float4 hx = *(const float4*)&hxsh[4 * k4];
        float4 wf = *(const float4*)&w2f[g * 300 + 4 * k4];
        float4 wa = *(const float4*)&w2a[g * 300 + 4 * k4];
        float4 wm = *(const float4*)&w2m[g * 300 + 4 * k4];
        nf += p.x * v.x * wf.x + p.y * v.y * wf.y + p.z * v.z * wf.z + p.w * v.w * wf.w;
        na += p.x * hm.x * wa.x + p.y * hm.y * wa.y + p.z * hm.z * wa.z + p.w * hm.w * wa.w;
        qa += hm.x * hm.x * wa.x + hm.y * hm.y * wa.y + hm.z * hm.z * wa.z + hm.w * hm.w * wa.w;
        nm += p.x * hx.x * wm.x + p.y * hx.y * wm.y + p.z * hx.z * wm.z + p.w * hx.w * wm.w;
      }
    }
#pragma unroll
    for (int o = 8; o; o >>= 1) {
      nf += __shfl_down(nf, o);
      na += __shfl_down(na, o);
      qa += __shfl_down(qa, o);
      nm += __shfl_down(nm, o);
    }
    if (lane == 0) {
      float pnf = base0[((size_t)t * 256 + p_n) * 20 + g];
      float pna = base2[((size_t)t * 256 + p_n) * 20 + g];
      float pnm = base3[((size_t)t * 256 + p_n) * 20 + g];
      float qnm = base3[((size_t)idx * 256 + h_n) * 20 + g];
      float* mrow = m_out + ((size_t)t * 128 + b) * 320 + z * 80;
      mrow[g] = nf / (pnf * vnf + EPSF);
      mrow[40 + g] = na / (pna * sqrtf(qa) + EPSF);
      mrow[60 + g] = nm / (pnm * qnm + EPSF);
    }
  }
}

// ---------------------------------------------------------------------------
__global__ __launch_bounds__(256) void mlp_kernel(
    const float* __restrict__ shA0, const float* __restrict__ shA1,
    const float* __restrict__ bnG, const float* __restrict__ bnB,
    const float* __restrict__ W1, const float* __restrict__ b1,
    const float* __restrict__ W2, const float* __restrict__ b2,
    const float* __restrict__ outW, const float* __restrict__ outb,
    float* __restrict__ out)
{
  const int b = blockIdx.x;
  const int tid = threadIdx.x;
  __shared__ float x0[600], x1[600];
  const float inv = 1.0f / sqrtf(1.0f + 1e-5f);
  for (int j = tid; j < 600; j += 256) {
    float v = (j < 300) ? shA0[b * 300 + j] : shA1[b * 300 + (j - 300)];
    x0[j] = bnG[j] * v * inv + bnB[j];
  }
  __syncthreads();
  for (int j = tid; j < 600; j += 256) {
    float acc = b1[j];
    const float* w = W1 + (size_t)j * 600;
    for (int k = 0; k < 600; k++) acc += x0[k] * w[k];
    float r = fmaxf(acc, 0.f);
    x1[j] = bnG[600 + j] * r * inv + bnB[600 + j];
  }
  __syncthreads();
  for (int j = tid; j < 600; j += 256) {
    float acc = b2[j];
    const float* w = W2 + (size_t)j * 600;
    for (int k = 0; k < 600; k++) acc += x1[k] * w[k];
    float r = fmaxf(acc, 0.f);
    x0[j] = bnG[1200 + j] * r * inv + bnB[1200 + j];
  }
  __syncthreads();
  if (tid < 3) {
    float acc = outb[tid];
    const float* w = outW + tid * 600;
    for (int k = 0; k < 600; k++) acc += x0[k] * w[k];
    out[b * 3 + tid] = acc;
  }
}

// ---------------------------------------------------------------------------
extern "C" void kernel_launch(void* const* d_in, const int* in_sizes, int n_in,
                              void* d_out, int out_size, void* d_ws, size_t ws_size,
                              hipStream_t stream) {
  const int* premise = (const int*)d_in[0];
  const int* hypothesis = (const int*)d_in[1];
  const float* embW = (const float*)d_in[2];
  const float* cWih = (const float*)d_in[3];
  const float* cWhh = (const float*)d_in[4];
  const float* cb = (const float*)d_in[5];
  const float* mpW = (const float*)d_in[6];
  const float* aWihF = (const float*)d_in[7];
  const float* aWhhF = (const float*)d_in[8];
  const float* abF = (const float*)d_in[9];
  const float* aWihB = (const float*)d_in[10];
  const float* aWhhB = (const float*)d_in[11];
  const float* abB = (const float*)d_in[12];
  const float* bnG = (const float*)d_in[13];
  const float* bnB = (const float*)d_in[14];
  const float* W1 = (const float*)d_in[15];
  const float* b1 = (const float*)d_in[16];
  const float* W2 = (const float*)d_in[17];
  const float* b2 = (const float*)d_in[18];
  const float* outW = (const float*)d_in[19];
  const float* outb = (const float*)d_in[20];
  float* out = (float*)d_out;

  float* ws = (float*)d_ws;
  // workspace layout (floats)
  float* comb  = ws + 0;           // 4,915,200  (T,256,300); WB packs + aWih perms overlay after ctx-gates GEMM
  float* gates = ws + 4915200;     // 19,660,800 (T,256,1200); overlaid after ctx LSTM
  float* hsfw  = ws + 24576000;    // 4,915,200  (cWih perm overlays here pre-LSTM)
  float* hsbw  = ws + 29491200;    // 4,915,200
  float* pnorm = ws + 34406400;    // 32,768    [2][64][256]
  float* mbuf  = ws + 35094528;    // 2,621,440 (T,128,320)
  float* sha   = ws + 38023168;    // 76,800    agg final h [2][128][300]

  // packed MFMA B-fragment weights overlay in comb region (dead after ctx-gates GEMM)
  uint4* WBctx = (uint4*)comb;
  uint4* WBaf  = (uint4*)(comb + 192000);
  uint4* WBab  = (uint4*)(comb + 384000);
  // gate-interleaved agg input weights (dead comb region, after WB packs)
  float* aWihFP = comb + 576000;   // 384,000
  float* aWihBP = comb + 960000;   // 384,000
  float* abFP   = comb + 1344000;  // 1,200
  float* abBP   = comb + 1345200;  // 1,200

  // gate-interleaved ctx input weights: hsfw region is dead until ctx LSTM
  float* cWihP = hsfw;             // 360,000
  float* cbP   = hsfw + 360000;    // 1,200

  // overlays inside the dead ctx-gates region (valid between ctx LSTM and agg GEMMs)
  float* watt     = gates;                 // 2,097,152 [4][128][64][64]
  float* hmeanbuf = gates + 2097152;       // 9,830,400 [4][128][64][300]
  int*   idxbuf   = (int*)(gates + 11927552); // 32,768 [4][128][64]
  float* nm4      = gates + 11960320;      // 2,621,440 [2][4][64][256][20]

  // allow >64KB dynamic LDS (gfx950 pool = 160KB/WG)
  hipFuncSetAttribute((const void*)lstm_res,
                      hipFuncAttributeMaxDynamicSharedMemorySize, LSTM_LDS_BYTES);
  hipFuncSetAttribute((const void*)maxp_mfma,
                      hipFuncAttributeMaxDynamicSharedMemorySize, MAXP_LDS_BYTES);
  hipFuncSetAttribute((const void*)gemm_mfma_nt,
                      hipFuncAttributeMaxDynamicSharedMemorySize, GMM_LDS_BYTES);
  hipFuncSetAttribute((const void*)norm4_kernel,
                      hipFuncAttributeMaxDynamicSharedMemorySize, NORM4_LDS_BYTES);

  // 1) embed + ctx input-weight gate-interleave
  embed_kernel<<<dim3(4800), dim3(256), 0, stream>>>(premise, hypothesis, embW, comb);
  permW_kernel<<<dim3(1200), dim3(256), 0, stream>>>(cWih, cb, cWihP, cbP, 300);

  // 2) ctx input gates (consumes comb) — split-f16 MFMA, fp32-grade accuracy
  gemm_mfma_nt<<<dim3(5, 128), dim3(512), GMM_LDS_BYTES, stream>>>(
      comb, cWihP, cbP, gates, 16384, 300);

  // 3) pack recurrent weights into MFMA B-fragment stream (dead comb region)
  //    + gate-interleave the agg input weights
  packB_kernel<<<dim3(188, 3), dim3(256), 0, stream>>>(
      cWhh, aWhhF, aWhhB, WBctx, WBaf, WBab);
  permW_kernel<<<dim3(1200), dim3(256), 0, stream>>>(aWihF, abF, aWihFP, abFP, 320);
  permW_kernel<<<dim3(1200), dim3(256), 0, stream>>>(aWihB, abB, aWihBP, abBP, 320);

  // 4) context LSTM: 16 reg + 11 LDS tiles resident, 48 streamed (r6 config)
  lstm_res<<<dim3(64), dim3(512), LSTM_LDS_BYTES, stream>>>(
      WBctx, WBctx, gates, gates, hsfw, hsbw, nullptr, 256);

  // 5) norms: persistent per (n,dir), W^2 staged once (kills 3.1GB L2 re-read)
  norm4_kernel<<<dim3(256, 2), dim3(320), NORM4_LDS_BYTES, stream>>>(
      hsfw, hsbw, mpW, nm4, pnorm);

  // 6) matching pipeline
  att_kernel<<<dim3(128, 4), dim3(256), 0, stream>>>(hsfw, hsbw, pnorm, watt, idxbuf);
  hmean_kernel<<<dim3(128, 4), dim3(256), 0, stream>>>(hsfw, hsbw, watt, hmeanbuf);
  maxp_mfma<<<dim3(128, 4), dim3(512), MAXP_LDS_BYTES, stream>>>(
      hsfw, hsbw, mpW, nm4, mbuf);
  rest_kernel<<<dim3(128, 4), dim3(320), 0, stream>>>(hsfw, hsbw, mpW, nm4, hmeanbuf, idxbuf, mbuf);

  // 7) agg input gates — split-f16 MFMA, gate-interleaved columns
  float* gaf = gates;
  float* gab = gates + 9830400;
  gemm_mfma_nt<<<dim3(5, 64), dim3(512), GMM_LDS_BYTES, stream>>>(
      mbuf, aWihFP, abFP, gaf, 8192, 320);
  gemm_mfma_nt<<<dim3(5, 64), dim3(512), GMM_LDS_BYTES, stream>>>(
      mbuf, aWihBP, abBP, gab, 8192, 320);

  // 8) aggregation LSTM: 32 blocks (16/dir), 8 waves
  lstm_res<<<dim3(32), dim3(512), LSTM_LDS_BYTES, stream>>>(
      WBaf, WBab, gaf, gab, nullptr, nullptr, sha, 128);

  // 9) MLP head
  mlp_kernel<<<dim3(128), dim3(256), 0, stream>>>(
      sha, sha + 38400, bnG, bnB, W1, b1, W2, b2, outW, outb, out);
}

// Round 10
// 2191.329 us; speedup vs baseline: 1.0974x; 1.0974x over previous
//
#include <hip/hip_runtime.h>
#include <cstddef>
#include <cstdint>
#include <math.h>

#define EPSF 1e-8f

// Model dims (fixed): T=64, B=128, D=300, H=300, L=20, AH=300, N2=2B=256

typedef _Float16 half8v __attribute__((ext_vector_type(8)));
typedef float f32x4v __attribute__((ext_vector_type(4)));
union U4H8 { uint4 u; half8v h; _Float16 e[8]; };

// fast device math: v_exp_f32 + v_rcp_f32 (rel err ~1e-7, fine for 3e-3 budget)
__device__ __forceinline__ float fsig(float x) {
  float e = __expf(-x);
  return __builtin_amdgcn_rcpf(1.f + e);
}
__device__ __forceinline__ float ftanh(float x) {
  float e = __expf(-2.f * fabsf(x));
  float r = (1.f - e) * __builtin_amdgcn_rcpf(1.f + e);
  return copysignf(r, x);
}

// asm-opaque 16B load WITH INTERNAL WAIT: result is architecturally valid at
// asm-exit, so any compiler-inserted spill or AGPR copy of the result stores
// correct data. (Round-7 failure: external vmcnt(0) + 120 pinned VGPR ->
// allocator placed spills BEFORE the wait -> garbage. Internal wait closes
// that hazard by construction; one-time ~300cyc/load serialization only.)
__device__ __forceinline__ uint4 gld16w(const uint4* p) {
  uint4 r;
  asm volatile("global_load_dwordx4 %0, %1, off\n\ts_waitcnt vmcnt(0)"
               : "=v"(r) : "v"(p) : "memory");
  return r;
}

// ---------------------------------------------------------------------------
// Split-f16 MFMA NT GEMM (round-6 WIN): C = bias + A*B^T, fp32-grade via
// A=Ah+Al, B=Bh+Bl, C ~= AhBh+AlBh+AhBl (dropped AlBl ~2^-22).
// Tile 128x240, N=1200=5x240; 512 thr; LDS pitch-72 hi/lo staging.
// ---------------------------------------------------------------------------
#define GMM_LDS_BYTES (2 * (128 * 72 * 2) + 2 * (240 * 72 * 2))  // 105,984

__global__ __launch_bounds__(512, 1) void gemm_mfma_nt(
    const float* __restrict__ A, const float* __restrict__ B,
    const float* __restrict__ bias, float* __restrict__ C,
    int M, int K)
{
  extern __shared__ char smem[];
  _Float16* Ah = (_Float16*)smem;                       // [128][72]
  _Float16* Al = (_Float16*)(smem + 18432);             // [128][72]
  _Float16* Bh = (_Float16*)(smem + 36864);             // [240][72]
  _Float16* Bl = (_Float16*)(smem + 36864 + 34560);     // [240][72]

  const int tid = threadIdx.x;
  const int wv = tid >> 6, lane = tid & 63;
  const int lm = lane & 15, lg = lane >> 4;
  const int mbase = blockIdx.y << 7;
  const int nbase = blockIdx.x * 240;

  f32x4v acc[15];
#pragma unroll
  for (int nt = 0; nt < 15; nt++) acc[nt] = (f32x4v){0.f, 0.f, 0.f, 0.f};

  const int nchunk = (K + 63) >> 6;
  for (int c = 0; c < nchunk; c++) {
    const int kc = c << 6;
    // stage A 128x64 -> hi/lo f16
    for (int e = tid; e < 2048; e += 512) {
      int row = e >> 4, q = e & 15;
      int k = kc + q * 4;
      const float* src = A + (size_t)(mbase + row) * K;
      float4 v = make_float4(0.f, 0.f, 0.f, 0.f);
      if (k + 4 <= K) {
        v = *(const float4*)(src + k);
      } else {
        if (k + 0 < K) v.x = src[k + 0];
        if (k + 1 < K) v.y = src[k + 1];
        if (k + 2 < K) v.z = src[k + 2];
        if (k + 3 < K) v.w = src[k + 3];
      }
      _Float16 hx = (_Float16)v.x, hy = (_Float16)v.y,
               hz = (_Float16)v.z, hw = (_Float16)v.w;
      _Float16* d = &Ah[row * 72 + q * 4];
      d[0] = hx; d[1] = hy; d[2] = hz; d[3] = hw;
      _Float16* dl = &Al[row * 72 + q * 4];
      dl[0] = (_Float16)(v.x - (float)hx); dl[1] = (_Float16)(v.y - (float)hy);
      dl[2] = (_Float16)(v.z - (float)hz); dl[3] = (_Float16)(v.w - (float)hw);
    }
    // stage B 240x64 -> hi/lo f16
    for (int e = tid; e < 3840; e += 512) {
      int row = e >> 4, q = e & 15;
      int k = kc + q * 4;
      const float* src = B + (size_t)(nbase + row) * K;
      float4 v = make_float4(0.f, 0.f, 0.f, 0.f);
      if (k + 4 <= K) {
        v = *(const float4*)(src + k);
      } else {
        if (k + 0 < K) v.x = src[k + 0];
        if (k + 1 < K) v.y = src[k + 1];
        if (k + 2 < K) v.z = src[k + 2];
        if (k + 3 < K) v.w = src[k + 3];
      }
      _Float16 hx = (_Float16)v.x, hy = (_Float16)v.y,
               hz = (_Float16)v.z, hw = (_Float16)v.w;
      _Float16* d = &Bh[row * 72 + q * 4];
      d[0] = hx; d[1] = hy; d[2] = hz; d[3] = hw;
      _Float16* dl = &Bl[row * 72 + q * 4];
      dl[0] = (_Float16)(v.x - (float)hx); dl[1] = (_Float16)(v.y - (float)hy);
      dl[2] = (_Float16)(v.z - (float)hz); dl[3] = (_Float16)(v.w - (float)hw);
    }
    __syncthreads();

#pragma unroll
    for (int kt = 0; kt < 2; kt++) {
      U4H8 ah, al;
      ah.u = *(const uint4*)&Ah[(wv * 16 + lm) * 72 + kt * 32 + lg * 8];
      al.u = *(const uint4*)&Al[(wv * 16 + lm) * 72 + kt * 32 + lg * 8];
#pragma unroll
      for (int nt = 0; nt < 15; nt++) {
        U4H8 bh, bl;
        bh.u = *(const uint4*)&Bh[(nt * 16 + lm) * 72 + kt * 32 + lg * 8];
        bl.u = *(const uint4*)&Bl[(nt * 16 + lm) * 72 + kt * 32 + lg * 8];
        acc[nt] = __builtin_amdgcn_mfma_f32_16x16x32_f16(ah.h, bh.h, acc[nt], 0, 0, 0);
        acc[nt] = __builtin_amdgcn_mfma_f32_16x16x32_f16(al.h, bh.h, acc[nt], 0, 0, 0);
        acc[nt] = __builtin_amdgcn_mfma_f32_16x16x32_f16(ah.h, bl.h, acc[nt], 0, 0, 0);
      }
    }
    __syncthreads();
  }

  // epilogue: D col = nbase+nt*16+lm, row m = mbase+wv*16+lg*4+r
#pragma unroll
  for (int nt = 0; nt < 15; nt++) {
    int col = nbase + nt * 16 + lm;
    float bv = bias[col];
#pragma unroll
    for (int r = 0; r < 4; r++) {
      int m = mbase + wv * 16 + lg * 4 + r;
      C[(size_t)m * 1200 + col] = acc[nt][r] + bv;
    }
  }
}

// ---------------------------------------------------------------------------
// permW: permute Wih rows to gate-interleaved order (row' = 4u+gate).
// ---------------------------------------------------------------------------
__global__ __launch_bounds__(256) void permW_kernel(
    const float* __restrict__ W, const float* __restrict__ bias,
    float* __restrict__ Wp, float* __restrict__ bp, int K)
{
  int r = blockIdx.x;              // 0..1199 = col' = 4u+gate
  int gate = r & 3, u = r >> 2;
  int src = gate * 300 + u;
  const float* s = W + (size_t)src * K;
  float* d = Wp + (size_t)r * K;
  for (int c = threadIdx.x; c < K; c += 256) d[c] = s[c];
  if (threadIdx.x == 0) bp[r] = bias[src];
}

// ---------------------------------------------------------------------------
// packB: W (1200,300) fp32 -> MFMA B-fragment stream for 16x16x32_f16.
// Gate-interleaved column order col' = 4*u + gate  (orig n = gate*300+u).
// Item i = (nt*10+kt)*64 + lane.
// ---------------------------------------------------------------------------
__global__ __launch_bounds__(256) void packB_kernel(
    const float* __restrict__ W0, const float* __restrict__ W1,
    const float* __restrict__ W2,
    uint4* __restrict__ T0, uint4* __restrict__ T1, uint4* __restrict__ T2)
{
  int i = blockIdx.x * 256 + threadIdx.x;
  if (i >= 48000) return;
  const float* W = (blockIdx.y == 0) ? W0 : (blockIdx.y == 1) ? W1 : W2;
  uint4* T = (blockIdx.y == 0) ? T0 : (blockIdx.y == 1) ? T1 : T2;
  int lane = i & 63;
  int tile = i >> 6;               // nt*10 + kt
  int nt = tile / 10, kt = tile - nt * 10;
  int lm = lane & 15, lg = lane >> 4;
  int colp = nt * 16 + lm;
  int u = colp >> 2, gate = colp & 3;
  int n = gate * 300 + u;
  U4H8 v;
#pragma unroll
  for (int j = 0; j < 8; j++) {
    int k = kt * 32 + lg * 8 + j;
    float x = (k < 300) ? W[(size_t)n * 300 + k] : 0.f;
    v.e[j] = (_Float16)x;
  }
  T[i] = v.u;
}

// ---------------------------------------------------------------------------
// Persistent LSTM via MFMA, partial weight residency, round 10: 3rd register
// tile per wave with spill-safe gld16w. Stream-byte model (r3/r4/r5):
// 0.121us/streamed tile/step (~35 B/cyc/CU L2->L1 fill wall).
//   - 24 tiles in REGISTERS (3/wave: nt = wv, wv+8, wv+16) via gld16w
//     (internal vmcnt(0): result valid at asm-exit -> spills store valid
//     data; round-7's corruption closed by construction).
//   - 11 tiles in dynamic LDS (nt = 24..34).
//   - 40 tiles streamed (nt = 35+wv+8i, i<5, uniform 5/wave), 410KB/step.
// LDS: hA8 5.25KB + gsh 38.5KB + bls 112.6KB = 156.4KB.
// ---------------------------------------------------------------------------
#define LSTM_LDS_BYTES (5248 + 38528 + 11 * 10240)   // 156,416

__global__ __launch_bounds__(512, 2) void lstm_res(
    const uint4* WB0, const uint4* WB1,   // packed B-frags; no __restrict__
    const float* __restrict__ gx0, const float* __restrict__ gx1, // (64,NB,1200) interleaved
    float* hist0, float* hist1,           // (64,NB,300) or null; no __restrict__
    float* hfin,                          // (2,NB,300) or null
    int NB)
{
  extern __shared__ char smem[];
  _Float16* hA8 = (_Float16*)smem;                    // [8][328]
  float* gsh = (float*)(smem + 5248);                 // [8][1204]
  uint4* bls = (uint4*)(smem + 5248 + 38528);         // [11][640]

  const int b = blockIdx.x;
  const int xcd = b & 7;
  const int grp = b >> 3;
  const int dirb = xcd >> 2;
  const int n0 = (grp * 4 + (xcd & 3)) * 8;
  const int tid = threadIdx.x;
  const int wv = tid >> 6, lane = tid & 63;
  const int lm = lane & 15, lg = lane >> 4;

  const uint4* WB = dirb ? WB1 : WB0;
  const float* gx = dirb ? gx1 : gx0;
  float* hist = dirb ? hist1 : hist0;

  // --- register-resident tiles nt = wv, wv+8, wv+16 (spill-safe loads) ---
  U4H8 br0[10], br1[10], br2[10];
  {
    const uint4* p0 = WB + (size_t)(wv * 10) * 64 + lane;
    const uint4* p1 = WB + (size_t)((wv + 8) * 10) * 64 + lane;
    const uint4* p2 = WB + (size_t)((wv + 16) * 10) * 64 + lane;
#pragma unroll
    for (int kt = 0; kt < 10; kt++) br0[kt].u = gld16w(p0 + kt * 64);
#pragma unroll
    for (int kt = 0; kt < 10; kt++) br1[kt].u = gld16w(p1 + kt * 64);
#pragma unroll
    for (int kt = 0; kt < 10; kt++) br2[kt].u = gld16w(p2 + kt * 64);
  }
  // --- LDS-resident tiles 24..34 (contiguous in WB): 11*640 uint4 ---
  for (int e = tid; e < 7040; e += 512) bls[e] = WB[24 * 640 + e];
  for (int e = tid; e < 8 * 328; e += 512) hA8[e] = (_Float16)0.f;
  asm volatile("s_waitcnt vmcnt(0)" ::: "memory");
  __builtin_amdgcn_sched_barrier(0);
  __syncthreads();

  // --- t-invariant elementwise indices: e = tid + q*512 -> (m,u) ---
  int gxo[5], gsho[5], hAo[5], ho[5];
  bool act[5];
#pragma unroll
  for (int q = 0; q < 5; q++) {
    int e = tid + q * 512;
    act[q] = (e < 2400);
    int m = act[q] ? (e / 300) : 0;
    int u = act[q] ? (e - m * 300) : 0;
    gxo[q] = (n0 + m) * 1200 + 4 * u;
    gsho[q] = m * 1204 + 4 * u;
    hAo[q] = m * 328 + u;
    ho[q] = (n0 + m) * 300 + u;
  }

  float crs[5] = {0.f, 0.f, 0.f, 0.f, 0.f};

  for (int t = 0; t < 64; t++) {
    const int tg = dirb ? (63 - t) : t;
    const size_t gxstep = (size_t)tg * NB * 1200;

    // prefetch x-gates (interleaved i,f,g,o), consumed post-barrier
    float4 gxv[5];
#pragma unroll
    for (int q = 0; q < 5; q++) {
      gxv[q] = make_float4(0.f, 0.f, 0.f, 0.f);
      if (act[q]) gxv[q] = *(const float4*)(gx + gxstep + gxo[q]);
    }

    // stream preload: first half of first streamed tile (nt = 35+wv)
    uint4 bA[5], bB[5];
#pragma unroll
    for (int kt = 0; kt < 5; kt++)
      bA[kt] = WB[(size_t)((35 + wv) * 10 + kt) * 64 + lane];

    // A fragments (rows 8-15 are zero: no LDS read for lm>=8)
    U4H8 af[10];
#pragma unroll
    for (int kt = 0; kt < 10; kt++) {
      uint4 v = make_uint4(0u, 0u, 0u, 0u);
      if (lm < 8) v = *(const uint4*)&hA8[lm * 328 + kt * 32 + lg * 8];
      af[kt].u = v;
    }

    // register-resident tiles (pure MFMA, hides in-flight stream loads)
    {
      f32x4v a0 = {0.f, 0.f, 0.f, 0.f};
      f32x4v a1 = {0.f, 0.f, 0.f, 0.f};
#pragma unroll
      for (int kt = 0; kt < 5; kt++)
        a0 = __builtin_amdgcn_mfma_f32_16x16x32_f16(af[kt].h, br0[kt].h, a0, 0, 0, 0);
#pragma unroll
      for (int kt = 5; kt < 10; kt++)
        a1 = __builtin_amdgcn_mfma_f32_16x16x32_f16(af[kt].h, br0[kt].h, a1, 0, 0, 0);
      if (lg < 2) {
        int col = wv * 16 + lm;
#pragma unroll
        for (int r = 0; r < 4; r++)
          gsh[(lg * 4 + r) * 1204 + col] = a0[r] + a1[r];
      }
    }
    {
      f32x4v a0 = {0.f, 0.f, 0.f, 0.f};
      f32x4v a1 = {0.f, 0.f, 0.f, 0.f};
#pragma unroll
      for (int kt = 0; kt < 5; kt++)
        a0 = __builtin_amdgcn_mfma_f32_16x16x32_f16(af[kt].h, br1[kt].h, a0, 0, 0, 0);
#pragma unroll
      for (int kt = 5; kt < 10; kt++)
        a1 = __builtin_amdgcn_mfma_f32_16x16x32_f16(af[kt].h, br1[kt].h, a1, 0, 0, 0);
      if (lg < 2) {
        int col = (wv + 8) * 16 + lm;
#pragma unroll
        for (int r = 0; r < 4; r++)
          gsh[(lg * 4 + r) * 1204 + col] = a0[r] + a1[r];
      }
    }
    {
      f32x4v a0 = {0.f, 0.f, 0.f, 0.f};
      f32x4v a1 = {0.f, 0.f, 0.f, 0.f};
#pragma unroll
      for (int kt = 0; kt < 5; kt++)
        a0 = __builtin_amdgcn_mfma_f32_16x16x32_f16(af[kt].h, br2[kt].h, a0, 0, 0, 0);
#pragma unroll
      for (int kt = 5; kt < 10; kt++)
        a1 = __builtin_amdgcn_mfma_f32_16x16x32_f16(af[kt].h, br2[kt].h, a1, 0, 0, 0);
      if (lg < 2) {
        int col = (wv + 16) * 16 + lm;
#pragma unroll
        for (int r = 0; r < 4; r++)
          gsh[(lg * 4 + r) * 1204 + col] = a0[r] + a1[r];
      }
    }

    // streamed tiles nt = 35+wv+8i (5 per wave), half-tile-ahead prefetch
#pragma unroll 1
    for (int i = 0; i < 5; i++) {
      int nt = 35 + wv + 8 * i;
#pragma unroll
      for (int kt = 0; kt < 5; kt++)
        bB[kt] = WB[(size_t)(nt * 10 + 5 + kt) * 64 + lane];
      f32x4v a0 = {0.f, 0.f, 0.f, 0.f};
#pragma unroll
      for (int kt = 0; kt < 5; kt++) {
        U4H8 bb; bb.u = bA[kt];
        a0 = __builtin_amdgcn_mfma_f32_16x16x32_f16(af[kt].h, bb.h, a0, 0, 0, 0);
      }
      if (i + 1 < 5) {
#pragma unroll
        for (int kt = 0; kt < 5; kt++)
          bA[kt] = WB[(size_t)((nt + 8) * 10 + kt) * 64 + lane];
      }
      f32x4v a1 = {0.f, 0.f, 0.f, 0.f};
#pragma unroll
      for (int kt = 0; kt < 5; kt++) {
        U4H8 bb; bb.u = bB[kt];
        a1 = __builtin_amdgcn_mfma_f32_16x16x32_f16(af[5 + kt].h, bb.h, a1, 0, 0, 0);
      }
      if (lg < 2) {
        int col = nt * 16 + lm;
#pragma unroll
        for (int r = 0; r < 4; r++)
          gsh[(lg * 4 + r) * 1204 + col] = a0[r] + a1[r];
      }
    }

    // LDS-resident tiles: nt = 24+wv (all waves) and 32+wv (waves 0-2)
#pragma unroll 1
    for (int li = 0; li < 2; li++) {
      int idxL = li == 0 ? wv : (8 + wv);
      if (li == 1 && wv >= 3) break;
      const uint4* bt = &bls[idxL * 640];
      f32x4v a0 = {0.f, 0.f, 0.f, 0.f};
      f32x4v a1 = {0.f, 0.f, 0.f, 0.f};
#pragma unroll
      for (int kt = 0; kt < 5; kt++) {
        U4H8 bb; bb.u = bt[kt * 64 + lane];
        a0 = __builtin_amdgcn_mfma_f32_16x16x32_f16(af[kt].h, bb.h, a0, 0, 0, 0);
      }
#pragma unroll
      for (int kt = 5; kt < 10; kt++) {
        U4H8 bb; bb.u = bt[kt * 64 + lane];
        a1 = __builtin_amdgcn_mfma_f32_16x16x32_f16(af[kt].h, bb.h, a1, 0, 0, 0);
      }
      if (lg < 2) {
        int col = (24 + idxL) * 16 + lm;
#pragma unroll
        for (int r = 0; r < 4; r++)
          gsh[(lg * 4 + r) * 1204 + col] = a0[r] + a1[r];
      }
    }
    __syncthreads();

    // elementwise: gates contiguous in gsh & gx (col' = 4u+gate)
#pragma unroll
    for (int q = 0; q < 5; q++) {
      if (act[q]) {
        const float4 gs = *(const float4*)&gsh[gsho[q]];
        float gi = gxv[q].x + gs.x;
        float gf = gxv[q].y + gs.y;
        float gg = gxv[q].z + gs.z;
        float go = gxv[q].w + gs.w;
        float si = fsig(gi);
        float sf = fsig(gf);
        float so = fsig(go);
        float cc = sf * crs[q] + si * ftanh(gg);
        float h = so * ftanh(cc);
        crs[q] = cc;
        hA8[hAo[q]] = (_Float16)h;
        if (hist) hist[(size_t)tg * NB * 300 + ho[q]] = h;
        if (hfin && t == 63) hfin[(size_t)dirb * NB * 300 + ho[q]] = h;
      }
    }
    __syncthreads();
  }
}

// ---------------------------------------------------------------------------
__global__ void embed_kernel(
    const int* __restrict__ prem, const int* __restrict__ hyp,
    const float* __restrict__ embW, float* __restrict__ comb)
{
  size_t i = (size_t)blockIdx.x * 256 + threadIdx.x;
  if (i >= (size_t)64 * 256 * 75) return;
  int d4 = (int)(i % 75);
  size_t r = i / 75;
  int n = (int)(r % 256);
  int t = (int)(r / 256);
  int id = (n < 128) ? prem[t * 128 + n] : hyp[t * 128 + (n - 128)];
  float4 v = *(const float4*)(embW + (size_t)id * 300 + d4 * 4);
  *(float4*)(comb + ((size_t)t * 256 + n) * 300 + d4 * 4) = v;
}

// ---------------------------------------------------------------------------
// norm4 (ORIGINAL rounds-0..6 version, RESTORED): weighted norms per
// (dir,t,n,l) + plain row norms. Round-9's "v2" (persistent per (n,dir),
// W^2 in LDS) was a 8x REGRESSION (761us, 23.6M bank-conflicts): it turned
// distributed L2 bandwidth (32768 blocks, mp_W L2-resident, 34.5TB/s
// aggregate) into serialized LDS throughput (1 blk/CU, 2 LDS reads/FLOP,
// one LDS pipe). Lesson: LDS staging only pays when it removes an
// uncached/contended path.
// ---------------------------------------------------------------------------
__global__ __launch_bounds__(320) void norm4_kernel(
    const float* __restrict__ hs_fw, const float* __restrict__ hs_bw,
    const float* __restrict__ mp_W,
    float* __restrict__ nm4, float* __restrict__ pnorm)
{
  const int t = blockIdx.x, n = blockIdx.y, dir = blockIdx.z;
  const float* HS = dir ? hs_bw : hs_fw;
  const float* row = HS + ((size_t)t * 256 + n) * 300;
  __shared__ float sh[300];
  const int tid = threadIdx.x, g = tid >> 4, lane = tid & 15;
  for (int k = tid; k < 300; k += 320) sh[k] = row[k];
  __syncthreads();
  if (g == 0) {
    float s2 = 0.f;
    for (int k = lane; k < 300; k += 16) { float x = sh[k]; s2 += x * x; }
    for (int o = 8; o; o >>= 1) s2 += __shfl_down(s2, o, 16);
    if (lane == 0) pnorm[((size_t)dir * 64 + t) * 256 + n] = sqrtf(s2);
  }
#pragma unroll
  for (int wset = 0; wset < 4; wset++) {
    const float* W = mp_W + dir * 24000 + wset * 6000 + g * 300;
    float s1 = 0.f;
    for (int k = lane; k < 300; k += 16) {
      float x = sh[k];
      float w = W[k];
      s1 += x * x * w * w;
    }
    for (int o = 8; o; o >>= 1) s1 += __shfl_down(s1, o, 16);
    if (lane == 0)
      nm4[((((size_t)dir * 4 + wset) * 64 + t) * 256 + n) * 20 + g] = sqrtf(s1);
  }
}

// ---------------------------------------------------------------------------
// att: per (b,z), att[64,64] cosine GEMM -> normalized w (watt) + argmax idx.
// ---------------------------------------------------------------------------
__global__ __launch_bounds__(256) void att_kernel(
    const float* __restrict__ hs_fw, const float* __restrict__ hs_bw,
    const float* __restrict__ pnorm,
    float* __restrict__ watt, int* __restrict__ idxbuf)
{
  const int b = blockIdx.x, z = blockIdx.y;
  const int dir = z & 1;
  const float* HS = dir ? hs_bw : hs_fw;
  const int p_n = (z < 2) ? b : 128 + b;
  const int h_n = (z < 2) ? 128 + b : b;
  const float* pnD = pnorm + (size_t)dir * 16384;

  __shared__ float pch[64 * 100];
  __shared__ float hch[64 * 100];
  __shared__ float att[64 * 65];
  __shared__ float winv_sh[64];

  const int tid = threadIdx.x;
  const int i = tid >> 4, j = tid & 15;
  float acc[4][4];
#pragma unroll
  for (int a = 0; a < 4; a++)
#pragma unroll
    for (int c = 0; c < 4; c++) acc[a][c] = 0.f;

  for (int kc = 0; kc < 300; kc += 100) {
    for (int e = tid; e < 1600; e += 256) {
      int row = e / 25, kq = e - row * 25;
      float4 v = *(const float4*)(HS + ((size_t)row * 256 + p_n) * 300 + kc + kq * 4);
      *(float4*)&pch[row * 100 + kq * 4] = v;
      float4 w = *(const float4*)(HS + ((size_t)row * 256 + h_n) * 300 + kc + kq * 4);
      *(float4*)&hch[row * 100 + kq * 4] = w;
    }
    __syncthreads();
#pragma unroll 5
    for (int kq = 0; kq < 25; kq++) {
      float4 av[4], bv[4];
#pragma unroll
      for (int a = 0; a < 4; a++) av[a] = *(const float4*)&pch[(i + 16 * a) * 100 + kq * 4];
#pragma unroll
      for (int c = 0; c < 4; c++) bv[c] = *(const float4*)&hch[(j + 16 * c) * 100 + kq * 4];
#pragma unroll
      for (int a = 0; a < 4; a++)
#pragma unroll
        for (int c = 0; c < 4; c++)
          acc[a][c] += av[a].x * bv[c].x + av[a].y * bv[c].y + av[a].z * bv[c].z + av[a].w * bv[c].w;
    }
    __syncthreads();
  }

#pragma unroll
  for (int a = 0; a < 4; a++) {
    int t = i + 16 * a;
    float pn = pnD[t * 256 + p_n] + EPSF;
#pragma unroll
    for (int c = 0; c < 4; c++) {
      int s = j + 16 * c;
      float hn = pnD[s * 256 + h_n] + EPSF;
      att[t * 65 + s] = acc[a][c] / (pn * hn);
    }
  }
  __syncthreads();
  if (tid < 64) {
    int t = tid;
    float ssum = 0.f, mx = -1e30f; int mi = 0;
    for (int s = 0; s < 64; s++) {
      float a = att[t * 65 + s];
      ssum += a;
      if (a > mx) { mx = a; mi = s; }
    }
    winv_sh[t] = 1.f / (ssum + EPSF);
    idxbuf[((size_t)z * 128 + b) * 64 + t] = mi;
  }
  __syncthreads();
  for (int e = tid; e < 4096; e += 256) {
    int t = e >> 6, s = e & 63;
    watt[((size_t)z * 128 + b) * 4096 + t * 64 + s] = att[t * 65 + s] * winv_sh[t];
  }
}

// ---------------------------------------------------------------------------
// hmean: per (b,z): hmean[t,k] = sum_s w[t,s]*h[s,k]
// ---------------------------------------------------------------------------
__global__ __launch_bounds__(256) void hmean_kernel(
    const float* __restrict__ hs_fw, const float* __restrict__ hs_bw,
    const float* __restrict__ watt, float* __restrict__ hmeanbuf)
{
  const int b = blockIdx.x, z = blockIdx.y;
  const int dir = z & 1;
  const float* HS = dir ? hs_bw : hs_fw;
  const int h_n = (z < 2) ? 128 + b : b;

  __shared__ float wsh[64 * 65];
  __shared__ float hch[64 * 128];

  const int tid = threadIdx.x;
  const int ti = tid >> 4, kj = tid & 15;
  const float* wsrc = watt + ((size_t)z * 128 + b) * 4096;
  for (int e = tid; e < 4096; e += 256) {
    int t = e >> 6, s = e & 63;
    wsh[t * 65 + s] = wsrc[t * 64 + s];
  }

  for (int kbase = 0; kbase < 300; kbase += 128) {
    int kw = min(128, 300 - kbase);
    int nf4 = kw >> 2;  // 32,32,11
    __syncthreads();
    for (int e = tid; e < 64 * nf4; e += 256) {
      int row = e / nf4, q = e - row * nf4;
      float4 v = *(const float4*)(HS + ((size_t)row * 256 + h_n) * 300 + kbase + q * 4);
      *(float4*)&hch[row * 128 + q * 4] = v;
    }
    __syncthreads();
    float acc[4][8];
#pragma unroll
    for (int a = 0; a < 4; a++)
#pragma unroll
      for (int c = 0; c < 8; c++) acc[a][c] = 0.f;
    for (int s = 0; s < 64; s++) {
      float4 h0 = *(const float4*)&hch[s * 128 + 4 * kj];
      float4 h1 = *(const float4*)&hch[s * 128 + 4 * (kj + 16)];
#pragma unroll
      for (int a = 0; a < 4; a++) {
        float w = wsh[(4 * ti + a) * 65 + s];
        acc[a][0] += w * h0.x; acc[a][1] += w * h0.y; acc[a][2] += w * h0.z; acc[a][3] += w * h0.w;
        acc[a][4] += w * h1.x; acc[a][5] += w * h1.y; acc[a][6] += w * h1.z; acc[a][7] += w * h1.w;
      }
    }
#pragma unroll
    for (int a = 0; a < 4; a++) {
      int t = 4 * ti + a;
#pragma unroll
      for (int c = 0; c < 2; c++) {
        int kq = kj + 16 * c;
        if (kq * 4 < kw) {
          int k = kbase + kq * 4;
          float4 v = make_float4(acc[a][4 * c], acc[a][4 * c + 1], acc[a][4 * c + 2], acc[a][4 * c + 3]);
          *(float4*)&hmeanbuf[(((size_t)z * 128 + b) * 64 + t) * 300 + k] = v;
        }
      }
    }
  }
}

// ---------------------------------------------------------------------------
// maxp via MFMA f16 (round-5 WIN): per (b,z) ONE block; x = l*64+t tiling;
// A-frag = p-frag (*) w2[l]-frag; h-frags reg-cached per st-pair.
// ---------------------------------------------------------------------------
#define MAXP_LDS_BYTES (41984 + 41984 + 13120 + 5120 + 5120)  // 107,328

__global__ __launch_bounds__(512, 2) void maxp_mfma(
    const float* __restrict__ hs_fw, const float* __restrict__ hs_bw,
    const float* __restrict__ mp_W, const float* __restrict__ nm4,
    float* __restrict__ m_out)
{
  extern __shared__ char smem[];
  _Float16* pA = (_Float16*)smem;                     // [64][328]
  _Float16* hB = (_Float16*)(smem + 41984);           // [64][328]
  _Float16* w2h = (_Float16*)(smem + 83968);          // [20][328]
  float* pn_sh = (float*)(smem + 97088);              // [64][20]
  float* hn_sh = (float*)(smem + 102208);             // [64][20]

  const int b = blockIdx.x, z = blockIdx.y;
  const int dir = z & 1;
  const float* HS = dir ? hs_bw : hs_fw;
  const int p_n = (z < 2) ? b : 128 + b;
  const int h_n = (z < 2) ? 128 + b : b;
  const float* Wm = mp_W + dir * 24000 + 6000;
  const float* nmD = nm4 + ((size_t)dir * 4 + 1) * 327680;

  const int tid = threadIdx.x;
  const int wv = tid >> 6, lane = tid & 63;
  const int lm = lane & 15, lg = lane >> 4;

  // ---- stage p, h (f32->f16), w2 (squared f16), pn, hn ----
  for (int e = tid; e < 4800; e += 512) {
    int row = e / 75, q = e - row * 75;
    float4 v = *(const float4*)(HS + ((size_t)row * 256 + p_n) * 300 + q * 4);
    float4 w = *(const float4*)(HS + ((size_t)row * 256 + h_n) * 300 + q * 4);
    _Float16* pd = &pA[row * 328 + q * 4];
    pd[0] = (_Float16)v.x; pd[1] = (_Float16)v.y; pd[2] = (_Float16)v.z; pd[3] = (_Float16)v.w;
    _Float16* hd = &hB[row * 328 + q * 4];
    hd[0] = (_Float16)w.x; hd[1] = (_Float16)w.y; hd[2] = (_Float16)w.z; hd[3] = (_Float16)w.w;
  }
  for (int e = tid; e < 64 * 28; e += 512) {
    int row = e / 28, c = 300 + (e - row * 28);
    pA[row * 328 + c] = (_Float16)0.f;
    hB[row * 328 + c] = (_Float16)0.f;
  }
  for (int e = tid; e < 1500; e += 512) {
    int row = e / 75, q = e - row * 75;
    float4 w = *(const float4*)(Wm + (size_t)row * 300 + q * 4);
    _Float16* d = &w2h[row * 328 + q * 4];
    d[0] = (_Float16)(w.x * w.x); d[1] = (_Float16)(w.y * w.y);
    d[2] = (_Float16)(w.z * w.z); d[3] = (_Float16)(w.w * w.w);
  }
  for (int e = tid; e < 20 * 28; e += 512) {
    int row = e / 28, c = 300 + (e - row * 28);
    w2h[row * 328 + c] = (_Float16)0.f;
  }
  for (int e = tid; e < 1280; e += 512) {
    int tq = e / 20, l = e - tq * 20;
    pn_sh[e] = nmD[((size_t)tq * 256 + p_n) * 20 + l];
    hn_sh[e] = nmD[((size_t)tq * 256 + h_n) * 20 + l];
  }
  __syncthreads();

  // ---- compute: wave wv owns x-tiles xt = wv + 8i (10 tiles) ----
  float rmax[10][4];
#pragma unroll
  for (int i = 0; i < 10; i++)
#pragma unroll
    for (int r = 0; r < 4; r++) rmax[i][r] = -1e30f;

#pragma unroll
  for (int sp = 0; sp < 2; sp++) {       // st pairs {0,1},{2,3}
    U4H8 hf[2][10];
#pragma unroll
    for (int hh = 0; hh < 2; hh++)
#pragma unroll
      for (int kt = 0; kt < 10; kt++)
        hf[hh][kt].u = *(const uint4*)&hB[(sp * 32 + hh * 16 + lm) * 328 + kt * 32 + lg * 8];

#pragma unroll
    for (int i = 0; i < 10; i++) {
      int xt = wv + 8 * i;               // 0..79
      int l = xt >> 2, t0 = (xt & 3) << 4;
      U4H8 af[10];
#pragma unroll
      for (int kt = 0; kt < 10; kt++) {
        U4H8 pf, wf;
        pf.u = *(const uint4*)&pA[(t0 + lm) * 328 + kt * 32 + lg * 8];
        wf.u = *(const uint4*)&w2h[l * 328 + kt * 32 + lg * 8];
        af[kt].h = pf.h * wf.h;          // v_pk_mul_f16
      }
      float pnv[4];
#pragma unroll
      for (int r = 0; r < 4; r++) pnv[r] = pn_sh[(t0 + lg * 4 + r) * 20 + l];
#pragma unroll
      for (int hh = 0; hh < 2; hh++) {
        int st = sp * 2 + hh;
        f32x4v acc = {0.f, 0.f, 0.f, 0.f};
#pragma unroll
        for (int kt = 0; kt < 10; kt++)
          acc = __builtin_amdgcn_mfma_f32_16x16x32_f16(af[kt].h, hf[hh][kt].h, acc, 0, 0, 0);
        float hn = hn_sh[(st * 16 + lm) * 20 + l];
#pragma unroll
        for (int r = 0; r < 4; r++) {
          float val = acc[r] * __builtin_amdgcn_rcpf(pnv[r] * hn + EPSF);
          rmax[i][r] = fmaxf(rmax[i][r], val);
        }
      }
    }
  }

  // ---- cross-lane max over s (16-lane groups) + write ----
#pragma unroll
  for (int i = 0; i < 10; i++) {
    int xt = wv + 8 * i;
    int l = xt >> 2, t0 = (xt & 3) << 4;
#pragma unroll
    for (int r = 0; r < 4; r++) {
      float v = rmax[i][r];
#pragma unroll
      for (int off = 8; off; off >>= 1) v = fmaxf(v, __shfl_down(v, off, 16));
      if (lm == 0) {
        int t = t0 + lg * 4 + r;
        m_out[((size_t)t * 128 + b) * 320 + z * 80 + 20 + l] = v;
      }
    }
  }
}

// ---------------------------------------------------------------------------
// rest: per (b,z): full / attm / maxattm for all t. W^2 staged once in LDS.
// ---------------------------------------------------------------------------
__global__ __launch_bounds__(320) void rest_kernel(
    const float* __restrict__ hs_fw, const float* __restrict__ hs_bw,
    const float* __restrict__ mp_W, const float* __restrict__ nm4,
    const float* __restrict__ hmeanbuf, const int* __restrict__ idxbuf,
    float* __restrict__ m_out)
{
  const int b = blockIdx.x, z = blockIdx.y;
  const int dir = z & 1;
  const float* HS = dir ? hs_bw : hs_fw;
  const int p_n = (z < 2) ? b : 128 + b;
  const int h_n = (z < 2) ? 128 + b : b;
  const int v_t = dir ? 0 : 63;

  __shared__ float w2f[6000], w2a[6000], w2m[6000];
  __shared__ float vsh[300], psh[300], hmsh[300], hxsh[300];

  const int tid = threadIdx.x;
  const int g = tid >> 4, lane = tid & 15;
  const float* Wf = mp_W + dir * 24000;
  const float* Wa = Wf + 12000;
  const float* Wma = Wf + 18000;
  for (int e = tid; e < 6000; e += 320) {
    float a = Wf[e], bb = Wa[e], c = Wma[e];
    w2f[e] = a * a; w2a[e] = bb * bb; w2m[e] = c * c;
  }
  for (int e = tid; e < 300; e += 320)
    vsh[e] = HS[((size_t)v_t * 256 + h_n) * 300 + e];
  __syncthreads();

  const float* base0 = nm4 + ((size_t)dir * 4 + 0) * 327680;
  const float* base2 = nm4 + ((size_t)dir * 4 + 2) * 327680;
  const float* base3 = nm4 + ((size_t)dir * 4 + 3) * 327680;
  const float vnf = base0[((size_t)v_t * 256 + h_n) * 20 + g];

  for (int t = 0; t < 64; t++) {
    int idx = idxbuf[((size_t)z * 128 + b) * 64 + t];
    __syncthreads();
    for (int e = tid; e < 300; e += 320) {
      psh[e] = HS[((size_t)t * 256 + p_n) * 300 + e];
      hmsh[e] = hmeanbuf[(((size_t)z * 128 + b) * 64 + t) * 300 + e];
      hxsh[e] = HS[((size_t)idx * 256 + h_n) * 300 + e];
    }
    __syncthreads();
    float nf = 0.f, na = 0.f, qa = 0.f, nm = 0.f;
#pragma unroll
    for (int c = 0; c < 5; c++) {
      int k4 = lane + 16 * c;
      if (k4 < 75) {
        float4 p = *(const float4*)&psh[4 * k4];
        float4 v = *(const float4*)&vsh[4 * k4];
        float4 hm = *(const float4*)&hmsh[4 * k4];
        float4 hx = *(const float4*)&hxsh[4 * k4];
        float4 wf = *(const float4*)&w2f[g * 300 + 4 * k4];
        float4 wa = *(const float4*)&w2a[g * 300 + 4 * k4];
        float4 wm = *(const float4*)&w2m[g * 300 + 4 * k4];
        nf += p.x * v.x * wf.x + p.y * v.y * wf.y + p.z * v.z * wf.z + p.w * v.w * wf.w;
        na += p.x * hm.x * wa.x + p.y * hm.y * wa.y + p.z * hm.z * wa.z + p.w * hm.w * wa.w;
        qa += hm.x * hm.x * wa.x + hm.y * hm.y * wa.y + hm.z * hm.z * wa.z + hm.w * hm.w * wa.w;
        nm += p.x * hx.x * wm.x + p.y * hx.y * wm.y + p.z * hx.z * wm.z + p.w * hx.w * wm.w;
      }
    }
#pragma unroll
    for (int o = 8; o; o >>= 1) {
      nf += __shfl_down(nf, o);
      na += __shfl_down(na, o);
      qa += __shfl_down(qa, o);
      nm += __shfl_down(nm, o);
    }
    if (lane == 0) {
      float pnf = base0[((size_t)t * 256 + p_n) * 20 + g];
      float pna = base2[((size_t)t * 256 + p_n) * 20 + g];
      float pnm = base3[((size_t)t * 256 + p_n) * 20 + g];
      float qnm = base3[((size_t)idx * 256 + h_n) * 20 + g];
      float* mrow = m_out + ((size_t)t * 128 + b) * 320 + z * 80;
      mrow[g] = nf / (pnf * vnf + EPSF);
      mrow[40 + g] = na / (pna * sqrtf(qa) + EPSF);
      mrow[60 + g] = nm / (pnm * qnm + EPSF);
    }
  }
}

// ---------------------------------------------------------------------------
__global__ __launch_bounds__(256) void mlp_kernel(
    const float* __restrict__ shA0, const float* __restrict__ shA1,
    const float* __restrict__ bnG, const float* __restrict__ bnB,
    const float* __restrict__ W1, const float* __restrict__ b1,
    const float* __restrict__ W2, const float* __restrict__ b2,
    const float* __restrict__ outW, const float* __restrict__ outb,
    float* __restrict__ out)
{
  const int b = blockIdx.x;
  const int tid = threadIdx.x;
  __shared__ float x0[600], x1[600];
  const float inv = 1.0f / sqrtf(1.0f + 1e-5f);
  for (int j = tid; j < 600; j += 256) {
    float v = (j < 300) ? shA0[b * 300 + j] : shA1[b * 300 + (j - 300)];
    x0[j] = bnG[j] * v * inv + bnB[j];
  }
  __syncthreads();
  for (int j = tid; j < 600; j += 256) {
    float acc = b1[j];
    const float* w = W1 + (size_t)j * 600;
    for (int k = 0; k < 600; k++) acc += x0[k] * w[k];
    float r = fmaxf(acc, 0.f);
    x1[j] = bnG[600 + j] * r * inv + bnB[600 + j];
  }
  __syncthreads();
  for (int j = tid; j < 600; j += 256) {
    float acc = b2[j];
    const float* w = W2 + (size_t)j * 600;
    for (int k = 0; k < 600; k++) acc += x1[k] * w[k];
    float r = fmaxf(acc, 0.f);
    x0[j] = bnG[1200 + j] * r * inv + bnB[1200 + j];
  }
  __syncthreads();
  if (tid < 3) {
    float acc = outb[tid];
    const float* w = outW + tid * 600;
    for (int k = 0; k < 600; k++) acc += x0[k] * w[k];
    out[b * 3 + tid] = acc;
  }
}

// ---------------------------------------------------------------------------
extern "C" void kernel_launch(void* const* d_in, const int* in_sizes, int n_in,
                              void* d_out, int out_size, void* d_ws, size_t ws_size,
                              hipStream_t stream) {
  const int* premise = (const int*)d_in[0];
  const int* hypothesis = (const int*)d_in[1];
  const float* embW = (const float*)d_in[2];
  const float* cWih = (const float*)d_in[3];
  const float* cWhh = (const float*)d_in[4];
  const float* cb = (const float*)d_in[5];
  const float* mpW = (const float*)d_in[6];
  const float* aWihF = (const float*)d_in[7];
  const float* aWhhF = (const float*)d_in[8];
  const float* abF = (const float*)d_in[9];
  const float* aWihB = (const float*)d_in[10];
  const float* aWhhB = (const float*)d_in[11];
  const float* abB = (const float*)d_in[12];
  const float* bnG = (const float*)d_in[13];
  const float* bnB = (const float*)d_in[14];
  const float* W1 = (const float*)d_in[15];
  const float* b1 = (const float*)d_in[16];
  const float* W2 = (const float*)d_in[17];
  const float* b2 = (const float*)d_in[18];
  const float* outW = (const float*)d_in[19];
  const float* outb = (const float*)d_in[20];
  float* out = (float*)d_out;

  float* ws = (float*)d_ws;
  // workspace layout (floats)
  float* comb  = ws + 0;           // 4,915,200  (T,256,300); WB packs + aWih perms overlay after ctx-gates GEMM
  float* gates = ws + 4915200;     // 19,660,800 (T,256,1200); overlaid after ctx LSTM
  float* hsfw  = ws + 24576000;    // 4,915,200  (cWih perm overlays here pre-LSTM)
  float* hsbw  = ws + 29491200;    // 4,915,200
  float* pnorm = ws + 34406400;    // 32,768    [2][64][256]
  float* mbuf  = ws + 35094528;    // 2,621,440 (T,128,320)
  float* sha   = ws + 38023168;    // 76,800    agg final h [2][128][300]

  // packed MFMA B-fragment weights overlay in comb region (dead after ctx-gates GEMM)
  uint4* WBctx = (uint4*)comb;
  uint4* WBaf  = (uint4*)(comb + 192000);
  uint4* WBab  = (uint4*)(comb + 384000);
  // gate-interleaved agg input weights (dead comb region, after WB packs)
  float* aWihFP = comb + 576000;   // 384,000
  float* aWihBP = comb + 960000;   // 384,000
  float* abFP   = comb + 1344000;  // 1,200
  float* abBP   = comb + 1345200;  // 1,200

  // gate-interleaved ctx input weights: hsfw region is dead until ctx LSTM
  float* cWihP = hsfw;             // 360,000
  float* cbP   = hsfw + 360000;    // 1,200

  // overlays inside the dead ctx-gates region (valid between ctx LSTM and agg GEMMs)
  float* watt     = gates;                 // 2,097,152 [4][128][64][64]
  float* hmeanbuf = gates + 2097152;       // 9,830,400 [4][128][64][300]
  int*   idxbuf   = (int*)(gates + 11927552); // 32,768 [4][128][64]
  float* nm4      = gates + 11960320;      // 2,621,440 [2][4][64][256][20]

  // allow >64KB dynamic LDS (gfx950 pool = 160KB/WG)
  hipFuncSetAttribute((const void*)lstm_res,
                      hipFuncAttributeMaxDynamicSharedMemorySize, LSTM_LDS_BYTES);
  hipFuncSetAttribute((const void*)maxp_mfma,
                      hipFuncAttributeMaxDynamicSharedMemorySize, MAXP_LDS_BYTES);
  hipFuncSetAttribute((const void*)gemm_mfma_nt,
                      hipFuncAttributeMaxDynamicSharedMemorySize, GMM_LDS_BYTES);

  // 1) embed + ctx input-weight gate-interleave
  embed_kernel<<<dim3(4800), dim3(256), 0, stream>>>(premise, hypothesis, embW, comb);
  permW_kernel<<<dim3(1200), dim3(256), 0, stream>>>(cWih, cb, cWihP, cbP, 300);

  // 2) ctx input gates (consumes comb) — split-f16 MFMA, fp32-grade accuracy
  gemm_mfma_nt<<<dim3(5, 128), dim3(512), GMM_LDS_BYTES, stream>>>(
      comb, cWihP, cbP, gates, 16384, 300);

  // 3) pack recurrent weights into MFMA B-fragment stream (dead comb region)
  //    + gate-interleave the agg input weights
  packB_kernel<<<dim3(188, 3), dim3(256), 0, stream>>>(
      cWhh, aWhhF, aWhhB, WBctx, WBaf, WBab);
  permW_kernel<<<dim3(1200), dim3(256), 0, stream>>>(aWihF, abF, aWihFP, abFP, 320);
  permW_kernel<<<dim3(1200), dim3(256), 0, stream>>>(aWihB, abB, aWihBP, abBP, 320);

  // 4) context LSTM: 24 reg + 11 LDS tiles resident, 40 streamed
  lstm_res<<<dim3(64), dim3(512), LSTM_LDS_BYTES, stream>>>(
      WBctx, WBctx, gates, gates, hsfw, hsbw, nullptr, 256);

  // 5) norms (all 4 W sets) + plain norms — ORIGINAL distributed version
  norm4_kernel<<<dim3(64, 256, 2), dim3(320), 0, stream>>>(hsfw, hsbw, mpW, nm4, pnorm);

  // 6) matching pipeline
  att_kernel<<<dim3(128, 4), dim3(256), 0, stream>>>(hsfw, hsbw, pnorm, watt, idxbuf);
  hmean_kernel<<<dim3(128, 4), dim3(256), 0, stream>>>(hsfw, hsbw, watt, hmeanbuf);
  maxp_mfma<<<dim3(128, 4), dim3(512), MAXP_LDS_BYTES, stream>>>(
      hsfw, hsbw, mpW, nm4, mbuf);
  rest_kernel<<<dim3(128, 4), dim3(320), 0, stream>>>(hsfw, hsbw, mpW, nm4, hmeanbuf, idxbuf, mbuf);

  // 7) agg input gates — split-f16 MFMA, gate-interleaved columns
  float* gaf = gates;
  float* gab = gates + 9830400;
  gemm_mfma_nt<<<dim3(5, 64), dim3(512), GMM_LDS_BYTES, stream>>>(
      mbuf, aWihFP, abFP, gaf, 8192, 320);
  gemm_mfma_nt<<<dim3(5, 64), dim3(512), GMM_LDS_BYTES, stream>>>(
      mbuf, aWihBP, abBP, gab, 8192, 320);

  // 8) aggregation LSTM: 32 blocks (16/dir), 8 waves
  lstm_res<<<dim3(32), dim3(512), LSTM_LDS_BYTES, stream>>>(
      WBaf, WBab, gaf, gab, nullptr, nullptr, sha, 128);

  // 9) MLP head
  mlp_kernel<<<dim3(128), dim3(256), 0, stream>>>(
      sha, sha + 38400, bnG, bnB, W1, b1, W2, b2, outW, outb, out);
}

// Round 11
// 1993.503 us; speedup vs baseline: 1.2063x; 1.0992x over previous
//
#include <hip/hip_runtime.h>
#include <cstddef>
#include <cstdint>
#include <math.h>

#define EPSF 1e-8f

// Model dims (fixed): T=64, B=128, D=300, H=300, L=20, AH=300, N2=2B=256

typedef _Float16 half8v __attribute__((ext_vector_type(8)));
typedef float f32x4v __attribute__((ext_vector_type(4)));
union U4H8 { uint4 u; half8v h; _Float16 e[8]; };

// fast device math: v_exp_f32 + v_rcp_f32 (rel err ~1e-7, fine for 3e-3 budget)
__device__ __forceinline__ float fsig(float x) {
  float e = __expf(-x);
  return __builtin_amdgcn_rcpf(1.f + e);
}
__device__ __forceinline__ float ftanh(float x) {
  float e = __expf(-2.f * fabsf(x));
  float r = (1.f - e) * __builtin_amdgcn_rcpf(1.f + e);
  return copysignf(r, x);
}

// asm-opaque 16B load: result cannot be re-materialized by the compiler ->
// forces true register residency. SAFE ONLY at low register pressure:
// 2 tiles/wave (80 pinned VGPR) fits; 3 tiles/wave spills — round-7
// (corrupt: spill before external wait) and round-10 (correct with internal
// wait but slow: scratch re-loads every step, 370->498us). 2 tiles is final.
__device__ __forceinline__ uint4 gld16(const uint4* p) {
  uint4 r;
  asm volatile("global_load_dwordx4 %0, %1, off" : "=v"(r) : "v"(p));
  return r;
}

// ---------------------------------------------------------------------------
// Split-f16 MFMA NT GEMM (round-6 WIN): C = bias + A*B^T, fp32-grade via
// A=Ah+Al, B=Bh+Bl, C ~= AhBh+AlBh+AhBl (dropped AlBl ~2^-22).
// Tile 128x240, N=1200=5x240; 512 thr; LDS pitch-72 hi/lo staging.
// ---------------------------------------------------------------------------
#define GMM_LDS_BYTES (2 * (128 * 72 * 2) + 2 * (240 * 72 * 2))  // 105,984

__global__ __launch_bounds__(512, 1) void gemm_mfma_nt(
    const float* __restrict__ A, const float* __restrict__ B,
    const float* __restrict__ bias, float* __restrict__ C,
    int M, int K)
{
  extern __shared__ char smem[];
  _Float16* Ah = (_Float16*)smem;                       // [128][72]
  _Float16* Al = (_Float16*)(smem + 18432);             // [128][72]
  _Float16* Bh = (_Float16*)(smem + 36864);             // [240][72]
  _Float16* Bl = (_Float16*)(smem + 36864 + 34560);     // [240][72]

  const int tid = threadIdx.x;
  const int wv = tid >> 6, lane = tid & 63;
  const int lm = lane & 15, lg = lane >> 4;
  const int mbase = blockIdx.y << 7;
  const int nbase = blockIdx.x * 240;

  f32x4v acc[15];
#pragma unroll
  for (int nt = 0; nt < 15; nt++) acc[nt] = (f32x4v){0.f, 0.f, 0.f, 0.f};

  const int nchunk = (K + 63) >> 6;
  for (int c = 0; c < nchunk; c++) {
    const int kc = c << 6;
    // stage A 128x64 -> hi/lo f16
    for (int e = tid; e < 2048; e += 512) {
      int row = e >> 4, q = e & 15;
      int k = kc + q * 4;
      const float* src = A + (size_t)(mbase + row) * K;
      float4 v = make_float4(0.f, 0.f, 0.f, 0.f);
      if (k + 4 <= K) {
        v = *(const float4*)(src + k);
      } else {
        if (k + 0 < K) v.x = src[k + 0];
        if (k + 1 < K) v.y = src[k + 1];
        if (k + 2 < K) v.z = src[k + 2];
        if (k + 3 < K) v.w = src[k + 3];
      }
      _Float16 hx = (_Float16)v.x, hy = (_Float16)v.y,
               hz = (_Float16)v.z, hw = (_Float16)v.w;
      _Float16* d = &Ah[row * 72 + q * 4];
      d[0] = hx; d[1] = hy; d[2] = hz; d[3] = hw;
      _Float16* dl = &Al[row * 72 + q * 4];
      dl[0] = (_Float16)(v.x - (float)hx); dl[1] = (_Float16)(v.y - (float)hy);
      dl[2] = (_Float16)(v.z - (float)hz); dl[3] = (_Float16)(v.w - (float)hw);
    }
    // stage B 240x64 -> hi/lo f16
    for (int e = tid; e < 3840; e += 512) {
      int row = e >> 4, q = e & 15;
      int k = kc + q * 4;
      const float* src = B + (size_t)(nbase + row) * K;
      float4 v = make_float4(0.f, 0.f, 0.f, 0.f);
      if (k + 4 <= K) {
        v = *(const float4*)(src + k);
      } else {
        if (k + 0 < K) v.x = src[k + 0];
        if (k + 1 < K) v.y = src[k + 1];
        if (k + 2 < K) v.z = src[k + 2];
        if (k + 3 < K) v.w = src[k + 3];
      }
      _Float16 hx = (_Float16)v.x, hy = (_Float16)v.y,
               hz = (_Float16)v.z, hw = (_Float16)v.w;
      _Float16* d = &Bh[row * 72 + q * 4];
      d[0] = hx; d[1] = hy; d[2] = hz; d[3] = hw;
      _Float16* dl = &Bl[row * 72 + q * 4];
      dl[0] = (_Float16)(v.x - (float)hx); dl[1] = (_Float16)(v.y - (float)hy);
      dl[2] = (_Float16)(v.z - (float)hz); dl[3] = (_Float16)(v.w - (float)hw);
    }
    __syncthreads();

#pragma unroll
    for (int kt = 0; kt < 2; kt++) {
      U4H8 ah, al;
      ah.u = *(const uint4*)&Ah[(wv * 16 + lm) * 72 + kt * 32 + lg * 8];
      al.u = *(const uint4*)&Al[(wv * 16 + lm) * 72 + kt * 32 + lg * 8];
#pragma unroll
      for (int nt = 0; nt < 15; nt++) {
        U4H8 bh, bl;
        bh.u = *(const uint4*)&Bh[(nt * 16 + lm) * 72 + kt * 32 + lg * 8];
        bl.u = *(const uint4*)&Bl[(nt * 16 + lm) * 72 + kt * 32 + lg * 8];
        acc[nt] = __builtin_amdgcn_mfma_f32_16x16x32_f16(ah.h, bh.h, acc[nt], 0, 0, 0);
        acc[nt] = __builtin_amdgcn_mfma_f32_16x16x32_f16(al.h, bh.h, acc[nt], 0, 0, 0);
        acc[nt] = __builtin_amdgcn_mfma_f32_16x16x32_f16(ah.h, bl.h, acc[nt], 0, 0, 0);
      }
    }
    __syncthreads();
  }

  // epilogue: D col = nbase+nt*16+lm, row m = mbase+wv*16+lg*4+r
#pragma unroll
  for (int nt = 0; nt < 15; nt++) {
    int col = nbase + nt * 16 + lm;
    float bv = bias[col];
#pragma unroll
    for (int r = 0; r < 4; r++) {
      int m = mbase + wv * 16 + lg * 4 + r;
      C[(size_t)m * 1200 + col] = acc[nt][r] + bv;
    }
  }
}

// ---------------------------------------------------------------------------
// permW: permute Wih rows to gate-interleaved order (row' = 4u+gate).
// ---------------------------------------------------------------------------
__global__ __launch_bounds__(256) void permW_kernel(
    const float* __restrict__ W, const float* __restrict__ bias,
    float* __restrict__ Wp, float* __restrict__ bp, int K)
{
  int r = blockIdx.x;              // 0..1199 = col' = 4u+gate
  int gate = r & 3, u = r >> 2;
  int src = gate * 300 + u;
  const float* s = W + (size_t)src * K;
  float* d = Wp + (size_t)r * K;
  for (int c = threadIdx.x; c < K; c += 256) d[c] = s[c];
  if (threadIdx.x == 0) bp[r] = bias[src];
}

// ---------------------------------------------------------------------------
// packB: W (1200,300) fp32 -> MFMA B-fragment stream for 16x16x32_f16.
// Gate-interleaved column order col' = 4*u + gate  (orig n = gate*300+u).
// Item i = (nt*10+kt)*64 + lane.
// ---------------------------------------------------------------------------
__global__ __launch_bounds__(256) void packB_kernel(
    const float* __restrict__ W0, const float* __restrict__ W1,
    const float* __restrict__ W2,
    uint4* __restrict__ T0, uint4* __restrict__ T1, uint4* __restrict__ T2)
{
  int i = blockIdx.x * 256 + threadIdx.x;
  if (i >= 48000) return;
  const float* W = (blockIdx.y == 0) ? W0 : (blockIdx.y == 1) ? W1 : W2;
  uint4* T = (blockIdx.y == 0) ? T0 : (blockIdx.y == 1) ? T1 : T2;
  int lane = i & 63;
  int tile = i >> 6;               // nt*10 + kt
  int nt = tile / 10, kt = tile - nt * 10;
  int lm = lane & 15, lg = lane >> 4;
  int colp = nt * 16 + lm;
  int u = colp >> 2, gate = colp & 3;
  int n = gate * 300 + u;
  U4H8 v;
#pragma unroll
  for (int j = 0; j < 8; j++) {
    int k = kt * 32 + lg * 8 + j;
    float x = (k < 300) ? W[(size_t)n * 300 + k] : 0.f;
    v.e[j] = (_Float16)x;
  }
  T[i] = v.u;
}

// ---------------------------------------------------------------------------
// Persistent LSTM via MFMA, partial weight residency (round-6 verified
// config, RESTORED — measured 370us/dispatch across three benches):
//   - 16 tiles in REGISTERS (2/wave) via asm-opaque gld16;
//   - 11 tiles in dynamic LDS (nt = 16..26);
//   - 48 tiles streamed (nt = 27+wv+8i, 6/wave), 491KB/step at the
//     ~35 B/cyc/CU L1-fill wall = the structural floor for this schedule.
// 3 tiles/wave is dead: r7 corrupt (spill before wait), r10 slow (spills
// re-loaded from scratch every step, 370->498us).
// LDS: hA8 5.25KB + gsh 38.5KB + bls 112.6KB = 156.4KB.
// ---------------------------------------------------------------------------
#define LSTM_LDS_BYTES (5248 + 38528 + 11 * 10240)   // 156,416

__global__ __launch_bounds__(512, 2) void lstm_res(
    const uint4* WB0, const uint4* WB1,   // packed B-frags; no __restrict__
    const float* __restrict__ gx0, const float* __restrict__ gx1, // (64,NB,1200) interleaved
    float* hist0, float* hist1,           // (64,NB,300) or null; no __restrict__
    float* hfin,                          // (2,NB,300) or null
    int NB)
{
  extern __shared__ char smem[];
  _Float16* hA8 = (_Float16*)smem;                    // [8][328]
  float* gsh = (float*)(smem + 5248);                 // [8][1204]
  uint4* bls = (uint4*)(smem + 5248 + 38528);         // [11][640]

  const int b = blockIdx.x;
  const int xcd = b & 7;
  const int grp = b >> 3;
  const int dirb = xcd >> 2;
  const int n0 = (grp * 4 + (xcd & 3)) * 8;
  const int tid = threadIdx.x;
  const int wv = tid >> 6, lane = tid & 63;
  const int lm = lane & 15, lg = lane >> 4;

  const uint4* WB = dirb ? WB1 : WB0;
  const float* gx = dirb ? gx1 : gx0;
  float* hist = dirb ? hist1 : hist0;

  // --- register-resident tiles nt = wv, wv+8 (asm-opaque, pinned) ---
  U4H8 br0[10], br1[10];
  {
    const uint4* p0 = WB + (size_t)(wv * 10) * 64 + lane;
    const uint4* p1 = WB + (size_t)((wv + 8) * 10) * 64 + lane;
#pragma unroll
    for (int kt = 0; kt < 10; kt++) br0[kt].u = gld16(p0 + kt * 64);
#pragma unroll
    for (int kt = 0; kt < 10; kt++) br1[kt].u = gld16(p1 + kt * 64);
  }
  // --- LDS-resident tiles 16..26 (contiguous in WB): 11*640 uint4 ---
  for (int e = tid; e < 7040; e += 512) bls[e] = WB[16 * 640 + e];
  for (int e = tid; e < 8 * 328; e += 512) hA8[e] = (_Float16)0.f;
  asm volatile("s_waitcnt vmcnt(0)" ::: "memory");
  __builtin_amdgcn_sched_barrier(0);
  __syncthreads();

  // --- t-invariant elementwise indices: e = tid + q*512 -> (m,u) ---
  int gxo[5], gsho[5], hAo[5], ho[5];
  bool act[5];
#pragma unroll
  for (int q = 0; q < 5; q++) {
    int e = tid + q * 512;
    act[q] = (e < 2400);
    int m = act[q] ? (e / 300) : 0;
    int u = act[q] ? (e - m * 300) : 0;
    gxo[q] = (n0 + m) * 1200 + 4 * u;
    gsho[q] = m * 1204 + 4 * u;
    hAo[q] = m * 328 + u;
    ho[q] = (n0 + m) * 300 + u;
  }

  float crs[5] = {0.f, 0.f, 0.f, 0.f, 0.f};

  for (int t = 0; t < 64; t++) {
    const int tg = dirb ? (63 - t) : t;
    const size_t gxstep = (size_t)tg * NB * 1200;

    // prefetch x-gates (interleaved i,f,g,o), consumed post-barrier
    float4 gxv[5];
#pragma unroll
    for (int q = 0; q < 5; q++) {
      gxv[q] = make_float4(0.f, 0.f, 0.f, 0.f);
      if (act[q]) gxv[q] = *(const float4*)(gx + gxstep + gxo[q]);
    }

    // stream preload: first half of first streamed tile (nt = 27+wv)
    uint4 bA[5], bB[5];
#pragma unroll
    for (int kt = 0; kt < 5; kt++)
      bA[kt] = WB[(size_t)((27 + wv) * 10 + kt) * 64 + lane];

    // A fragments (rows 8-15 are zero: no LDS read for lm>=8)
    U4H8 af[10];
#pragma unroll
    for (int kt = 0; kt < 10; kt++) {
      uint4 v = make_uint4(0u, 0u, 0u, 0u);
      if (lm < 8) v = *(const uint4*)&hA8[lm * 328 + kt * 32 + lg * 8];
      af[kt].u = v;
    }

    // register-resident tiles (pure MFMA, hides in-flight stream loads)
    {
      f32x4v a0 = {0.f, 0.f, 0.f, 0.f};
      f32x4v a1 = {0.f, 0.f, 0.f, 0.f};
#pragma unroll
      for (int kt = 0; kt < 5; kt++)
        a0 = __builtin_amdgcn_mfma_f32_16x16x32_f16(af[kt].h, br0[kt].h, a0, 0, 0, 0);
#pragma unroll
      for (int kt = 5; kt < 10; kt++)
        a1 = __builtin_amdgcn_mfma_f32_16x16x32_f16(af[kt].h, br0[kt].h, a1, 0, 0, 0);
      if (lg < 2) {
        int col = wv * 16 + lm;
#pragma unroll
        for (int r = 0; r < 4; r++)
          gsh[(lg * 4 + r) * 1204 + col] = a0[r] + a1[r];
      }
    }
    {
      f32x4v a0 = {0.f, 0.f, 0.f, 0.f};
      f32x4v a1 = {0.f, 0.f, 0.f, 0.f};
#pragma unroll
      for (int kt = 0; kt < 5; kt++)
        a0 = __builtin_amdgcn_mfma_f32_16x16x32_f16(af[kt].h, br1[kt].h, a0, 0, 0, 0);
#pragma unroll
      for (int kt = 5; kt < 10; kt++)
        a1 = __builtin_amdgcn_mfma_f32_16x16x32_f16(af[kt].h, br1[kt].h, a1, 0, 0, 0);
      if (lg < 2) {
        int col = (wv + 8) * 16 + lm;
#pragma unroll
        for (int r = 0; r < 4; r++)
          gsh[(lg * 4 + r) * 1204 + col] = a0[r] + a1[r];
      }
    }

    // streamed tiles nt = 27+wv+8i (6 per wave), half-tile-ahead prefetch
#pragma unroll 1
    for (int i = 0; i < 6; i++) {
      int nt = 27 + wv + 8 * i;
#pragma unroll
      for (int kt = 0; kt < 5; kt++)
        bB[kt] = WB[(size_t)(nt * 10 + 5 + kt) * 64 + lane];
      f32x4v a0 = {0.f, 0.f, 0.f, 0.f};
#pragma unroll
      for (int kt = 0; kt < 5; kt++) {
        U4H8 bb; bb.u = bA[kt];
        a0 = __builtin_amdgcn_mfma_f32_16x16x32_f16(af[kt].h, bb.h, a0, 0, 0, 0);
      }
      if (i + 1 < 6) {
#pragma unroll
        for (int kt = 0; kt < 5; kt++)
          bA[kt] = WB[(size_t)((nt + 8) * 10 + kt) * 64 + lane];
      }
      f32x4v a1 = {0.f, 0.f, 0.f, 0.f};
#pragma unroll
      for (int kt = 0; kt < 5; kt++) {
        U4H8 bb; bb.u = bB[kt];
        a1 = __builtin_amdgcn_mfma_f32_16x16x32_f16(af[5 + kt].h, bb.h, a1, 0, 0, 0);
      }
      if (lg < 2) {
        int col = nt * 16 + lm;
#pragma unroll
        for (int r = 0; r < 4; r++)
          gsh[(lg * 4 + r) * 1204 + col] = a0[r] + a1[r];
      }
    }

    // LDS-resident tiles: nt = 16+wv (all waves) and 24+wv (waves 0-2)
#pragma unroll 1
    for (int li = 0; li < 2; li++) {
      int idxL = li == 0 ? wv : (8 + wv);
      if (li == 1 && wv >= 3) break;
      const uint4* bt = &bls[idxL * 640];
      f32x4v a0 = {0.f, 0.f, 0.f, 0.f};
      f32x4v a1 = {0.f, 0.f, 0.f, 0.f};
#pragma unroll
      for (int kt = 0; kt < 5; kt++) {
        U4H8 bb; bb.u = bt[kt * 64 + lane];
        a0 = __builtin_amdgcn_mfma_f32_16x16x32_f16(af[kt].h, bb.h, a0, 0, 0, 0);
      }
#pragma unroll
      for (int kt = 5; kt < 10; kt++) {
        U4H8 bb; bb.u = bt[kt * 64 + lane];
        a1 = __builtin_amdgcn_mfma_f32_16x16x32_f16(af[kt].h, bb.h, a1, 0, 0, 0);
      }
      if (lg < 2) {
        int col = (16 + idxL) * 16 + lm;
#pragma unroll
        for (int r = 0; r < 4; r++)
          gsh[(lg * 4 + r) * 1204 + col] = a0[r] + a1[r];
      }
    }
    __syncthreads();

    // elementwise: gates contiguous in gsh & gx (col' = 4u+gate)
#pragma unroll
    for (int q = 0; q < 5; q++) {
      if (act[q]) {
        const float4 gs = *(const float4*)&gsh[gsho[q]];
        float gi = gxv[q].x + gs.x;
        float gf = gxv[q].y + gs.y;
        float gg = gxv[q].z + gs.z;
        float go = gxv[q].w + gs.w;
        float si = fsig(gi);
        float sf = fsig(gf);
        float so = fsig(go);
        float cc = sf * crs[q] + si * ftanh(gg);
        float h = so * ftanh(cc);
        crs[q] = cc;
        hA8[hAo[q]] = (_Float16)h;
        if (hist) hist[(size_t)tg * NB * 300 + ho[q]] = h;
        if (hfin && t == 63) hfin[(size_t)dirb * NB * 300 + ho[q]] = h;
      }
    }
    __syncthreads();
  }
}

// ---------------------------------------------------------------------------
__global__ void embed_kernel(
    const int* __restrict__ prem, const int* __restrict__ hyp,
    const float* __restrict__ embW, float* __restrict__ comb)
{
  size_t i = (size_t)blockIdx.x * 256 + threadIdx.x;
  if (i >= (size_t)64 * 256 * 75) return;
  int d4 = (int)(i % 75);
  size_t r = i / 75;
  int n = (int)(r % 256);
  int t = (int)(r / 256);
  int id = (n < 128) ? prem[t * 128 + n] : hyp[t * 128 + (n - 128)];
  float4 v = *(const float4*)(embW + (size_t)id * 300 + d4 * 4);
  *(float4*)(comb + ((size_t)t * 256 + n) * 300 + d4 * 4) = v;
}

// ---------------------------------------------------------------------------
// norm4 (ORIGINAL distributed version): weighted norms per (dir,t,n,l) +
// plain row norms. Round-9 lesson: do NOT LDS-stage mp_W here — it is
// L2-resident and served at aggregate L2 BW across 32768 blocks; staging
// serialized it onto one LDS pipe per CU (8x regression).
// ---------------------------------------------------------------------------
__global__ __launch_bounds__(320) void norm4_kernel(
    const float* __restrict__ hs_fw, const float* __restrict__ hs_bw,
    const float* __restrict__ mp_W,
    float* __restrict__ nm4, float* __restrict__ pnorm)
{
  const int t = blockIdx.x, n = blockIdx.y, dir = blockIdx.z;
  const float* HS = dir ? hs_bw : hs_fw;
  const float* row = HS + ((size_t)t * 256 + n) * 300;
  __shared__ float sh[300];
  const int tid = threadIdx.x, g = tid >> 4, lane = tid & 15;
  for (int k = tid; k < 300; k += 320) sh[k] = row[k];
  __syncthreads();
  if (g == 0) {
    float s2 = 0.f;
    for (int k = lane; k < 300; k += 16) { float x = sh[k]; s2 += x * x; }
    for (int o = 8; o; o >>= 1) s2 += __shfl_down(s2, o, 16);
    if (lane == 0) pnorm[((size_t)dir * 64 + t) * 256 + n] = sqrtf(s2);
  }
#pragma unroll
  for (int wset = 0; wset < 4; wset++) {
    const float* W = mp_W + dir * 24000 + wset * 6000 + g * 300;
    float s1 = 0.f;
    for (int k = lane; k < 300; k += 16) {
      float x = sh[k];
      float w = W[k];
      s1 += x * x * w * w;
    }
    for (int o = 8; o; o >>= 1) s1 += __shfl_down(s1, o, 16);
    if (lane == 0)
      nm4[((((size_t)dir * 4 + wset) * 64 + t) * 256 + n) * 20 + g] = sqrtf(s1);
  }
}

// ---------------------------------------------------------------------------
// att: per (b,z), att[64,64] cosine GEMM -> normalized w (watt) + argmax idx.
// ---------------------------------------------------------------------------
__global__ __launch_bounds__(256) void att_kernel(
    const float* __restrict__ hs_fw, const float* __restrict__ hs_bw,
    const float* __restrict__ pnorm,
    float* __restrict__ watt, int* __restrict__ idxbuf)
{
  const int b = blockIdx.x, z = blockIdx.y;
  const int dir = z & 1;
  const float* HS = dir ? hs_bw : hs_fw;
  const int p_n = (z < 2) ? b : 128 + b;
  const int h_n = (z < 2) ? 128 + b : b;
  const float* pnD = pnorm + (size_t)dir * 16384;

  __shared__ float pch[64 * 100];
  __shared__ float hch[64 * 100];
  __shared__ float att[64 * 65];
  __shared__ float winv_sh[64];

  const int tid = threadIdx.x;
  const int i = tid >> 4, j = tid & 15;
  float acc[4][4];
#pragma unroll
  for (int a = 0; a < 4; a++)
#pragma unroll
    for (int c = 0; c < 4; c++) acc[a][c] = 0.f;

  for (int kc = 0; kc < 300; kc += 100) {
    for (int e = tid; e < 1600; e += 256) {
      int row = e / 25, kq = e - row * 25;
      float4 v = *(const float4*)(HS + ((size_t)row * 256 + p_n) * 300 + kc + kq * 4);
      *(float4*)&pch[row * 100 + kq * 4] = v;
      float4 w = *(const float4*)(HS + ((size_t)row * 256 + h_n) * 300 + kc + kq * 4);
      *(float4*)&hch[row * 100 + kq * 4] = w;
    }
    __syncthreads();
#pragma unroll 5
    for (int kq = 0; kq < 25; kq++) {
      float4 av[4], bv[4];
#pragma unroll
      for (int a = 0; a < 4; a++) av[a] = *(const float4*)&pch[(i + 16 * a) * 100 + kq * 4];
#pragma unroll
      for (int c = 0; c < 4; c++) bv[c] = *(const float4*)&hch[(j + 16 * c) * 100 + kq * 4];
#pragma unroll
      for (int a = 0; a < 4; a++)
#pragma unroll
        for (int c = 0; c < 4; c++)
          acc[a][c] += av[a].x * bv[c].x + av[a].y * bv[c].y + av[a].z * bv[c].z + av[a].w * bv[c].w;
    }
    __syncthreads();
  }

#pragma unroll
  for (int a = 0; a < 4; a++) {
    int t = i + 16 * a;
    float pn = pnD[t * 256 + p_n] + EPSF;
#pragma unroll
    for (int c = 0; c < 4; c++) {
      int s = j + 16 * c;
      float hn = pnD[s * 256 + h_n] + EPSF;
      att[t * 65 + s] = acc[a][c] / (pn * hn);
    }
  }
  __syncthreads();
  if (tid < 64) {
    int t = tid;
    float ssum = 0.f, mx = -1e30f; int mi = 0;
    for (int s = 0; s < 64; s++) {
      float a = att[t * 65 + s];
      ssum += a;
      if (a > mx) { mx = a; mi = s; }
    }
    winv_sh[t] = 1.f / (ssum + EPSF);
    idxbuf[((size_t)z * 128 + b) * 64 + t] = mi;
  }
  __syncthreads();
  for (int e = tid; e < 4096; e += 256) {
    int t = e >> 6, s = e & 63;
    watt[((size_t)z * 128 + b) * 4096 + t * 64 + s] = att[t * 65 + s] * winv_sh[t];
  }
}

// ---------------------------------------------------------------------------
// hmean: per (b,z): hmean[t,k] = sum_s w[t,s]*h[s,k]
// ---------------------------------------------------------------------------
__global__ __launch_bounds__(256) void hmean_kernel(
    const float* __restrict__ hs_fw, const float* __restrict__ hs_bw,
    const float* __restrict__ watt, float* __restrict__ hmeanbuf)
{
  const int b = blockIdx.x, z = blockIdx.y;
  const int dir = z & 1;
  const float* HS = dir ? hs_bw : hs_fw;
  const int h_n = (z < 2) ? 128 + b : b;

  __shared__ float wsh[64 * 65];
  __shared__ float hch[64 * 128];

  const int tid = threadIdx.x;
  const int ti = tid >> 4, kj = tid & 15;
  const float* wsrc = watt + ((size_t)z * 128 + b) * 4096;
  for (int e = tid; e < 4096; e += 256) {
    int t = e >> 6, s = e & 63;
    wsh[t * 65 + s] = wsrc[t * 64 + s];
  }

  for (int kbase = 0; kbase < 300; kbase += 128) {
    int kw = min(128, 300 - kbase);
    int nf4 = kw >> 2;  // 32,32,11
    __syncthreads();
    for (int e = tid; e < 64 * nf4; e += 256) {
      int row = e / nf4, q = e - row * nf4;
      float4 v = *(const float4*)(HS + ((size_t)row * 256 + h_n) * 300 + kbase + q * 4);
      *(float4*)&hch[row * 128 + q * 4] = v;
    }
    __syncthreads();
    float acc[4][8];
#pragma unroll
    for (int a = 0; a < 4; a++)
#pragma unroll
      for (int c = 0; c < 8; c++) acc[a][c] = 0.f;
    for (int s = 0; s < 64; s++) {
      float4 h0 = *(const float4*)&hch[s * 128 + 4 * kj];
      float4 h1 = *(const float4*)&hch[s * 128 + 4 * (kj + 16)];
#pragma unroll
      for (int a = 0; a < 4; a++) {
        float w = wsh[(4 * ti + a) * 65 + s];
        acc[a][0] += w * h0.x; acc[a][1] += w * h0.y; acc[a][2] += w * h0.z; acc[a][3] += w * h0.w;
        acc[a][4] += w * h1.x; acc[a][5] += w * h1.y; acc[a][6] += w * h1.z; acc[a][7] += w * h1.w;
      }
    }
#pragma unroll
    for (int a = 0; a < 4; a++) {
      int t = 4 * ti + a;
#pragma unroll
      for (int c = 0; c < 2; c++) {
        int kq = kj + 16 * c;
        if (kq * 4 < kw) {
          int k = kbase + kq * 4;
          float4 v = make_float4(acc[a][4 * c], acc[a][4 * c + 1], acc[a][4 * c + 2], acc[a][4 * c + 3]);
          *(float4*)&hmeanbuf[(((size_t)z * 128 + b) * 64 + t) * 300 + k] = v;
        }
      }
    }
  }
}

// ---------------------------------------------------------------------------
// maxp via MFMA f16 (round-5 WIN): per (b,z) ONE block; x = l*64+t tiling;
// A-frag = p-frag (*) w2[l]-frag; h-frags reg-cached per st-pair.
// ---------------------------------------------------------------------------
#define MAXP_LDS_BYTES (41984 + 41984 + 13120 + 5120 + 5120)  // 107,328

__global__ __launch_bounds__(512, 2) void maxp_mfma(
    const float* __restrict__ hs_fw, const float* __restrict__ hs_bw,
    const float* __restrict__ mp_W, const float* __restrict__ nm4,
    float* __restrict__ m_out)
{
  extern __shared__ char smem[];
  _Float16* pA = (_Float16*)smem;                     // [64][328]
  _Float16* hB = (_Float16*)(smem + 41984);           // [64][328]
  _Float16* w2h = (_Float16*)(smem + 83968);          // [20][328]
  float* pn_sh = (float*)(smem + 97088);              // [64][20]
  float* hn_sh = (float*)(smem + 102208);             // [64][20]

  const int b = blockIdx.x, z = blockIdx.y;
  const int dir = z & 1;
  const float* HS = dir ? hs_bw : hs_fw;
  const int p_n = (z < 2) ? b : 128 + b;
  const int h_n = (z < 2) ? 128 + b : b;
  const float* Wm = mp_W + dir * 24000 + 6000;
  const float* nmD = nm4 + ((size_t)dir * 4 + 1) * 327680;

  const int tid = threadIdx.x;
  const int wv = tid >> 6, lane = tid & 63;
  const int lm = lane & 15, lg = lane >> 4;

  // ---- stage p, h (f32->f16), w2 (squared f16), pn, hn ----
  for (int e = tid; e < 4800; e += 512) {
    int row = e / 75, q = e - row * 75;
    float4 v = *(const float4*)(HS + ((size_t)row * 256 + p_n) * 300 + q * 4);
    float4 w = *(const float4*)(HS + ((size_t)row * 256 + h_n) * 300 + q * 4);
    _Float16* pd = &pA[row * 328 + q * 4];
    pd[0] = (_Float16)v.x; pd[1] = (_Float16)v.y; pd[2] = (_Float16)v.z; pd[3] = (_Float16)v.w;
    _Float16* hd = &hB[row * 328 + q * 4];
    hd[0] = (_Float16)w.x; hd[1] = (_Float16)w.y; hd[2] = (_Float16)w.z; hd[3] = (_Float16)w.w;
  }
  for (int e = tid; e < 64 * 28; e += 512) {
    int row = e / 28, c = 300 + (e - row * 28);
    pA[row * 328 + c] = (_Float16)0.f;
    hB[row * 328 + c] = (_Float16)0.f;
  }
  for (int e = tid; e < 1500; e += 512) {
    int row = e / 75, q = e - row * 75;
    float4 w = *(const float4*)(Wm + (size_t)row * 300 + q * 4);
    _Float16* d = &w2h[row * 328 + q * 4];
    d[0] = (_Float16)(w.x * w.x); d[1] = (_Float16)(w.y * w.y);
    d[2] = (_Float16)(w.z * w.z); d[3] = (_Float16)(w.w * w.w);
  }
  for (int e = tid; e < 20 * 28; e += 512) {
    int row = e / 28, c = 300 + (e - row * 28);
    w2h[row * 328 + c] = (_Float16)0.f;
  }
  for (int e = tid; e < 1280; e += 512) {
    int tq = e / 20, l = e - tq * 20;
    pn_sh[e] = nmD[((size_t)tq * 256 + p_n) * 20 + l];
    hn_sh[e] = nmD[((size_t)tq * 256 + h_n) * 20 + l];
  }
  __syncthreads();

  // ---- compute: wave wv owns x-tiles xt = wv + 8i (10 tiles) ----
  float rmax[10][4];
#pragma unroll
  for (int i = 0; i < 10; i++)
#pragma unroll
    for (int r = 0; r < 4; r++) rmax[i][r] = -1e30f;

#pragma unroll
  for (int sp = 0; sp < 2; sp++) {       // st pairs {0,1},{2,3}
    U4H8 hf[2][10];
#pragma unroll
    for (int hh = 0; hh < 2; hh++)
#pragma unroll
      for (int kt = 0; kt < 10; kt++)
        hf[hh][kt].u = *(const uint4*)&hB[(sp * 32 + hh * 16 + lm) * 328 + kt * 32 + lg * 8];

#pragma unroll
    for (int i = 0; i < 10; i++) {
      int xt = wv + 8 * i;               // 0..79
      int l = xt >> 2, t0 = (xt & 3) << 4;
      U4H8 af[10];
#pragma unroll
      for (int kt = 0; kt < 10; kt++) {
        U4H8 pf, wf;
        pf.u = *(const uint4*)&pA[(t0 + lm) * 328 + kt * 32 + lg * 8];
        wf.u = *(const uint4*)&w2h[l * 328 + kt * 32 + lg * 8];
        af[kt].h = pf.h * wf.h;          // v_pk_mul_f16
      }
      float pnv[4];
#pragma unroll
      for (int r = 0; r < 4; r++) pnv[r] = pn_sh[(t0 + lg * 4 + r) * 20 + l];
#pragma unroll
      for (int hh = 0; hh < 2; hh++) {
        int st = sp * 2 + hh;
        f32x4v acc = {0.f, 0.f, 0.f, 0.f};
#pragma unroll
        for (int kt = 0; kt < 10; kt++)
          acc = __builtin_amdgcn_mfma_f32_16x16x32_f16(af[kt].h, hf[hh][kt].h, acc, 0, 0, 0);
        float hn = hn_sh[(st * 16 + lm) * 20 + l];
#pragma unroll
        for (int r = 0; r < 4; r++) {
          float val = acc[r] * __builtin_amdgcn_rcpf(pnv[r] * hn + EPSF);
          rmax[i][r] = fmaxf(rmax[i][r], val);
        }
      }
    }
  }

  // ---- cross-lane max over s (16-lane groups) + write ----
#pragma unroll
  for (int i = 0; i < 10; i++) {
    int xt = wv + 8 * i;
    int l = xt >> 2, t0 = (xt & 3) << 4;
#pragma unroll
    for (int r = 0; r < 4; r++) {
      float v = rmax[i][r];
#pragma unroll
      for (int off = 8; off; off >>= 1) v = fmaxf(v, __shfl_down(v, off, 16));
      if (lm == 0) {
        int t = t0 + lg * 4 + r;
        m_out[((size_t)t * 128 + b) * 320 + z * 80 + 20 + l] = v;
      }
    }
  }
}

// ---------------------------------------------------------------------------
// rest: per (b,z): full / attm / maxattm for all t. W^2 staged once in LDS.
// ---------------------------------------------------------------------------
__global__ __launch_bounds__(320) void rest_kernel(
    const float* __restrict__ hs_fw, const float* __restrict__ hs_bw,
    const float* __restrict__ mp_W, const float* __restrict__ nm4,
    const float* __restrict__ hmeanbuf, const int* __restrict__ idxbuf,
    float* __restrict__ m_out)
{
  const int b = blockIdx.x, z = blockIdx.y;
  const int dir = z & 1;
  const float* HS = dir ? hs_bw : hs_fw;
  const int p_n = (z < 2) ? b : 128 + b;
  const int h_n = (z < 2) ? 128 + b : b;
  const int v_t = dir ? 0 : 63;

  __shared__ float w2f[6000], w2a[6000], w2m[6000];
  __shared__ float vsh[300], psh[300], hmsh[300], hxsh[300];

  const int tid = threadIdx.x;
  const int g = tid >> 4, lane = tid & 15;
  const float* Wf = mp_W + dir * 24000;
  const float* Wa = Wf + 12000;
  const float* Wma = Wf + 18000;
  for (int e = tid; e < 6000; e += 320) {
    float a = Wf[e], bb = Wa[e], c = Wma[e];
    w2f[e] = a * a; w2a[e] = bb * bb; w2m[e] = c * c;
  }
  for (int e = tid; e < 300; e += 320)
    vsh[e] = HS[((size_t)v_t * 256 + h_n) * 300 + e];
  __syncthreads();

  const float* base0 = nm4 + ((size_t)dir * 4 + 0) * 327680;
  const float* base2 = nm4 + ((size_t)dir * 4 + 2) * 327680;
  const float* base3 = nm4 + ((size_t)dir * 4 + 3) * 327680;
  const float vnf = base0[((size_t)v_t * 256 + h_n) * 20 + g];

  for (int t = 0; t < 64; t++) {
    int idx = idxbuf[((size_t)z * 128 + b) * 64 + t];
    __syncthreads();
    for (int e = tid; e < 300; e += 320) {
      psh[e] = HS[((size_t)t * 256 + p_n) * 300 + e];
      hmsh[e] = hmeanbuf[(((size_t)z * 128 + b) * 64 + t) * 300 + e];
      hxsh[e] = HS[((size_t)idx * 256 + h_n) * 300 + e];
    }
    __syncthreads();
    float nf = 0.f, na = 0.f, qa = 0.f, nm = 0.f;
#pragma unroll
    for (int c = 0; c < 5; c++) {
      int k4 = lane + 16 * c;
      if (k4 < 75) {
        float4 p = *(const float4*)&psh[4 * k4];
        float4 v = *(const float4*)&vsh[4 * k4];
        float4 hm = *(const float4*)&hmsh[4 * k4];
        float4 hx = *(const float4*)&hxsh[4 * k4];
        float4 wf = *(const float4*)&w2f[g * 300 + 4 * k4];
        float4 wa = *(const float4*)&w2a[g * 300 + 4 * k4];
        float4 wm = *(const float4*)&w2m[g * 300 + 4 * k4];
        nf += p.x * v.x * wf.x + p.y * v.y * wf.y + p.z * v.z * wf.z + p.w * v.w * wf.w;
        na += p.x * hm.x * wa.x + p.y * hm.y * wa.y + p.z * hm.z * wa.z + p.w * hm.w * wa.w;
        qa += hm.x * hm.x * wa.x + hm.y * hm.y * wa.y + hm.z * hm.z * wa.z + hm.w * hm.w * wa.w;
        nm += p.x * hx.x * wm.x + p.y * hx.y * wm.y + p.z * hx.z * wm.z + p.w * hx.w * wm.w;
      }
    }
#pragma unroll
    for (int o = 8; o; o >>= 1) {
      nf += __shfl_down(nf, o);
      na += __shfl_down(na, o);
      qa += __shfl_down(qa, o);
      nm += __shfl_down(nm, o);
    }
    if (lane == 0) {
      float pnf = base0[((size_t)t * 256 + p_n) * 20 + g];
      float pna = base2[((size_t)t * 256 + p_n) * 20 + g];
      float pnm = base3[((size_t)t * 256 + p_n) * 20 + g];
      float qnm = base3[((size_t)idx * 256 + h_n) * 20 + g];
      float* mrow = m_out + ((size_t)t * 128 + b) * 320 + z * 80;
      mrow[g] = nf / (pnf * vnf + EPSF);
      mrow[40 + g] = na / (pna * sqrtf(qa) + EPSF);
      mrow[60 + g] = nm / (pnm * qnm + EPSF);
    }
  }
}

// ---------------------------------------------------------------------------
__global__ __launch_bounds__(256) void mlp_kernel(
    const float* __restrict__ shA0, const float* __restrict__ shA1,
    const float* __restrict__ bnG, const float* __restrict__ bnB,
    const float* __restrict__ W1, const float* __restrict__ b1,
    const float* __restrict__ W2, const float* __restrict__ b2,
    const float* __restrict__ outW, const float* __restrict__ outb,
    float* __restrict__ out)
{
  const int b = blockIdx.x;
  const int tid = threadIdx.x;
  __shared__ float x0[600], x1[600];
  const float inv = 1.0f / sqrtf(1.0f + 1e-5f);
  for (int j = tid; j < 600; j += 256) {
    float v = (j < 300) ? shA0[b * 300 + j] : shA1[b * 300 + (j - 300)];
    x0[j] = bnG[j] * v * inv + bnB[j];
  }
  __syncthreads();
  for (int j = tid; j < 600; j += 256) {
    float acc = b1[j];
    const float* w = W1 + (size_t)j * 600;
    for (int k = 0; k < 600; k++) acc += x0[k] * w[k];
    float r = fmaxf(acc, 0.f);
    x1[j] = bnG[600 + j] * r * inv + bnB[600 + j];
  }
  __syncthreads();
  for (int j = tid; j < 600; j += 256) {
    float acc = b2[j];
    const float* w = W2 + (size_t)j * 600;
    for (int k = 0; k < 600; k++) acc += x1[k] * w[k];
    float r = fmaxf(acc, 0.f);
    x0[j] = bnG[1200 + j] * r * inv + bnB[1200 + j];
  }
  __syncthreads();
  if (tid < 3) {
    float acc = outb[tid];
    const float* w = outW + tid * 600;
    for (int k = 0; k < 600; k++) acc += x0[k] * w[k];
    out[b * 3 + tid] = acc;
  }
}

// ---------------------------------------------------------------------------
extern "C" void kernel_launch(void* const* d_in, const int* in_sizes, int n_in,
                              void* d_out, int out_size, void* d_ws, size_t ws_size,
                              hipStream_t stream) {
  const int* premise = (const int*)d_in[0];
  const int* hypothesis = (const int*)d_in[1];
  const float* embW = (const float*)d_in[2];
  const float* cWih = (const float*)d_in[3];
  const float* cWhh = (const float*)d_in[4];
  const float* cb = (const float*)d_in[5];
  const float* mpW = (const float*)d_in[6];
  const float* aWihF = (const float*)d_in[7];
  const float* aWhhF = (const float*)d_in[8];
  const float* abF = (const float*)d_in[9];
  const float* aWihB = (const float*)d_in[10];
  const float* aWhhB = (const float*)d_in[11];
  const float* abB = (const float*)d_in[12];
  const float* bnG = (const float*)d_in[13];
  const float* bnB = (const float*)d_in[14];
  const float* W1 = (const float*)d_in[15];
  const float* b1 = (const float*)d_in[16];
  const float* W2 = (const float*)d_in[17];
  const float* b2 = (const float*)d_in[18];
  const float* outW = (const float*)d_in[19];
  const float* outb = (const float*)d_in[20];
  float* out = (float*)d_out;

  float* ws = (float*)d_ws;
  // workspace layout (floats)
  float* comb  = ws + 0;           // 4,915,200  (T,256,300); WB packs + aWih perms overlay after ctx-gates GEMM
  float* gates = ws + 4915200;     // 19,660,800 (T,256,1200); overlaid after ctx LSTM
  float* hsfw  = ws + 24576000;    // 4,915,200  (cWih perm overlays here pre-LSTM)
  float* hsbw  = ws + 29491200;    // 4,915,200
  float* pnorm = ws + 34406400;    // 32,768    [2][64][256]
  float* mbuf  = ws + 35094528;    // 2,621,440 (T,128,320)
  float* sha   = ws + 38023168;    // 76,800    agg final h [2][128][300]

  // packed MFMA B-fragment weights overlay in comb region (dead after ctx-gates GEMM)
  uint4* WBctx = (uint4*)comb;
  uint4* WBaf  = (uint4*)(comb + 192000);
  uint4* WBab  = (uint4*)(comb + 384000);
  // gate-interleaved agg input weights (dead comb region, after WB packs)
  float* aWihFP = comb + 576000;   // 384,000
  float* aWihBP = comb + 960000;   // 384,000
  float* abFP   = comb + 1344000;  // 1,200
  float* abBP   = comb + 1345200;  // 1,200

  // gate-interleaved ctx input weights: hsfw region is dead until ctx LSTM
  float* cWihP = hsfw;             // 360,000
  float* cbP   = hsfw + 360000;    // 1,200

  // overlays inside the dead ctx-gates region (valid between ctx LSTM and agg GEMMs)
  float* watt     = gates;                 // 2,097,152 [4][128][64][64]
  float* hmeanbuf = gates + 2097152;       // 9,830,400 [4][128][64][300]
  int*   idxbuf   = (int*)(gates + 11927552); // 32,768 [4][128][64]
  float* nm4      = gates + 11960320;      // 2,621,440 [2][4][64][256][20]

  // allow >64KB dynamic LDS (gfx950 pool = 160KB/WG)
  hipFuncSetAttribute((const void*)lstm_res,
                      hipFuncAttributeMaxDynamicSharedMemorySize, LSTM_LDS_BYTES);
  hipFuncSetAttribute((const void*)maxp_mfma,
                      hipFuncAttributeMaxDynamicSharedMemorySize, MAXP_LDS_BYTES);
  hipFuncSetAttribute((const void*)gemm_mfma_nt,
                      hipFuncAttributeMaxDynamicSharedMemorySize, GMM_LDS_BYTES);

  // 1) embed + ctx input-weight gate-interleave
  embed_kernel<<<dim3(4800), dim3(256), 0, stream>>>(premise, hypothesis, embW, comb);
  permW_kernel<<<dim3(1200), dim3(256), 0, stream>>>(cWih, cb, cWihP, cbP, 300);

  // 2) ctx input gates (consumes comb) — split-f16 MFMA, fp32-grade accuracy
  gemm_mfma_nt<<<dim3(5, 128), dim3(512), GMM_LDS_BYTES, stream>>>(
      comb, cWihP, cbP, gates, 16384, 300);

  // 3) pack recurrent weights into MFMA B-fragment stream (dead comb region)
  //    + gate-interleave the agg input weights
  packB_kernel<<<dim3(188, 3), dim3(256), 0, stream>>>(
      cWhh, aWhhF, aWhhB, WBctx, WBaf, WBab);
  permW_kernel<<<dim3(1200), dim3(256), 0, stream>>>(aWihF, abF, aWihFP, abFP, 320);
  permW_kernel<<<dim3(1200), dim3(256), 0, stream>>>(aWihB, abB, aWihBP, abBP, 320);

  // 4) context LSTM: 16 reg + 11 LDS tiles resident, 48 streamed (r6 config)
  lstm_res<<<dim3(64), dim3(512), LSTM_LDS_BYTES, stream>>>(
      WBctx, WBctx, gates, gates, hsfw, hsbw, nullptr, 256);

  // 5) norms (all 4 W sets) + plain norms — ORIGINAL distributed version
  norm4_kernel<<<dim3(64, 256, 2), dim3(320), 0, stream>>>(hsfw, hsbw, mpW, nm4, pnorm);

  // 6) matching pipeline
  att_kernel<<<dim3(128, 4), dim3(256), 0, stream>>>(hsfw, hsbw, pnorm, watt, idxbuf);
  hmean_kernel<<<dim3(128, 4), dim3(256), 0, stream>>>(hsfw, hsbw, watt, hmeanbuf);
  maxp_mfma<<<dim3(128, 4), dim3(512), MAXP_LDS_BYTES, stream>>>(
      hsfw, hsbw, mpW, nm4, mbuf);
  rest_kernel<<<dim3(128, 4), dim3(320), 0, stream>>>(hsfw, hsbw, mpW, nm4, hmeanbuf, idxbuf, mbuf);

  // 7) agg input gates — split-f16 MFMA, gate-interleaved columns
  float* gaf = gates;
  float* gab = gates + 9830400;
  gemm_mfma_nt<<<dim3(5, 64), dim3(512), GMM_LDS_BYTES, stream>>>(
      mbuf, aWihFP, abFP, gaf, 8192, 320);
  gemm_mfma_nt<<<dim3(5, 64), dim3(512), GMM_LDS_BYTES, stream>>>(
      mbuf, aWihBP, abBP, gab, 8192, 320);

  // 8) aggregation LSTM: 32 blocks (16/dir), 8 waves
  lstm_res<<<dim3(32), dim3(512), LSTM_LDS_BYTES, stream>>>(
      WBaf, WBab, gaf, gab, nullptr, nullptr, sha, 128);

  // 9) MLP head
  mlp_kernel<<<dim3(128), dim3(256), 0, stream>>>(
      sha, sha + 38400, bnG, bnB, W1, b1, W2, b2, outW, outb, out);
}

// Round 13
// 1740.206 us; speedup vs baseline: 1.3819x; 1.1456x over previous
//
#include <hip/hip_runtime.h>
#include <cstddef>
#include <cstdint>
#include <math.h>

#define EPSF 1e-8f

// Model dims (fixed): T=64, B=128, D=300, H=300, L=20, AH=300, N2=2B=256

typedef _Float16 half8v __attribute__((ext_vector_type(8)));
typedef float f32x4v __attribute__((ext_vector_type(4)));
union U4H8 { uint4 u; half8v h; _Float16 e[8]; };

// fast device math: v_exp_f32 + v_rcp_f32 (rel err ~1e-7, fine for 3e-3 budget)
__device__ __forceinline__ float fsig(float x) {
  float e = __expf(-x);
  return __builtin_amdgcn_rcpf(1.f + e);
}
__device__ __forceinline__ float ftanh(float x) {
  float e = __expf(-2.f * fabsf(x));
  float r = (1.f - e) * __builtin_amdgcn_rcpf(1.f + e);
  return copysignf(r, x);
}

// asm-opaque 16B load: result cannot be re-materialized by the compiler ->
// forces true register residency. SAFE ONLY at low register pressure:
// 2 tiles/wave (80 pinned VGPR) fits; 3 tiles/wave spills — round-7
// (corrupt: spill before external wait) and round-10 (correct with internal
// wait but slow: scratch re-loads every step, 370->498us). 2 tiles is final.
__device__ __forceinline__ uint4 gld16(const uint4* p) {
  uint4 r;
  asm volatile("global_load_dwordx4 %0, %1, off" : "=v"(r) : "v"(p));
  return r;
}

// ---------------------------------------------------------------------------
// Split-f16 MFMA NT GEMM (round-6 WIN): C = bias + A*B^T, fp32-grade via
// A=Ah+Al, B=Bh+Bl, C ~= AhBh+AlBh+AhBl (dropped AlBl ~2^-22).
// Tile 128x240, N=1200=5x240; 512 thr; LDS pitch-72 hi/lo staging.
// Round-12: optional second (B,bias,C) set selected by blockIdx.z so the two
// agg-gate GEMMs run as ONE launch (640 blocks schedule in 3 CU-rounds vs
// 2x2 rounds separate; inner code unchanged).
// ---------------------------------------------------------------------------
#define GMM_LDS_BYTES (2 * (128 * 72 * 2) + 2 * (240 * 72 * 2))  // 105,984

__global__ __launch_bounds__(512, 1) void gemm_mfma_nt(
    const float* __restrict__ A, const float* __restrict__ B,
    const float* __restrict__ bias, float* __restrict__ C,
    const float* __restrict__ B2, const float* __restrict__ bias2,
    float* __restrict__ C2,
    int M, int K)
{
  extern __shared__ char smem[];
  _Float16* Ah = (_Float16*)smem;                       // [128][72]
  _Float16* Al = (_Float16*)(smem + 18432);             // [128][72]
  _Float16* Bh = (_Float16*)(smem + 36864);             // [240][72]
  _Float16* Bl = (_Float16*)(smem + 36864 + 34560);     // [240][72]

  const float* Bp = B;
  const float* biasp = bias;
  float* Cp = C;
  if (blockIdx.z == 1) { Bp = B2; biasp = bias2; Cp = C2; }

  const int tid = threadIdx.x;
  const int wv = tid >> 6, lane = tid & 63;
  const int lm = lane & 15, lg = lane >> 4;
  const int mbase = blockIdx.y << 7;
  const int nbase = blockIdx.x * 240;

  f32x4v acc[15];
#pragma unroll
  for (int nt = 0; nt < 15; nt++) acc[nt] = (f32x4v){0.f, 0.f, 0.f, 0.f};

  const int nchunk = (K + 63) >> 6;
  for (int c = 0; c < nchunk; c++) {
    const int kc = c << 6;
    // stage A 128x64 -> hi/lo f16
    for (int e = tid; e < 2048; e += 512) {
      int row = e >> 4, q = e & 15;
      int k = kc + q * 4;
      const float* src = A + (size_t)(mbase + row) * K;
      float4 v = make_float4(0.f, 0.f, 0.f, 0.f);
      if (k + 4 <= K) {
        v = *(const float4*)(src + k);
      } else {
        if (k + 0 < K) v.x = src[k + 0];
        if (k + 1 < K) v.y = src[k + 1];
        if (k + 2 < K) v.z = src[k + 2];
        if (k + 3 < K) v.w = src[k + 3];
      }
      _Float16 hx = (_Float16)v.x, hy = (_Float16)v.y,
               hz = (_Float16)v.z, hw = (_Float16)v.w;
      _Float16* d = &Ah[row * 72 + q * 4];
      d[0] = hx; d[1] = hy; d[2] = hz; d[3] = hw;
      _Float16* dl = &Al[row * 72 + q * 4];
      dl[0] = (_Float16)(v.x - (float)hx); dl[1] = (_Float16)(v.y - (float)hy);
      dl[2] = (_Float16)(v.z - (float)hz); dl[3] = (_Float16)(v.w - (float)hw);
    }
    // stage B 240x64 -> hi/lo f16
    for (int e = tid; e < 3840; e += 512) {
      int row = e >> 4, q = e & 15;
      int k = kc + q * 4;
      const float* src = Bp + (size_t)(nbase + row) * K;
      float4 v = make_float4(0.f, 0.f, 0.f, 0.f);
      if (k + 4 <= K) {
        v = *(const float4*)(src + k);
      } else {
        if (k + 0 < K) v.x = src[k + 0];
        if (k + 1 < K) v.y = src[k + 1];
        if (k + 2 < K) v.z = src[k + 2];
        if (k + 3 < K) v.w = src[k + 3];
      }
      _Float16 hx = (_Float16)v.x, hy = (_Float16)v.y,
               hz = (_Float16)v.z, hw = (_Float16)v.w;
      _Float16* d = &Bh[row * 72 + q * 4];
      d[0] = hx; d[1] = hy; d[2] = hz; d[3] = hw;
      _Float16* dl = &Bl[row * 72 + q * 4];
      dl[0] = (_Float16)(v.x - (float)hx); dl[1] = (_Float16)(v.y - (float)hy);
      dl[2] = (_Float16)(v.z - (float)hz); dl[3] = (_Float16)(v.w - (float)hw);
    }
    __syncthreads();

#pragma unroll
    for (int kt = 0; kt < 2; kt++) {
      U4H8 ah, al;
      ah.u = *(const uint4*)&Ah[(wv * 16 + lm) * 72 + kt * 32 + lg * 8];
      al.u = *(const uint4*)&Al[(wv * 16 + lm) * 72 + kt * 32 + lg * 8];
#pragma unroll
      for (int nt = 0; nt < 15; nt++) {
        U4H8 bh, bl;
        bh.u = *(const uint4*)&Bh[(nt * 16 + lm) * 72 + kt * 32 + lg * 8];
        bl.u = *(const uint4*)&Bl[(nt * 16 + lm) * 72 + kt * 32 + lg * 8];
        acc[nt] = __builtin_amdgcn_mfma_f32_16x16x32_f16(ah.h, bh.h, acc[nt], 0, 0, 0);
        acc[nt] = __builtin_amdgcn_mfma_f32_16x16x32_f16(al.h, bh.h, acc[nt], 0, 0, 0);
        acc[nt] = __builtin_amdgcn_mfma_f32_16x16x32_f16(ah.h, bl.h, acc[nt], 0, 0, 0);
      }
    }
    __syncthreads();
  }

  // epilogue: D col = nbase+nt*16+lm, row m = mbase+wv*16+lg*4+r
#pragma unroll
  for (int nt = 0; nt < 15; nt++) {
    int col = nbase + nt * 16 + lm;
    float bv = biasp[col];
#pragma unroll
    for (int r = 0; r < 4; r++) {
      int m = mbase + wv * 16 + lg * 4 + r;
      Cp[(size_t)m * 1200 + col] = acc[nt][r] + bv;
    }
  }
}

// ---------------------------------------------------------------------------
// permW: permute Wih rows to gate-interleaved order (row' = 4u+gate).
// ---------------------------------------------------------------------------
__global__ __launch_bounds__(256) void permW_kernel(
    const float* __restrict__ W, const float* __restrict__ bias,
    float* __restrict__ Wp, float* __restrict__ bp, int K)
{
  int r = blockIdx.x;              // 0..1199 = col' = 4u+gate
  int gate = r & 3, u = r >> 2;
  int src = gate * 300 + u;
  const float* s = W + (size_t)src * K;
  float* d = Wp + (size_t)r * K;
  for (int c = threadIdx.x; c < K; c += 256) d[c] = s[c];
  if (threadIdx.x == 0) bp[r] = bias[src];
}

// ---------------------------------------------------------------------------
// packB: W (1200,300) fp32 -> MFMA B-fragment stream for 16x16x32_f16.
// Gate-interleaved column order col' = 4*u + gate  (orig n = gate*300+u).
// Item i = (nt*10+kt)*64 + lane.
// ---------------------------------------------------------------------------
__global__ __launch_bounds__(256) void packB_kernel(
    const float* __restrict__ W0, const float* __restrict__ W1,
    const float* __restrict__ W2,
    uint4* __restrict__ T0, uint4* __restrict__ T1, uint4* __restrict__ T2)
{
  int i = blockIdx.x * 256 + threadIdx.x;
  if (i >= 48000) return;
  const float* W = (blockIdx.y == 0) ? W0 : (blockIdx.y == 1) ? W1 : W2;
  uint4* T = (blockIdx.y == 0) ? T0 : (blockIdx.y == 1) ? T1 : T2;
  int lane = i & 63;
  int tile = i >> 6;               // nt*10 + kt
  int nt = tile / 10, kt = tile - nt * 10;
  int lm = lane & 15, lg = lane >> 4;
  int colp = nt * 16 + lm;
  int u = colp >> 2, gate = colp & 3;
  int n = gate * 300 + u;
  U4H8 v;
#pragma unroll
  for (int j = 0; j < 8; j++) {
    int k = kt * 32 + lg * 8 + j;
    float x = (k < 300) ? W[(size_t)n * 300 + k] : 0.f;
    v.e[j] = (_Float16)x;
  }
  T[i] = v.u;
}

// ---------------------------------------------------------------------------
// Persistent LSTM via MFMA, partial weight residency (round-6 verified
// config — measured 370us/dispatch across four benches):
//   - 16 tiles in REGISTERS (2/wave) via asm-opaque gld16;
//   - 11 tiles in dynamic LDS (nt = 16..26);
//   - 48 tiles streamed (nt = 27+wv+8i, 6/wave), 491KB/step at the
//     ~35 B/cyc/CU L1-fill wall = the structural floor for this schedule.
// 3 tiles/wave is dead: r7 corrupt (spill before wait), r10 slow (spills
// re-loaded from scratch every step, 370->498us).
// LDS: hA8 5.25KB + gsh 38.5KB + bls 112.6KB = 156.4KB.
// ---------------------------------------------------------------------------
#define LSTM_LDS_BYTES (5248 + 38528 + 11 * 10240)   // 156,416

__global__ __launch_bounds__(512, 2) void lstm_res(
    const uint4* WB0, const uint4* WB1,   // packed B-frags; no __restrict__
    const float* __restrict__ gx0, const float* __restrict__ gx1, // (64,NB,1200) interleaved
    float* hist0, float* hist1,           // (64,NB,300) or null; no __restrict__
    float* hfin,                          // (2,NB,300) or null
    int NB)
{
  extern __shared__ char smem[];
  _Float16* hA8 = (_Float16*)smem;                    // [8][328]
  float* gsh = (float*)(smem + 5248);                 // [8][1204]
  uint4* bls = (uint4*)(smem + 5248 + 38528);         // [11][640]

  const int b = blockIdx.x;
  const int xcd = b & 7;
  const int grp = b >> 3;
  const int dirb = xcd >> 2;
  const int n0 = (grp * 4 + (xcd & 3)) * 8;
  const int tid = threadIdx.x;
  const int wv = tid >> 6, lane = tid & 63;
  const int lm = lane & 15, lg = lane >> 4;

  const uint4* WB = dirb ? WB1 : WB0;
  const float* gx = dirb ? gx1 : gx0;
  float* hist = dirb ? hist1 : hist0;

  // --- register-resident tiles nt = wv, wv+8 (asm-opaque, pinned) ---
  U4H8 br0[10], br1[10];
  {
    const uint4* p0 = WB + (size_t)(wv * 10) * 64 + lane;
    const uint4* p1 = WB + (size_t)((wv + 8) * 10) * 64 + lane;
#pragma unroll
    for (int kt = 0; kt < 10; kt++) br0[kt].u = gld16(p0 + kt * 64);
#pragma unroll
    for (int kt = 0; kt < 10; kt++) br1[kt].u = gld16(p1 + kt * 64);
  }
  // --- LDS-resident tiles 16..26 (contiguous in WB): 11*640 uint4 ---
  for (int e = tid; e < 7040; e += 512) bls[e] = WB[16 * 640 + e];
  for (int e = tid; e < 8 * 328; e += 512) hA8[e] = (_Float16)0.f;
  asm volatile("s_waitcnt vmcnt(0)" ::: "memory");
  __builtin_amdgcn_sched_barrier(0);
  __syncthreads();

  // --- t-invariant elementwise indices: e = tid + q*512 -> (m,u) ---
  int gxo[5], gsho[5], hAo[5], ho[5];
  bool act[5];
#pragma unroll
  for (int q = 0; q < 5; q++) {
    int e = tid + q * 512;
    act[q] = (e < 2400);
    int m = act[q] ? (e / 300) : 0;
    int u = act[q] ? (e - m * 300) : 0;
    gxo[q] = (n0 + m) * 1200 + 4 * u;
    gsho[q] = m * 1204 + 4 * u;
    hAo[q] = m * 328 + u;
    ho[q] = (n0 + m) * 300 + u;
  }

  float crs[5] = {0.f, 0.f, 0.f, 0.f, 0.f};

  for (int t = 0; t < 64; t++) {
    const int tg = dirb ? (63 - t) : t;
    const size_t gxstep = (size_t)tg * NB * 1200;

    // prefetch x-gates (interleaved i,f,g,o), consumed post-barrier
    float4 gxv[5];
#pragma unroll
    for (int q = 0; q < 5; q++) {
      gxv[q] = make_float4(0.f, 0.f, 0.f, 0.f);
      if (act[q]) gxv[q] = *(const float4*)(gx + gxstep + gxo[q]);
    }

    // stream preload: first half of first streamed tile (nt = 27+wv)
    uint4 bA[5], bB[5];
#pragma unroll
    for (int kt = 0; kt < 5; kt++)
      bA[kt] = WB[(size_t)((27 + wv) * 10 + kt) * 64 + lane];

    // A fragments (rows 8-15 are zero: no LDS read for lm>=8)
    U4H8 af[10];
#pragma unroll
    for (int kt = 0; kt < 10; kt++) {
      uint4 v = make_uint4(0u, 0u, 0u, 0u);
      if (lm < 8) v = *(const uint4*)&hA8[lm * 328 + kt * 32 + lg * 8];
      af[kt].u = v;
    }

    // register-resident tiles (pure MFMA, hides in-flight stream loads)
    {
      f32x4v a0 = {0.f, 0.f, 0.f, 0.f};
      f32x4v a1 = {0.f, 0.f, 0.f, 0.f};
#pragma unroll
      for (int kt = 0; kt < 5; kt++)
        a0 = __builtin_amdgcn_mfma_f32_16x16x32_f16(af[kt].h, br0[kt].h, a0, 0, 0, 0);
#pragma unroll
      for (int kt = 5; kt < 10; kt++)
        a1 = __builtin_amdgcn_mfma_f32_16x16x32_f16(af[kt].h, br0[kt].h, a1, 0, 0, 0);
      if (lg < 2) {
        int col = wv * 16 + lm;
#pragma unroll
        for (int r = 0; r < 4; r++)
          gsh[(lg * 4 + r) * 1204 + col] = a0[r] + a1[r];
      }
    }
    {
      f32x4v a0 = {0.f, 0.f, 0.f, 0.f};
      f32x4v a1 = {0.f, 0.f, 0.f, 0.f};
#pragma unroll
      for (int kt = 0; kt < 5; kt++)
        a0 = __builtin_amdgcn_mfma_f32_16x16x32_f16(af[kt].h, br1[kt].h, a0, 0, 0, 0);
#pragma unroll
      for (int kt = 5; kt < 10; kt++)
        a1 = __builtin_amdgcn_mfma_f32_16x16x32_f16(af[kt].h, br1[kt].h, a1, 0, 0, 0);
      if (lg < 2) {
        int col = (wv + 8) * 16 + lm;
#pragma unroll
        for (int r = 0; r < 4; r++)
          gsh[(lg * 4 + r) * 1204 + col] = a0[r] + a1[r];
      }
    }

    // streamed tiles nt = 27+wv+8i (6 per wave), half-tile-ahead prefetch
#pragma unroll 1
    for (int i = 0; i < 6; i++) {
      int nt = 27 + wv + 8 * i;
#pragma unroll
      for (int kt = 0; kt < 5; kt++)
        bB[kt] = WB[(size_t)(nt * 10 + 5 + kt) * 64 + lane];
      f32x4v a0 = {0.f, 0.f, 0.f, 0.f};
#pragma unroll
      for (int kt = 0; kt < 5; kt++) {
        U4H8 bb; bb.u = bA[kt];
        a0 = __builtin_amdgcn_mfma_f32_16x16x32_f16(af[kt].h, bb.h, a0, 0, 0, 0);
      }
      if (i + 1 < 6) {
#pragma unroll
        for (int kt = 0; kt < 5; kt++)
          bA[kt] = WB[(size_t)((nt + 8) * 10 + kt) * 64 + lane];
      }
      f32x4v a1 = {0.f, 0.f, 0.f, 0.f};
#pragma unroll
      for (int kt = 0; kt < 5; kt++) {
        U4H8 bb; bb.u = bB[kt];
        a1 = __builtin_amdgcn_mfma_f32_16x16x32_f16(af[5 + kt].h, bb.h, a1, 0, 0, 0);
      }
      if (lg < 2) {
        int col = nt * 16 + lm;
#pragma unroll
        for (int r = 0; r < 4; r++)
          gsh[(lg * 4 + r) * 1204 + col] = a0[r] + a1[r];
      }
    }

    // LDS-resident tiles: nt = 16+wv (all waves) and 24+wv (waves 0-2)
#pragma unroll 1
    for (int li = 0; li < 2; li++) {
      int idxL = li == 0 ? wv : (8 + wv);
      if (li == 1 && wv >= 3) break;
      const uint4* bt = &bls[idxL * 640];
      f32x4v a0 = {0.f, 0.f, 0.f, 0.f};
      f32x4v a1 = {0.f, 0.f, 0.f, 0.f};
#pragma unroll
      for (int kt = 0; kt < 5; kt++) {
        U4H8 bb; bb.u = bt[kt * 64 + lane];
        a0 = __builtin_amdgcn_mfma_f32_16x16x32_f16(af[kt].h, bb.h, a0, 0, 0, 0);
      }
#pragma unroll
      for (int kt = 5; kt < 10; kt++) {
        U4H8 bb; bb.u = bt[kt * 64 + lane];
        a1 = __builtin_amdgcn_mfma_f32_16x16x32_f16(af[kt].h, bb.h, a1, 0, 0, 0);
      }
      if (lg < 2) {
        int col = (16 + idxL) * 16 + lm;
#pragma unroll
        for (int r = 0; r < 4; r++)
          gsh[(lg * 4 + r) * 1204 + col] = a0[r] + a1[r];
      }
    }
    __syncthreads();

    // elementwise: gates contiguous in gsh & gx (col' = 4u+gate)
#pragma unroll
    for (int q = 0; q < 5; q++) {
      if (act[q]) {
        const float4 gs = *(const float4*)&gsh[gsho[q]];
        float gi = gxv[q].x + gs.x;
        float gf = gxv[q].y + gs.y;
        float gg = gxv[q].z + gs.z;
        float go = gxv[q].w + gs.w;
        float si = fsig(gi);
        float sf = fsig(gf);
        float so = fsig(go);
        float cc = sf * crs[q] + si * ftanh(gg);
        float h = so * ftanh(cc);
        crs[q] = cc;
        hA8[hAo[q]] = (_Float16)h;
        if (hist) hist[(size_t)tg * NB * 300 + ho[q]] = h;
        if (hfin && t == 63) hfin[(size_t)dirb * NB * 300 + ho[q]] = h;
      }
    }
    __syncthreads();
  }
}

// ---------------------------------------------------------------------------
__global__ void embed_kernel(
    const int* __restrict__ prem, const int* __restrict__ hyp,
    const float* __restrict__ embW, float* __restrict__ comb)
{
  size_t i = (size_t)blockIdx.x * 256 + threadIdx.x;
  if (i >= (size_t)64 * 256 * 75) return;
  int d4 = (int)(i % 75);
  size_t r = i / 75;
  int n = (int)(r % 256);
  int t = (int)(r / 256);
  int id = (n < 128) ? prem[t * 128 + n] : hyp[t * 128 + (n - 128)];
  float4 v = *(const float4*)(embW + (size_t)id * 300 + d4 * 4);
  *(float4*)(comb + ((size_t)t * 256 + n) * 300 + d4 * 4) = v;
}

// ---------------------------------------------------------------------------
// norm4 v3: one block per (n,dir); W^2 held in per-thread REGISTERS
// (4 wsets x 19 k-slots = 76 VGPR, all compile-time indexed), loaded once.
// Kills the original's 3.1GB mp_W L2 re-read (~90us at 34.5TB/s aggregate)
// WITHOUT round-9's mistake (LDS staging -> serialized one-LDS-pipe/CU,
// 2 reads/FLOP, 761us). Per t: stage 1.2KB h-row in LDS (read once into
// x2 regs), ~95 VALU + 16 shfl. Math identical per element modulo the
// (x*x)(w*w) association, proven absmax-neutral in round 9's passing run.
// ---------------------------------------------------------------------------
__global__ __launch_bounds__(320) void norm4_kernel(
    const float* __restrict__ hs_fw, const float* __restrict__ hs_bw,
    const float* __restrict__ mp_W,
    float* __restrict__ nm4, float* __restrict__ pnorm)
{
  const int n = blockIdx.x, dir = blockIdx.y;
  const float* HS = dir ? hs_bw : hs_fw;
  const int tid = threadIdx.x, g = tid >> 4, lane = tid & 15;
  __shared__ float sh[300];

  // per-thread W^2 registers: w2r[wset][c], k_local = lane + 16c (<300)
  float w2r[4][19];
#pragma unroll
  for (int wset = 0; wset < 4; wset++) {
    const float* W = mp_W + dir * 24000 + wset * 6000 + g * 300;
#pragma unroll
    for (int c = 0; c < 19; c++) {
      int k = lane + 16 * c;
      float w = (k < 300) ? W[k] : 0.f;
      w2r[wset][c] = w * w;
    }
  }

  for (int t = 0; t < 64; t++) {
    __syncthreads();   // protect sh from overwrite while prior readers finish
    for (int k = tid; k < 300; k += 320)
      sh[k] = HS[((size_t)t * 256 + n) * 300 + k];
    __syncthreads();

    float x2[19];
#pragma unroll
    for (int c = 0; c < 19; c++) {
      int k = lane + 16 * c;
      float x = (k < 300) ? sh[k] : 0.f;
      x2[c] = x * x;
    }
    if (g == 0) {
      float s2 = 0.f;
#pragma unroll
      for (int c = 0; c < 19; c++) s2 += x2[c];
      for (int o = 8; o; o >>= 1) s2 += __shfl_down(s2, o, 16);
      if (lane == 0) pnorm[((size_t)dir * 64 + t) * 256 + n] = sqrtf(s2);
    }
#pragma unroll
    for (int wset = 0; wset < 4; wset++) {
      float s1 = 0.f;
#pragma unroll
      for (int c = 0; c < 19; c++) s1 += x2[c] * w2r[wset][c];
      for (int o = 8; o; o >>= 1) s1 += __shfl_down(s1, o, 16);
      if (lane == 0)
        nm4[((((size_t)dir * 4 + wset) * 64 + t) * 256 + n) * 20 + g] = sqrtf(s1);
    }
  }
}

// ---------------------------------------------------------------------------
// att: per (b,z), att[64,64] cosine GEMM -> normalized w (watt) + argmax idx.
// ---------------------------------------------------------------------------
__global__ __launch_bounds__(256) void att_kernel(
    const float* __restrict__ hs_fw, const float* __restrict__ hs_bw,
    const float* __restrict__ pnorm,
    float* __restrict__ watt, int* __restrict__ idxbuf)
{
  const int b = blockIdx.x, z = blockIdx.y;
  const int dir = z & 1;
  const float* HS = dir ? hs_bw : hs_fw;
  const int p_n = (z < 2) ? b : 128 + b;
  const int h_n = (z < 2) ? 128 + b : b;
  const float* pnD = pnorm + (size_t)dir * 16384;

  __shared__ float pch[64 * 100];
  __shared__ float hch[64 * 100];
  __shared__ float att[64 * 65];
  __shared__ float winv_sh[64];

  const int tid = threadIdx.x;
  const int i = tid >> 4, j = tid & 15;
  float acc[4][4];
#pragma unroll
  for (int a = 0; a < 4; a++)
#pragma unroll
    for (int c = 0; c < 4; c++) acc[a][c] = 0.f;

  for (int kc = 0; kc < 300; kc += 100) {
    for (int e = tid; e < 1600; e += 256) {
      int row = e / 25, kq = e - row * 25;
      float4 v = *(const float4*)(HS + ((size_t)row * 256 + p_n) * 300 + kc + kq * 4);
      *(float4*)&pch[row * 100 + kq * 4] = v;
      float4 w = *(const float4*)(HS + ((size_t)row * 256 + h_n) * 300 + kc + kq * 4);
      *(float4*)&hch[row * 100 + kq * 4] = w;
    }
    __syncthreads();
#pragma unroll 5
    for (int kq = 0; kq < 25; kq++) {
      float4 av[4], bv[4];
#pragma unroll
      for (int a = 0; a < 4; a++) av[a] = *(const float4*)&pch[(i + 16 * a) * 100 + kq * 4];
#pragma unroll
      for (int c = 0; c < 4; c++) bv[c] = *(const float4*)&hch[(j + 16 * c) * 100 + kq * 4];
#pragma unroll
      for (int a = 0; a < 4; a++)
#pragma unroll
        for (int c = 0; c < 4; c++)
          acc[a][c] += av[a].x * bv[c].x + av[a].y * bv[c].y + av[a].z * bv[c].z + av[a].w * bv[c].w;
    }
    __syncthreads();
  }

#pragma unroll
  for (int a = 0; a < 4; a++) {
    int t = i + 16 * a;
    float pn = pnD[t * 256 + p_n] + EPSF;
#pragma unroll
    for (int c = 0; c < 4; c++) {
      int s = j + 16 * c;
      float hn = pnD[s * 256 + h_n] + EPSF;
      att[t * 65 + s] = acc[a][c] / (pn * hn);
    }
  }
  __syncthreads();
  if (tid < 64) {
    int t = tid;
    float ssum = 0.f, mx = -1e30f; int mi = 0;
    for (int s = 0; s < 64; s++) {
      float a = att[t * 65 + s];
      ssum += a;
      if (a > mx) { mx = a; mi = s; }
    }
    winv_sh[t] = 1.f / (ssum + EPSF);
    idxbuf[((size_t)z * 128 + b) * 64 + t] = mi;
  }
  __syncthreads();
  for (int e = tid; e < 4096; e += 256) {
    int t = e >> 6, s = e & 63;
    watt[((size_t)z * 128 + b) * 4096 + t * 64 + s] = att[t * 65 + s] * winv_sh[t];
  }
}

// ---------------------------------------------------------------------------
// hmean: per (b,z): hmean[t,k] = sum_s w[t,s]*h[s,k]
// ---------------------------------------------------------------------------
__global__ __launch_bounds__(256) void hmean_kernel(
    const float* __restrict__ hs_fw, const float* __restrict__ hs_bw,
    const float* __restrict__ watt, float* __restrict__ hmeanbuf)
{
  const int b = blockIdx.x, z = blockIdx.y;
  const int dir = z & 1;
  const float* HS = dir ? hs_bw : hs_fw;
  const int h_n = (z < 2) ? 128 + b : b;

  __shared__ float wsh[64 * 65];
  __shared__ float hch[64 * 128];

  const int tid = threadIdx.x;
  const int ti = tid >> 4, kj = tid & 15;
  const float* wsrc = watt + ((size_t)z * 128 + b) * 4096;
  for (int e = tid; e < 4096; e += 256) {
    int t = e >> 6, s = e & 63;
    wsh[t * 65 + s] = wsrc[t * 64 + s];
  }

  for (int kbase = 0; kbase < 300; kbase += 128) {
    int kw = min(128, 300 - kbase);
    int nf4 = kw >> 2;  // 32,32,11
    __syncthreads();
    for (int e = tid; e < 64 * nf4; e += 256) {
      int row = e / nf4, q = e - row * nf4;
      float4 v = *(const float4*)(HS + ((size_t)row * 256 + h_n) * 300 + kbase + q * 4);
      *(float4*)&hch[row * 128 + q * 4] = v;
    }
    __syncthreads();
    float acc[4][8];
#pragma unroll
    for (int a = 0; a < 4; a++)
#pragma unroll
      for (int c = 0; c < 8; c++) acc[a][c] = 0.f;
    for (int s = 0; s < 64; s++) {
      float4 h0 = *(const float4*)&hch[s * 128 + 4 * kj];
      float4 h1 = *(const float4*)&hch[s * 128 + 4 * (kj + 16)];
#pragma unroll
      for (int a = 0; a < 4; a++) {
        float w = wsh[(4 * ti + a) * 65 + s];
        acc[a][0] += w * h0.x; acc[a][1] += w * h0.y; acc[a][2] += w * h0.z; acc[a][3] += w * h0.w;
        acc[a][4] += w * h1.x; acc[a][5] += w * h1.y; acc[a][6] += w * h1.z; acc[a][7] += w * h1.w;
      }
    }
#pragma unroll
    for (int a = 0; a < 4; a++) {
      int t = 4 * ti + a;
#pragma unroll
      for (int c = 0; c < 2; c++) {
        int kq = kj + 16 * c;
        if (kq * 4 < kw) {
          int k = kbase + kq * 4;
          float4 v = make_float4(acc[a][4 * c], acc[a][4 * c + 1], acc[a][4 * c + 2], acc[a][4 * c + 3]);
          *(float4*)&hmeanbuf[(((size_t)z * 128 + b) * 64 + t) * 300 + k] = v;
        }
      }
    }
  }
}

// ---------------------------------------------------------------------------
// maxp via MFMA f16 (round-5 WIN): per (b,z) ONE block; x = l*64+t tiling;
// A-frag = p-frag (*) w2[l]-frag; h-frags reg-cached per st-pair.
// ---------------------------------------------------------------------------
#define MAXP_LDS_BYTES (41984 + 41984 + 13120 + 5120 + 5120)  // 107,328

__global__ __launch_bounds__(512, 2) void maxp_mfma(
    const float* __restrict__ hs_fw, const float* __restrict__ hs_bw,
    const float* __restrict__ mp_W, const float* __restrict__ nm4,
    float* __restrict__ m_out)
{
  extern __shared__ char smem[];
  _Float16* pA = (_Float16*)smem;                     // [64][328]
  _Float16* hB = (_Float16*)(smem + 41984);           // [64][328]
  _Float16* w2h = (_Float16*)(smem + 83968);          // [20][328]
  float* pn_sh = (float*)(smem + 97088);              // [64][20]
  float* hn_sh = (float*)(smem + 102208);             // [64][20]

  const int b = blockIdx.x, z = blockIdx.y;
  const int dir = z & 1;
  const float* HS = dir ? hs_bw : hs_fw;
  const int p_n = (z < 2) ? b : 128 + b;
  const int h_n = (z < 2) ? 128 + b : b;
  const float* Wm = mp_W + dir * 24000 + 6000;
  const float* nmD = nm4 + ((size_t)dir * 4 + 1) * 327680;

  const int tid = threadIdx.x;
  const int wv = tid >> 6, lane = tid & 63;
  const int lm = lane & 15, lg = lane >> 4;

  // ---- stage p, h (f32->f16), w2 (squared f16), pn, hn ----
  for (int e = tid; e < 4800; e += 512) {
    int row = e / 75, q = e - row * 75;
    float4 v = *(const float4*)(HS + ((size_t)row * 256 + p_n) * 300 + q * 4);
    float4 w = *(const float4*)(HS + ((size_t)row * 256 + h_n) * 300 + q * 4);
    _Float16* pd = &pA[row * 328 + q * 4];
    pd[0] = (_Float16)v.x; pd[1] = (_Float16)v.y; pd[2] = (_Float16)v.z; pd[3] = (_Float16)v.w;
    _Float16* hd = &hB[row * 328 + q * 4];
    hd[0] = (_Float16)w.x; hd[1] = (_Float16)w.y; hd[2] = (_Float16)w.z; hd[3] = (_Float16)w.w;
  }
  for (int e = tid; e < 64 * 28; e += 512) {
    int row = e / 28, c = 300 + (e - row * 28);
    pA[row * 328 + c] = (_Float16)0.f;
    hB[row * 328 + c] = (_Float16)0.f;
  }
  for (int e = tid; e < 1500; e += 512) {
    int row = e / 75, q = e - row * 75;
    float4 w = *(const float4*)(Wm + (size_t)row * 300 + q * 4);
    _Float16* d = &w2h[row * 328 + q * 4];
    d[0] = (_Float16)(w.x * w.x); d[1] = (_Float16)(w.y * w.y);
    d[2] = (_Float16)(w.z * w.z); d[3] = (_Float16)(w.w * w.w);
  }
  for (int e = tid; e < 20 * 28; e += 512) {
    int row = e / 28, c = 300 + (e - row * 28);
    w2h[row * 328 + c] = (_Float16)0.f;
  }
  for (int e = tid; e < 1280; e += 512) {
    int tq = e / 20, l = e - tq * 20;
    pn_sh[e] = nmD[((size_t)tq * 256 + p_n) * 20 + l];
    hn_sh[e] = nmD[((size_t)tq * 256 + h_n) * 20 + l];
  }
  __syncthreads();

  // ---- compute: wave wv owns x-tiles xt = wv + 8i (10 tiles) ----
  float rmax[10][4];
#pragma unroll
  for (int i = 0; i < 10; i++)
#pragma unroll
    for (int r = 0; r < 4; r++) rmax[i][r] = -1e30f;

#pragma unroll
  for (int sp = 0; sp < 2; sp++) {       // st pairs {0,1},{2,3}
    U4H8 hf[2][10];
#pragma unroll
    for (int hh = 0; hh < 2; hh++)
#pragma unroll
      for (int kt = 0; kt < 10; kt++)
        hf[hh][kt].u = *(const uint4*)&hB[(sp * 32 + hh * 16 + lm) * 328 + kt * 32 + lg * 8];

#pragma unroll
    for (int i = 0; i < 10; i++) {
      int xt = wv + 8 * i;               // 0..79
      int l = xt >> 2, t0 = (xt & 3) << 4;
      U4H8 af[10];
#pragma unroll
      for (int kt = 0; kt < 10; kt++) {
        U4H8 pf, wf;
        pf.u = *(const uint4*)&pA[(t0 + lm) * 328 + kt * 32 + lg * 8];
        wf.u = *(const uint4*)&w2h[l * 328 + kt * 32 + lg * 8];
        af[kt].h = pf.h * wf.h;          // v_pk_mul_f16
      }
      float pnv[4];
#pragma unroll
      for (int r = 0; r < 4; r++) pnv[r] = pn_sh[(t0 + lg * 4 + r) * 20 + l];
#pragma unroll
      for (int hh = 0; hh < 2; hh++) {
        int st = sp * 2 + hh;
        f32x4v acc = {0.f, 0.f, 0.f, 0.f};
#pragma unroll
        for (int kt = 0; kt < 10; kt++)
          acc = __builtin_amdgcn_mfma_f32_16x16x32_f16(af[kt].h, hf[hh][kt].h, acc, 0, 0, 0);
        float hn = hn_sh[(st * 16 + lm) * 20 + l];
#pragma unroll
        for (int r = 0; r < 4; r++) {
          float val = acc[r] * __builtin_amdgcn_rcpf(pnv[r] * hn + EPSF);
          rmax[i][r] = fmaxf(rmax[i][r], val);
        }
      }
    }
  }

  // ---- cross-lane max over s (16-lane groups) + write ----
#pragma unroll
  for (int i = 0; i < 10; i++) {
    int xt = wv + 8 * i;
    int l = xt >> 2, t0 = (xt & 3) << 4;
#pragma unroll
    for (int r = 0; r < 4; r++) {
      float v = rmax[i][r];
#pragma unroll
      for (int off = 8; off; off >>= 1) v = fmaxf(v, __shfl_down(v, off, 16));
      if (lm == 0) {
        int t = t0 + lg * 4 + r;
        m_out[((size_t)t * 128 + b) * 320 + z * 80 + 20 + l] = v;
      }
    }
  }
}

// ---------------------------------------------------------------------------
// rest: per (b,z): full / attm / maxattm for all t. W^2 staged once in LDS.
// ---------------------------------------------------------------------------
__global__ __launch_bounds__(320) void rest_kernel(
    const float* __restrict__ hs_fw, const float* __restrict__ hs_bw,
    const float* __restrict__ mp_W, const float* __restrict__ nm4,
    const float* __restrict__ hmeanbuf, const int* __restrict__ idxbuf,
    float* __restrict__ m_out)
{
  const int b = blockIdx.x, z = blockIdx.y;
  const int dir = z & 1;
  const float* HS = dir ? hs_bw : hs_fw;
  const int p_n = (z < 2) ? b : 128 + b;
  const int h_n = (z < 2) ? 128 + b : b;
  const int v_t = dir ? 0 : 63;

  __shared__ float w2f[6000], w2a[6000], w2m[6000];
  __shared__ float vsh[300], psh[300], hmsh[300], hxsh[300];

  const int tid = threadIdx.x;
  const int g = tid >> 4, lane = tid & 15;
  const float* Wf = mp_W + dir * 24000;
  const float* Wa = Wf + 12000;
  const float* Wma = Wf + 18000;
  for (int e = tid; e < 6000; e += 320) {
    float a = Wf[e], bb = Wa[e], c = Wma[e];
    w2f[e] = a * a; w2a[e] = bb * bb; w2m[e] = c * c;
  }
  for (int e = tid; e < 300; e += 320)
    vsh[e] = HS[((size_t)v_t * 256 + h_n) * 300 + e];
  __syncthreads();

  const float* base0 = nm4 + ((size_t)dir * 4 + 0) * 327680;
  const float* base2 = nm4 + ((size_t)dir * 4 + 2) * 327680;
  const float* base3 = nm4 + ((size_t)dir * 4 + 3) * 327680;
  const float vnf = base0[((size_t)v_t * 256 + h_n) * 20 + g];

  for (int t = 0; t < 64; t++) {
    int idx = idxbuf[((size_t)z * 128 + b) * 64 + t];
    __syncthreads();
    for (int e = tid; e < 300; e += 320) {
      psh[e] = HS[((size_t)t * 256 + p_n) * 300 + e];
      hmsh[e] = hmeanbuf[(((size_t)z * 128 + b) * 64 + t) * 300 + e];
      hxsh[e] = HS[((size_t)idx * 256 + h_n) * 300 + e];
    }
    __syncthreads();
    float nf = 0.f, na = 0.f, qa = 0.f, nm = 0.f;
#pragma unroll
    for (int c = 0; c < 5; c++) {
      int k4 = lane + 16 * c;
      if (k4 < 75) {
        float4 p = *(const float4*)&psh[4 * k4];
        float4 v = *(const float4*)&vsh[4 * k4];
        float4 hm = *(const float4*)&hmsh[4 * k4];
        float4 hx = *(const float4*)&hxsh[4 * k4];
        float4 wf = *(const float4*)&w2f[g * 300 + 4 * k4];
        float4 wa = *(const float4*)&w2a[g * 300 + 4 * k4];
        float4 wm = *(const float4*)&w2m[g * 300 + 4 * k4];
        nf += p.x * v.x * wf.x + p.y * v.y * wf.y + p.z * v.z * wf.z + p.w * v.w * wf.w;
        na += p.x * hm.x * wa.x + p.y * hm.y * wa.y + p.z * hm.z * wa.z + p.w * hm.w * wa.w;
        qa += hm.x * hm.x * wa.x + hm.y * hm.y * wa.y + hm.z * hm.z * wa.z + hm.w * hm.w * wa.w;
        nm += p.x * hx.x * wm.x + p.y * hx.y * wm.y + p.z * hx.z * wm.z + p.w * hx.w * wm.w;
      }
    }
#pragma unroll
    for (int o = 8; o; o >>= 1) {
      nf += __shfl_down(nf, o);
      na += __shfl_down(na, o);
      qa += __shfl_down(qa, o);
      nm += __shfl_down(nm, o);
    }
    if (lane == 0) {
      float pnf = base0[((size_t)t * 256 + p_n) * 20 + g];
      float pna = base2[((size_t)t * 256 + p_n) * 20 + g];
      float pnm = base3[((size_t)t * 256 + p_n) * 20 + g];
      float qnm = base3[((size_t)idx * 256 + h_n) * 20 + g];
      float* mrow = m_out + ((size_t)t * 128 + b) * 320 + z * 80;
      mrow[g] = nf / (pnf * vnf + EPSF);
      mrow[40 + g] = na / (pna * sqrtf(qa) + EPSF);
      mrow[60 + g] = nm / (pnm * qnm + EPSF);
    }
  }
}

// ---------------------------------------------------------------------------
__global__ __launch_bounds__(256) void mlp_kernel(
    const float* __restrict__ shA0, const float* __restrict__ shA1,
    const float* __restrict__ bnG, const float* __restrict__ bnB,
    const float* __restrict__ W1, const float* __restrict__ b1,
    const float* __restrict__ W2, const float* __restrict__ b2,
    const float* __restrict__ outW, const float* __restrict__ outb,
    float* __restrict__ out)
{
  const int b = blockIdx.x;
  const int tid = threadIdx.x;
  __shared__ float x0[600], x1[600];
  const float inv = 1.0f / sqrtf(1.0f + 1e-5f);
  for (int j = tid; j < 600; j += 256) {
    float v = (j < 300) ? shA0[b * 300 + j] : shA1[b * 300 + (j - 300)];
    x0[j] = bnG[j] * v * inv + bnB[j];
  }
  __syncthreads();
  for (int j = tid; j < 600; j += 256) {
    float acc = b1[j];
    const float* w = W1 + (size_t)j * 600;
    for (int k = 0; k < 600; k++) acc += x0[k] * w[k];
    float r = fmaxf(acc, 0.f);
    x1[j] = bnG[600 + j] * r * inv + bnB[600 + j];
  }
  __syncthreads();
  for (int j = tid; j < 600; j += 256) {
    float acc = b2[j];
    const float* w = W2 + (size_t)j * 600;
    for (int k = 0; k < 600; k++) acc += x1[k] * w[k];
    float r = fmaxf(acc, 0.f);
    x0[j] = bnG[1200 + j] * r * inv + bnB[1200 + j];
  }
  __syncthreads();
  if (tid < 3) {
    float acc = outb[tid];
    const float* w = outW + tid * 600;
    for (int k = 0; k < 600; k++) acc += x0[k] * w[k];
    out[b * 3 + tid] = acc;
  }
}

// ---------------------------------------------------------------------------
extern "C" void kernel_launch(void* const* d_in, const int* in_sizes, int n_in,
                              void* d_out, int out_size, void* d_ws, size_t ws_size,
                              hipStream_t stream) {
  const int* premise = (const int*)d_in[0];
  const int* hypothesis = (const int*)d_in[1];
  const float* embW = (const float*)d_in[2];
  const float* cWih = (const float*)d_in[3];
  const float* cWhh = (const float*)d_in[4];
  const float* cb = (const float*)d_in[5];
  const float* mpW = (const float*)d_in[6];
  const float* aWihF = (const float*)d_in[7];
  const float* aWhhF = (const float*)d_in[8];
  const float* abF = (const float*)d_in[9];
  const float* aWihB = (const float*)d_in[10];
  const float* aWhhB = (const float*)d_in[11];
  const float* abB = (const float*)d_in[12];
  const float* bnG = (const float*)d_in[13];
  const float* bnB = (const float*)d_in[14];
  const float* W1 = (const float*)d_in[15];
  const float* b1 = (const float*)d_in[16];
  const float* W2 = (const float*)d_in[17];
  const float* b2 = (const float*)d_in[18];
  const float* outW = (const float*)d_in[19];
  const float* outb = (const float*)d_in[20];
  float* out = (float*)d_out;

  float* ws = (float*)d_ws;
  // workspace layout (floats)
  float* comb  = ws + 0;           // 4,915,200  (T,256,300); WB packs + aWih perms overlay after ctx-gates GEMM
  float* gates = ws + 4915200;     // 19,660,800 (T,256,1200); overlaid after ctx LSTM
  float* hsfw  = ws + 24576000;    // 4,915,200  (cWih perm overlays here pre-LSTM)
  float* hsbw  = ws + 29491200;    // 4,915,200
  float* pnorm = ws + 34406400;    // 32,768    [2][64][256]
  float* mbuf  = ws + 35094528;    // 2,621,440 (T,128,320)
  float* sha   = ws + 38023168;    // 76,800    agg final h [2][128][300]

  // packed MFMA B-fragment weights overlay in comb region (dead after ctx-gates GEMM)
  uint4* WBctx = (uint4*)comb;
  uint4* WBaf  = (uint4*)(comb + 192000);
  uint4* WBab  = (uint4*)(comb + 384000);
  // gate-interleaved agg input weights (dead comb region, after WB packs)
  float* aWihFP = comb + 576000;   // 384,000
  float* aWihBP = comb + 960000;   // 384,000
  float* abFP   = comb + 1344000;  // 1,200
  float* abBP   = comb + 1345200;  // 1,200

  // gate-interleaved ctx input weights: hsfw region is dead until ctx LSTM
  float* cWihP = hsfw;             // 360,000
  float* cbP   = hsfw + 360000;    // 1,200

  // overlays inside the dead ctx-gates region (valid between ctx LSTM and agg GEMMs)
  float* watt     = gates;                 // 2,097,152 [4][128][64][64]
  float* hmeanbuf = gates + 2097152;       // 9,830,400 [4][128][64][300]
  int*   idxbuf   = (int*)(gates + 11927552); // 32,768 [4][128][64]
  float* nm4      = gates + 11960320;      // 2,621,440 [2][4][64][256][20]

  // allow >64KB dynamic LDS (gfx950 pool = 160KB/WG)
  hipFuncSetAttribute((const void*)lstm_res,
                      hipFuncAttributeMaxDynamicSharedMemorySize, LSTM_LDS_BYTES);
  hipFuncSetAttribute((const void*)maxp_mfma,
                      hipFuncAttributeMaxDynamicSharedMemorySize, MAXP_LDS_BYTES);
  hipFuncSetAttribute((const void*)gemm_mfma_nt,
                      hipFuncAttributeMaxDynamicSharedMemorySize, GMM_LDS_BYTES);

  // 1) embed + ctx input-weight gate-interleave
  embed_kernel<<<dim3(4800), dim3(256), 0, stream>>>(premise, hypothesis, embW, comb);
  permW_kernel<<<dim3(1200), dim3(256), 0, stream>>>(cWih, cb, cWihP, cbP, 300);

  // 2) ctx input gates (consumes comb) — split-f16 MFMA, fp32-grade accuracy
  gemm_mfma_nt<<<dim3(5, 128, 1), dim3(512), GMM_LDS_BYTES, stream>>>(
      comb, cWihP, cbP, gates, nullptr, nullptr, nullptr, 16384, 300);

  // 3) pack recurrent weights into MFMA B-fragment stream (dead comb region)
  //    + gate-interleave the agg input weights
  packB_kernel<<<dim3(188, 3), dim3(256), 0, stream>>>(
      cWhh, aWhhF, aWhhB, WBctx, WBaf, WBab);
  permW_kernel<<<dim3(1200), dim3(256), 0, stream>>>(aWihF, abF, aWihFP, abFP, 320);
  permW_kernel<<<dim3(1200), dim3(256), 0, stream>>>(aWihB, abB, aWihBP, abBP, 320);

  // 4) context LSTM: 16 reg + 11 LDS tiles resident, 48 streamed (r6 config)
  lstm_res<<<dim3(64), dim3(512), LSTM_LDS_BYTES, stream>>>(
      WBctx, WBctx, gates, gates, hsfw, hsbw, nullptr, 256);

  // 5) norms — v3: per (n,dir), W^2 in registers (no mp_W re-read, no LDS
  //    serialization; round-9's failure mode structurally absent)
  norm4_kernel<<<dim3(256, 2), dim3(320), 0, stream>>>(hsfw, hsbw, mpW, nm4, pnorm);

  // 6) matching pipeline
  att_kernel<<<dim3(128, 4), dim3(256), 0, stream>>>(hsfw, hsbw, pnorm, watt, idxbuf);
  hmean_kernel<<<dim3(128, 4), dim3(256), 0, stream>>>(hsfw, hsbw, watt, hmeanbuf);
  maxp_mfma<<<dim3(128, 4), dim3(512), MAXP_LDS_BYTES, stream>>>(
      hsfw, hsbw, mpW, nm4, mbuf);
  rest_kernel<<<dim3(128, 4), dim3(320), 0, stream>>>(hsfw, hsbw, mpW, nm4, hmeanbuf, idxbuf, mbuf);

  // 7) agg input gates — split-f16 MFMA, BOTH directions in ONE launch (z)
  float* gaf = gates;
  float* gab = gates + 9830400;
  gemm_mfma_nt<<<dim3(5, 64, 2), dim3(512), GMM_LDS_BYTES, stream>>>(
      mbuf, aWihFP, abFP, gaf, aWihBP, abBP, gab, 8192, 320);

  // 8) aggregation LSTM: 32 blocks (16/dir), 8 waves
  lstm_res<<<dim3(32), dim3(512), LSTM_LDS_BYTES, stream>>>(
      WBaf, WBab, gaf, gab, nullptr, nullptr, sha, 128);

  // 9) MLP head
  mlp_kernel<<<dim3(128), dim3(256), 0, stream>>>(
      sha, sha + 38400, bnG, bnB, W1, b1, W2, b2, outW, outb, out);
}

// Round 14
// 1698.841 us; speedup vs baseline: 1.4156x; 1.0243x over previous
//
#include <hip/hip_runtime.h>
#include <cstddef>
#include <cstdint>
#include <math.h>

#define EPSF 1e-8f

// Model dims (fixed): T=64, B=128, D=300, H=300, L=20, AH=300, N2=2B=256

typedef _Float16 half8v __attribute__((ext_vector_type(8)));
typedef float f32x4v __attribute__((ext_vector_type(4)));
union U4H8 { uint4 u; half8v h; _Float16 e[8]; };

// fast device math: v_exp_f32 + v_rcp_f32 (rel err ~1e-7, fine for 3e-3 budget)
__device__ __forceinline__ float fsig(float x) {
  float e = __expf(-x);
  return __builtin_amdgcn_rcpf(1.f + e);
}
__device__ __forceinline__ float ftanh(float x) {
  float e = __expf(-2.f * fabsf(x));
  float r = (1.f - e) * __builtin_amdgcn_rcpf(1.f + e);
  return copysignf(r, x);
}

// asm-opaque 16B load: result cannot be re-materialized by the compiler ->
// forces true register residency. SAFE ONLY at low register pressure:
// 2 tiles/wave (80 pinned VGPR) fits; 3 tiles/wave spills — round-7
// (corrupt: spill before external wait) and round-10 (correct with internal
// wait but slow: scratch re-loads every step, 370->498us). 2 tiles is final.
__device__ __forceinline__ uint4 gld16(const uint4* p) {
  uint4 r;
  asm volatile("global_load_dwordx4 %0, %1, off" : "=v"(r) : "v"(p));
  return r;
}

// ---------------------------------------------------------------------------
// Split-f16 MFMA NT GEMM (round-6 WIN): C = bias + A*B^T, fp32-grade via
// A=Ah+Al, B=Bh+Bl, C ~= AhBh+AlBh+AhBl (dropped AlBl ~2^-22).
// Tile 128x240, N=1200=5x240; 512 thr; LDS pitch-72 hi/lo staging.
// Round-12: optional second (B,bias,C) set selected by blockIdx.z so the two
// agg-gate GEMMs run as ONE launch (round-13 verified).
// ---------------------------------------------------------------------------
#define GMM_LDS_BYTES (2 * (128 * 72 * 2) + 2 * (240 * 72 * 2))  // 105,984

__global__ __launch_bounds__(512, 1) void gemm_mfma_nt(
    const float* __restrict__ A, const float* __restrict__ B,
    const float* __restrict__ bias, float* __restrict__ C,
    const float* __restrict__ B2, const float* __restrict__ bias2,
    float* __restrict__ C2,
    int M, int K)
{
  extern __shared__ char smem[];
  _Float16* Ah = (_Float16*)smem;                       // [128][72]
  _Float16* Al = (_Float16*)(smem + 18432);             // [128][72]
  _Float16* Bh = (_Float16*)(smem + 36864);             // [240][72]
  _Float16* Bl = (_Float16*)(smem + 36864 + 34560);     // [240][72]

  const float* Bp = B;
  const float* biasp = bias;
  float* Cp = C;
  if (blockIdx.z == 1) { Bp = B2; biasp = bias2; Cp = C2; }

  const int tid = threadIdx.x;
  const int wv = tid >> 6, lane = tid & 63;
  const int lm = lane & 15, lg = lane >> 4;
  const int mbase = blockIdx.y << 7;
  const int nbase = blockIdx.x * 240;

  f32x4v acc[15];
#pragma unroll
  for (int nt = 0; nt < 15; nt++) acc[nt] = (f32x4v){0.f, 0.f, 0.f, 0.f};

  const int nchunk = (K + 63) >> 6;
  for (int c = 0; c < nchunk; c++) {
    const int kc = c << 6;
    // stage A 128x64 -> hi/lo f16
    for (int e = tid; e < 2048; e += 512) {
      int row = e >> 4, q = e & 15;
      int k = kc + q * 4;
      const float* src = A + (size_t)(mbase + row) * K;
      float4 v = make_float4(0.f, 0.f, 0.f, 0.f);
      if (k + 4 <= K) {
        v = *(const float4*)(src + k);
      } else {
        if (k + 0 < K) v.x = src[k + 0];
        if (k + 1 < K) v.y = src[k + 1];
        if (k + 2 < K) v.z = src[k + 2];
        if (k + 3 < K) v.w = src[k + 3];
      }
      _Float16 hx = (_Float16)v.x, hy = (_Float16)v.y,
               hz = (_Float16)v.z, hw = (_Float16)v.w;
      _Float16* d = &Ah[row * 72 + q * 4];
      d[0] = hx; d[1] = hy; d[2] = hz; d[3] = hw;
      _Float16* dl = &Al[row * 72 + q * 4];
      dl[0] = (_Float16)(v.x - (float)hx); dl[1] = (_Float16)(v.y - (float)hy);
      dl[2] = (_Float16)(v.z - (float)hz); dl[3] = (_Float16)(v.w - (float)hw);
    }
    // stage B 240x64 -> hi/lo f16
    for (int e = tid; e < 3840; e += 512) {
      int row = e >> 4, q = e & 15;
      int k = kc + q * 4;
      const float* src = Bp + (size_t)(nbase + row) * K;
      float4 v = make_float4(0.f, 0.f, 0.f, 0.f);
      if (k + 4 <= K) {
        v = *(const float4*)(src + k);
      } else {
        if (k + 0 < K) v.x = src[k + 0];
        if (k + 1 < K) v.y = src[k + 1];
        if (k + 2 < K) v.z = src[k + 2];
        if (k + 3 < K) v.w = src[k + 3];
      }
      _Float16 hx = (_Float16)v.x, hy = (_Float16)v.y,
               hz = (_Float16)v.z, hw = (_Float16)v.w;
      _Float16* d = &Bh[row * 72 + q * 4];
      d[0] = hx; d[1] = hy; d[2] = hz; d[3] = hw;
      _Float16* dl = &Bl[row * 72 + q * 4];
      dl[0] = (_Float16)(v.x - (float)hx); dl[1] = (_Float16)(v.y - (float)hy);
      dl[2] = (_Float16)(v.z - (float)hz); dl[3] = (_Float16)(v.w - (float)hw);
    }
    __syncthreads();

#pragma unroll
    for (int kt = 0; kt < 2; kt++) {
      U4H8 ah, al;
      ah.u = *(const uint4*)&Ah[(wv * 16 + lm) * 72 + kt * 32 + lg * 8];
      al.u = *(const uint4*)&Al[(wv * 16 + lm) * 72 + kt * 32 + lg * 8];
#pragma unroll
      for (int nt = 0; nt < 15; nt++) {
        U4H8 bh, bl;
        bh.u = *(const uint4*)&Bh[(nt * 16 + lm) * 72 + kt * 32 + lg * 8];
        bl.u = *(const uint4*)&Bl[(nt * 16 + lm) * 72 + kt * 32 + lg * 8];
        acc[nt] = __builtin_amdgcn_mfma_f32_16x16x32_f16(ah.h, bh.h, acc[nt], 0, 0, 0);
        acc[nt] = __builtin_amdgcn_mfma_f32_16x16x32_f16(al.h, bh.h, acc[nt], 0, 0, 0);
        acc[nt] = __builtin_amdgcn_mfma_f32_16x16x32_f16(ah.h, bl.h, acc[nt], 0, 0, 0);
      }
    }
    __syncthreads();
  }

  // epilogue: D col = nbase+nt*16+lm, row m = mbase+wv*16+lg*4+r
#pragma unroll
  for (int nt = 0; nt < 15; nt++) {
    int col = nbase + nt * 16 + lm;
    float bv = biasp[col];
#pragma unroll
    for (int r = 0; r < 4; r++) {
      int m = mbase + wv * 16 + lg * 4 + r;
      Cp[(size_t)m * 1200 + col] = acc[nt][r] + bv;
    }
  }
}

// ---------------------------------------------------------------------------
// permW: permute Wih rows to gate-interleaved order (row' = 4u+gate).
// ---------------------------------------------------------------------------
__global__ __launch_bounds__(256) void permW_kernel(
    const float* __restrict__ W, const float* __restrict__ bias,
    float* __restrict__ Wp, float* __restrict__ bp, int K)
{
  int r = blockIdx.x;              // 0..1199 = col' = 4u+gate
  int gate = r & 3, u = r >> 2;
  int src = gate * 300 + u;
  const float* s = W + (size_t)src * K;
  float* d = Wp + (size_t)r * K;
  for (int c = threadIdx.x; c < K; c += 256) d[c] = s[c];
  if (threadIdx.x == 0) bp[r] = bias[src];
}

// ---------------------------------------------------------------------------
// packB: W (1200,300) fp32 -> MFMA B-fragment stream for 16x16x32_f16.
// Gate-interleaved column order col' = 4*u + gate  (orig n = gate*300+u).
// Item i = (nt*10+kt)*64 + lane.
// ---------------------------------------------------------------------------
__global__ __launch_bounds__(256) void packB_kernel(
    const float* __restrict__ W0, const float* __restrict__ W1,
    const float* __restrict__ W2,
    uint4* __restrict__ T0, uint4* __restrict__ T1, uint4* __restrict__ T2)
{
  int i = blockIdx.x * 256 + threadIdx.x;
  if (i >= 48000) return;
  const float* W = (blockIdx.y == 0) ? W0 : (blockIdx.y == 1) ? W1 : W2;
  uint4* T = (blockIdx.y == 0) ? T0 : (blockIdx.y == 1) ? T1 : T2;
  int lane = i & 63;
  int tile = i >> 6;               // nt*10 + kt
  int nt = tile / 10, kt = tile - nt * 10;
  int lm = lane & 15, lg = lane >> 4;
  int colp = nt * 16 + lm;
  int u = colp >> 2, gate = colp & 3;
  int n = gate * 300 + u;
  U4H8 v;
#pragma unroll
  for (int j = 0; j < 8; j++) {
    int k = kt * 32 + lg * 8 + j;
    float x = (k < 300) ? W[(size_t)n * 300 + k] : 0.f;
    v.e[j] = (_Float16)x;
  }
  T[i] = v.u;
}

// ---------------------------------------------------------------------------
// Persistent LSTM via MFMA, partial weight residency (round-6 verified
// config — measured 370-380us/dispatch across five benches):
//   - 16 tiles in REGISTERS (2/wave) via asm-opaque gld16;
//   - 11 tiles in dynamic LDS (nt = 16..26);
//   - 48 tiles streamed (nt = 27+wv+8i, 6/wave), 491KB/step at the
//     ~35 B/cyc/CU L1-fill wall = the structural floor for this schedule.
// 3 tiles/wave is dead: r7 corrupt (spill before wait), r10 slow (spills
// re-loaded from scratch every step, 370->498us).
// LDS: hA8 5.25KB + gsh 38.5KB + bls 112.6KB = 156.4KB.
// ---------------------------------------------------------------------------
#define LSTM_LDS_BYTES (5248 + 38528 + 11 * 10240)   // 156,416

__global__ __launch_bounds__(512, 2) void lstm_res(
    const uint4* WB0, const uint4* WB1,   // packed B-frags; no __restrict__
    const float* __restrict__ gx0, const float* __restrict__ gx1, // (64,NB,1200) interleaved
    float* hist0, float* hist1,           // (64,NB,300) or null; no __restrict__
    float* hfin,                          // (2,NB,300) or null
    int NB)
{
  extern __shared__ char smem[];
  _Float16* hA8 = (_Float16*)smem;                    // [8][328]
  float* gsh = (float*)(smem + 5248);                 // [8][1204]
  uint4* bls = (uint4*)(smem + 5248 + 38528);         // [11][640]

  const int b = blockIdx.x;
  const int xcd = b & 7;
  const int grp = b >> 3;
  const int dirb = xcd >> 2;
  const int n0 = (grp * 4 + (xcd & 3)) * 8;
  const int tid = threadIdx.x;
  const int wv = tid >> 6, lane = tid & 63;
  const int lm = lane & 15, lg = lane >> 4;

  const uint4* WB = dirb ? WB1 : WB0;
  const float* gx = dirb ? gx1 : gx0;
  float* hist = dirb ? hist1 : hist0;

  // --- register-resident tiles nt = wv, wv+8 (asm-opaque, pinned) ---
  U4H8 br0[10], br1[10];
  {
    const uint4* p0 = WB + (size_t)(wv * 10) * 64 + lane;
    const uint4* p1 = WB + (size_t)((wv + 8) * 10) * 64 + lane;
#pragma unroll
    for (int kt = 0; kt < 10; kt++) br0[kt].u = gld16(p0 + kt * 64);
#pragma unroll
    for (int kt = 0; kt < 10; kt++) br1[kt].u = gld16(p1 + kt * 64);
  }
  // --- LDS-resident tiles 16..26 (contiguous in WB): 11*640 uint4 ---
  for (int e = tid; e < 7040; e += 512) bls[e] = WB[16 * 640 + e];
  for (int e = tid; e < 8 * 328; e += 512) hA8[e] = (_Float16)0.f;
  asm volatile("s_waitcnt vmcnt(0)" ::: "memory");
  __builtin_amdgcn_sched_barrier(0);
  __syncthreads();

  // --- t-invariant elementwise indices: e = tid + q*512 -> (m,u) ---
  int gxo[5], gsho[5], hAo[5], ho[5];
  bool act[5];
#pragma unroll
  for (int q = 0; q < 5; q++) {
    int e = tid + q * 512;
    act[q] = (e < 2400);
    int m = act[q] ? (e / 300) : 0;
    int u = act[q] ? (e - m * 300) : 0;
    gxo[q] = (n0 + m) * 1200 + 4 * u;
    gsho[q] = m * 1204 + 4 * u;
    hAo[q] = m * 328 + u;
    ho[q] = (n0 + m) * 300 + u;
  }

  float crs[5] = {0.f, 0.f, 0.f, 0.f, 0.f};

  for (int t = 0; t < 64; t++) {
    const int tg = dirb ? (63 - t) : t;
    const size_t gxstep = (size_t)tg * NB * 1200;

    // prefetch x-gates (interleaved i,f,g,o), consumed post-barrier
    float4 gxv[5];
#pragma unroll
    for (int q = 0; q < 5; q++) {
      gxv[q] = make_float4(0.f, 0.f, 0.f, 0.f);
      if (act[q]) gxv[q] = *(const float4*)(gx + gxstep + gxo[q]);
    }

    // stream preload: first half of first streamed tile (nt = 27+wv)
    uint4 bA[5], bB[5];
#pragma unroll
    for (int kt = 0; kt < 5; kt++)
      bA[kt] = WB[(size_t)((27 + wv) * 10 + kt) * 64 + lane];

    // A fragments (rows 8-15 are zero: no LDS read for lm>=8)
    U4H8 af[10];
#pragma unroll
    for (int kt = 0; kt < 10; kt++) {
      uint4 v = make_uint4(0u, 0u, 0u, 0u);
      if (lm < 8) v = *(const uint4*)&hA8[lm * 328 + kt * 32 + lg * 8];
      af[kt].u = v;
    }

    // register-resident tiles (pure MFMA, hides in-flight stream loads)
    {
      f32x4v a0 = {0.f, 0.f, 0.f, 0.f};
      f32x4v a1 = {0.f, 0.f, 0.f, 0.f};
#pragma unroll
      for (int kt = 0; kt < 5; kt++)
        a0 = __builtin_amdgcn_mfma_f32_16x16x32_f16(af[kt].h, br0[kt].h, a0, 0, 0, 0);
#pragma unroll
      for (int kt = 5; kt < 10; kt++)
        a1 = __builtin_amdgcn_mfma_f32_16x16x32_f16(af[kt].h, br0[kt].h, a1, 0, 0, 0);
      if (lg < 2) {
        int col = wv * 16 + lm;
#pragma unroll
        for (int r = 0; r < 4; r++)
          gsh[(lg * 4 + r) * 1204 + col] = a0[r] + a1[r];
      }
    }
    {
      f32x4v a0 = {0.f, 0.f, 0.f, 0.f};
      f32x4v a1 = {0.f, 0.f, 0.f, 0.f};
#pragma unroll
      for (int kt = 0; kt < 5; kt++)
        a0 = __builtin_amdgcn_mfma_f32_16x16x32_f16(af[kt].h, br1[kt].h, a0, 0, 0, 0);
#pragma unroll
      for (int kt = 5; kt < 10; kt++)
        a1 = __builtin_amdgcn_mfma_f32_16x16x32_f16(af[kt].h, br1[kt].h, a1, 0, 0, 0);
      if (lg < 2) {
        int col = (wv + 8) * 16 + lm;
#pragma unroll
        for (int r = 0; r < 4; r++)
          gsh[(lg * 4 + r) * 1204 + col] = a0[r] + a1[r];
      }
    }

    // streamed tiles nt = 27+wv+8i (6 per wave), half-tile-ahead prefetch
#pragma unroll 1
    for (int i = 0; i < 6; i++) {
      int nt = 27 + wv + 8 * i;
#pragma unroll
      for (int kt = 0; kt < 5; kt++)
        bB[kt] = WB[(size_t)(nt * 10 + 5 + kt) * 64 + lane];
      f32x4v a0 = {0.f, 0.f, 0.f, 0.f};
#pragma unroll
      for (int kt = 0; kt < 5; kt++) {
        U4H8 bb; bb.u = bA[kt];
        a0 = __builtin_amdgcn_mfma_f32_16x16x32_f16(af[kt].h, bb.h, a0, 0, 0, 0);
      }
      if (i + 1 < 6) {
#pragma unroll
        for (int kt = 0; kt < 5; kt++)
          bA[kt] = WB[(size_t)((nt + 8) * 10 + kt) * 64 + lane];
      }
      f32x4v a1 = {0.f, 0.f, 0.f, 0.f};
#pragma unroll
      for (int kt = 0; kt < 5; kt++) {
        U4H8 bb; bb.u = bB[kt];
        a1 = __builtin_amdgcn_mfma_f32_16x16x32_f16(af[5 + kt].h, bb.h, a1, 0, 0, 0);
      }
      if (lg < 2) {
        int col = nt * 16 + lm;
#pragma unroll
        for (int r = 0; r < 4; r++)
          gsh[(lg * 4 + r) * 1204 + col] = a0[r] + a1[r];
      }
    }

    // LDS-resident tiles: nt = 16+wv (all waves) and 24+wv (waves 0-2)
#pragma unroll 1
    for (int li = 0; li < 2; li++) {
      int idxL = li == 0 ? wv : (8 + wv);
      if (li == 1 && wv >= 3) break;
      const uint4* bt = &bls[idxL * 640];
      f32x4v a0 = {0.f, 0.f, 0.f, 0.f};
      f32x4v a1 = {0.f, 0.f, 0.f, 0.f};
#pragma unroll
      for (int kt = 0; kt < 5; kt++) {
        U4H8 bb; bb.u = bt[kt * 64 + lane];
        a0 = __builtin_amdgcn_mfma_f32_16x16x32_f16(af[kt].h, bb.h, a0, 0, 0, 0);
      }
#pragma unroll
      for (int kt = 5; kt < 10; kt++) {
        U4H8 bb; bb.u = bt[kt * 64 + lane];
        a1 = __builtin_amdgcn_mfma_f32_16x16x32_f16(af[kt].h, bb.h, a1, 0, 0, 0);
      }
      if (lg < 2) {
        int col = (16 + idxL) * 16 + lm;
#pragma unroll
        for (int r = 0; r < 4; r++)
          gsh[(lg * 4 + r) * 1204 + col] = a0[r] + a1[r];
      }
    }
    __syncthreads();

    // elementwise: gates contiguous in gsh & gx (col' = 4u+gate)
#pragma unroll
    for (int q = 0; q < 5; q++) {
      if (act[q]) {
        const float4 gs = *(const float4*)&gsh[gsho[q]];
        float gi = gxv[q].x + gs.x;
        float gf = gxv[q].y + gs.y;
        float gg = gxv[q].z + gs.z;
        float go = gxv[q].w + gs.w;
        float si = fsig(gi);
        float sf = fsig(gf);
        float so = fsig(go);
        float cc = sf * crs[q] + si * ftanh(gg);
        float h = so * ftanh(cc);
        crs[q] = cc;
        hA8[hAo[q]] = (_Float16)h;
        if (hist) hist[(size_t)tg * NB * 300 + ho[q]] = h;
        if (hfin && t == 63) hfin[(size_t)dirb * NB * 300 + ho[q]] = h;
      }
    }
    __syncthreads();
  }
}

// ---------------------------------------------------------------------------
__global__ void embed_kernel(
    const int* __restrict__ prem, const int* __restrict__ hyp,
    const float* __restrict__ embW, float* __restrict__ comb)
{
  size_t i = (size_t)blockIdx.x * 256 + threadIdx.x;
  if (i >= (size_t)64 * 256 * 75) return;
  int d4 = (int)(i % 75);
  size_t r = i / 75;
  int n = (int)(r % 256);
  int t = (int)(r / 256);
  int id = (n < 128) ? prem[t * 128 + n] : hyp[t * 128 + (n - 128)];
  float4 v = *(const float4*)(embW + (size_t)id * 300 + d4 * 4);
  *(float4*)(comb + ((size_t)t * 256 + n) * 300 + d4 * 4) = v;
}

// ---------------------------------------------------------------------------
// norm4 v3 (round-13 WIN) + round-14 register prefetch: the serial 64-t loop
// staged each h-row with latency exposed (load->barrier->compute at 5 waves);
// now each thread prefetches its t+1 element during t's compute.
// ---------------------------------------------------------------------------
__global__ __launch_bounds__(320) void norm4_kernel(
    const float* __restrict__ hs_fw, const float* __restrict__ hs_bw,
    const float* __restrict__ mp_W,
    float* __restrict__ nm4, float* __restrict__ pnorm)
{
  const int n = blockIdx.x, dir = blockIdx.y;
  const float* HS = dir ? hs_bw : hs_fw;
  const int tid = threadIdx.x, g = tid >> 4, lane = tid & 15;
  __shared__ float sh[300];

  // per-thread W^2 registers: w2r[wset][c], k_local = lane + 16c (<300)
  float w2r[4][19];
#pragma unroll
  for (int wset = 0; wset < 4; wset++) {
    const float* W = mp_W + dir * 24000 + wset * 6000 + g * 300;
#pragma unroll
    for (int c = 0; c < 19; c++) {
      int k = lane + 16 * c;
      float w = (k < 300) ? W[k] : 0.f;
      w2r[wset][c] = w * w;
    }
  }

  // prologue prefetch: t=0 h-row element
  float xv = 0.f;
  if (tid < 300) xv = HS[((size_t)0 * 256 + n) * 300 + tid];

  for (int t = 0; t < 64; t++) {
    __syncthreads();   // prior t's readers done with sh
    if (tid < 300) sh[tid] = xv;
    __syncthreads();
    // prefetch next t's element (latency hides under compute below)
    if (t + 1 < 64 && tid < 300)
      xv = HS[((size_t)(t + 1) * 256 + n) * 300 + tid];

    float x2[19];
#pragma unroll
    for (int c = 0; c < 19; c++) {
      int k = lane + 16 * c;
      float x = (k < 300) ? sh[k] : 0.f;
      x2[c] = x * x;
    }
    if (g == 0) {
      float s2 = 0.f;
#pragma unroll
      for (int c = 0; c < 19; c++) s2 += x2[c];
      for (int o = 8; o; o >>= 1) s2 += __shfl_down(s2, o, 16);
      if (lane == 0) pnorm[((size_t)dir * 64 + t) * 256 + n] = sqrtf(s2);
    }
#pragma unroll
    for (int wset = 0; wset < 4; wset++) {
      float s1 = 0.f;
#pragma unroll
      for (int c = 0; c < 19; c++) s1 += x2[c] * w2r[wset][c];
      for (int o = 8; o; o >>= 1) s1 += __shfl_down(s1, o, 16);
      if (lane == 0)
        nm4[((((size_t)dir * 4 + wset) * 64 + t) * 256 + n) * 20 + g] = sqrtf(s1);
    }
  }
}

// ---------------------------------------------------------------------------
// att: per (b,z), att[64,64] cosine GEMM -> normalized w (watt) + argmax idx.
// ---------------------------------------------------------------------------
__global__ __launch_bounds__(256) void att_kernel(
    const float* __restrict__ hs_fw, const float* __restrict__ hs_bw,
    const float* __restrict__ pnorm,
    float* __restrict__ watt, int* __restrict__ idxbuf)
{
  const int b = blockIdx.x, z = blockIdx.y;
  const int dir = z & 1;
  const float* HS = dir ? hs_bw : hs_fw;
  const int p_n = (z < 2) ? b : 128 + b;
  const int h_n = (z < 2) ? 128 + b : b;
  const float* pnD = pnorm + (size_t)dir * 16384;

  __shared__ float pch[64 * 100];
  __shared__ float hch[64 * 100];
  __shared__ float att[64 * 65];
  __shared__ float winv_sh[64];

  const int tid = threadIdx.x;
  const int i = tid >> 4, j = tid & 15;
  float acc[4][4];
#pragma unroll
  for (int a = 0; a < 4; a++)
#pragma unroll
    for (int c = 0; c < 4; c++) acc[a][c] = 0.f;

  for (int kc = 0; kc < 300; kc += 100) {
    for (int e = tid; e < 1600; e += 256) {
      int row = e / 25, kq = e - row * 25;
      float4 v = *(const float4*)(HS + ((size_t)row * 256 + p_n) * 300 + kc + kq * 4);
      *(float4*)&pch[row * 100 + kq * 4] = v;
      float4 w = *(const float4*)(HS + ((size_t)row * 256 + h_n) * 300 + kc + kq * 4);
      *(float4*)&hch[row * 100 + kq * 4] = w;
    }
    __syncthreads();
#pragma unroll 5
    for (int kq = 0; kq < 25; kq++) {
      float4 av[4], bv[4];
#pragma unroll
      for (int a = 0; a < 4; a++) av[a] = *(const float4*)&pch[(i + 16 * a) * 100 + kq * 4];
#pragma unroll
      for (int c = 0; c < 4; c++) bv[c] = *(const float4*)&hch[(j + 16 * c) * 100 + kq * 4];
#pragma unroll
      for (int a = 0; a < 4; a++)
#pragma unroll
        for (int c = 0; c < 4; c++)
          acc[a][c] += av[a].x * bv[c].x + av[a].y * bv[c].y + av[a].z * bv[c].z + av[a].w * bv[c].w;
    }
    __syncthreads();
  }

#pragma unroll
  for (int a = 0; a < 4; a++) {
    int t = i + 16 * a;
    float pn = pnD[t * 256 + p_n] + EPSF;
#pragma unroll
    for (int c = 0; c < 4; c++) {
      int s = j + 16 * c;
      float hn = pnD[s * 256 + h_n] + EPSF;
      att[t * 65 + s] = acc[a][c] / (pn * hn);
    }
  }
  __syncthreads();
  if (tid < 64) {
    int t = tid;
    float ssum = 0.f, mx = -1e30f; int mi = 0;
    for (int s = 0; s < 64; s++) {
      float a = att[t * 65 + s];
      ssum += a;
      if (a > mx) { mx = a; mi = s; }
    }
    winv_sh[t] = 1.f / (ssum + EPSF);
    idxbuf[((size_t)z * 128 + b) * 64 + t] = mi;
  }
  __syncthreads();
  for (int e = tid; e < 4096; e += 256) {
    int t = e >> 6, s = e & 63;
    watt[((size_t)z * 128 + b) * 4096 + t * 64 + s] = att[t * 65 + s] * winv_sh[t];
  }
}

// ---------------------------------------------------------------------------
// hmean: per (b,z): hmean[t,k] = sum_s w[t,s]*h[s,k]
// ---------------------------------------------------------------------------
__global__ __launch_bounds__(256) void hmean_kernel(
    const float* __restrict__ hs_fw, const float* __restrict__ hs_bw,
    const float* __restrict__ watt, float* __restrict__ hmeanbuf)
{
  const int b = blockIdx.x, z = blockIdx.y;
  const int dir = z & 1;
  const float* HS = dir ? hs_bw : hs_fw;
  const int h_n = (z < 2) ? 128 + b : b;

  __shared__ float wsh[64 * 65];
  __shared__ float hch[64 * 128];

  const int tid = threadIdx.x;
  const int ti = tid >> 4, kj = tid & 15;
  const float* wsrc = watt + ((size_t)z * 128 + b) * 4096;
  for (int e = tid; e < 4096; e += 256) {
    int t = e >> 6, s = e & 63;
    wsh[t * 65 + s] = wsrc[t * 64 + s];
  }

  for (int kbase = 0; kbase < 300; kbase += 128) {
    int kw = min(128, 300 - kbase);
    int nf4 = kw >> 2;  // 32,32,11
    __syncthreads();
    for (int e = tid; e < 64 * nf4; e += 256) {
      int row = e / nf4, q = e - row * nf4;
      float4 v = *(const float4*)(HS + ((size_t)row * 256 + h_n) * 300 + kbase + q * 4);
      *(float4*)&hch[row * 128 + q * 4] = v;
    }
    __syncthreads();
    float acc[4][8];
#pragma unroll
    for (int a = 0; a < 4; a++)
#pragma unroll
      for (int c = 0; c < 8; c++) acc[a][c] = 0.f;
    for (int s = 0; s < 64; s++) {
      float4 h0 = *(const float4*)&hch[s * 128 + 4 * kj];
      float4 h1 = *(const float4*)&hch[s * 128 + 4 * (kj + 16)];
#pragma unroll
      for (int a = 0; a < 4; a++) {
        float w = wsh[(4 * ti + a) * 65 + s];
        acc[a][0] += w * h0.x; acc[a][1] += w * h0.y; acc[a][2] += w * h0.z; acc[a][3] += w * h0.w;
        acc[a][4] += w * h1.x; acc[a][5] += w * h1.y; acc[a][6] += w * h1.z; acc[a][7] += w * h1.w;
      }
    }
#pragma unroll
    for (int a = 0; a < 4; a++) {
      int t = 4 * ti + a;
#pragma unroll
      for (int c = 0; c < 2; c++) {
        int kq = kj + 16 * c;
        if (kq * 4 < kw) {
          int k = kbase + kq * 4;
          float4 v = make_float4(acc[a][4 * c], acc[a][4 * c + 1], acc[a][4 * c + 2], acc[a][4 * c + 3]);
          *(float4*)&hmeanbuf[(((size_t)z * 128 + b) * 64 + t) * 300 + k] = v;
        }
      }
    }
  }
}

// ---------------------------------------------------------------------------
// maxp via MFMA f16 (round-5 WIN): per (b,z) ONE block; x = l*64+t tiling;
// A-frag = p-frag (*) w2[l]-frag; h-frags reg-cached per st-pair.
// ---------------------------------------------------------------------------
#define MAXP_LDS_BYTES (41984 + 41984 + 13120 + 5120 + 5120)  // 107,328

__global__ __launch_bounds__(512, 2) void maxp_mfma(
    const float* __restrict__ hs_fw, const float* __restrict__ hs_bw,
    const float* __restrict__ mp_W, const float* __restrict__ nm4,
    float* __restrict__ m_out)
{
  extern __shared__ char smem[];
  _Float16* pA = (_Float16*)smem;                     // [64][328]
  _Float16* hB = (_Float16*)(smem + 41984);           // [64][328]
  _Float16* w2h = (_Float16*)(smem + 83968);          // [20][328]
  float* pn_sh = (float*)(smem + 97088);              // [64][20]
  float* hn_sh = (float*)(smem + 102208);             // [64][20]

  const int b = blockIdx.x, z = blockIdx.y;
  const int dir = z & 1;
  const float* HS = dir ? hs_bw : hs_fw;
  const int p_n = (z < 2) ? b : 128 + b;
  const int h_n = (z < 2) ? 128 + b : b;
  const float* Wm = mp_W + dir * 24000 + 6000;
  const float* nmD = nm4 + ((size_t)dir * 4 + 1) * 327680;

  const int tid = threadIdx.x;
  const int wv = tid >> 6, lane = tid & 63;
  const int lm = lane & 15, lg = lane >> 4;

  // ---- stage p, h (f32->f16), w2 (squared f16), pn, hn ----
  for (int e = tid; e < 4800; e += 512) {
    int row = e / 75, q = e - row * 75;
    float4 v = *(const float4*)(HS + ((size_t)row * 256 + p_n) * 300 + q * 4);
    float4 w = *(const float4*)(HS + ((size_t)row * 256 + h_n) * 300 + q * 4);
    _Float16* pd = &pA[row * 328 + q * 4];
    pd[0] = (_Float16)v.x; pd[1] = (_Float16)v.y; pd[2] = (_Float16)v.z; pd[3] = (_Float16)v.w;
    _Float16* hd = &hB[row * 328 + q * 4];
    hd[0] = (_Float16)w.x; hd[1] = (_Float16)w.y; hd[2] = (_Float16)w.z; hd[3] = (_Float16)w.w;
  }
  for (int e = tid; e < 64 * 28; e += 512) {
    int row = e / 28, c = 300 + (e - row * 28);
    pA[row * 328 + c] = (_Float16)0.f;
    hB[row * 328 + c] = (_Float16)0.f;
  }
  for (int e = tid; e < 1500; e += 512) {
    int row = e / 75, q = e - row * 75;
    float4 w = *(const float4*)(Wm + (size_t)row * 300 + q * 4);
    _Float16* d = &w2h[row * 328 + q * 4];
    d[0] = (_Float16)(w.x * w.x); d[1] = (_Float16)(w.y * w.y);
    d[2] = (_Float16)(w.z * w.z); d[3] = (_Float16)(w.w * w.w);
  }
  for (int e = tid; e < 20 * 28; e += 512) {
    int row = e / 28, c = 300 + (e - row * 28);
    w2h[row * 328 + c] = (_Float16)0.f;
  }
  for (int e = tid; e < 1280; e += 512) {
    int tq = e / 20, l = e - tq * 20;
    pn_sh[e] = nmD[((size_t)tq * 256 + p_n) * 20 + l];
    hn_sh[e] = nmD[((size_t)tq * 256 + h_n) * 20 + l];
  }
  __syncthreads();

  // ---- compute: wave wv owns x-tiles xt = wv + 8i (10 tiles) ----
  float rmax[10][4];
#pragma unroll
  for (int i = 0; i < 10; i++)
#pragma unroll
    for (int r = 0; r < 4; r++) rmax[i][r] = -1e30f;

#pragma unroll
  for (int sp = 0; sp < 2; sp++) {       // st pairs {0,1},{2,3}
    U4H8 hf[2][10];
#pragma unroll
    for (int hh = 0; hh < 2; hh++)
#pragma unroll
      for (int kt = 0; kt < 10; kt++)
        hf[hh][kt].u = *(const uint4*)&hB[(sp * 32 + hh * 16 + lm) * 328 + kt * 32 + lg * 8];

#pragma unroll
    for (int i = 0; i < 10; i++) {
      int xt = wv + 8 * i;               // 0..79
      int l = xt >> 2, t0 = (xt & 3) << 4;
      U4H8 af[10];
#pragma unroll
      for (int kt = 0; kt < 10; kt++) {
        U4H8 pf, wf;
        pf.u = *(const uint4*)&pA[(t0 + lm) * 328 + kt * 32 + lg * 8];
        wf.u = *(const uint4*)&w2h[l * 328 + kt * 32 + lg * 8];
        af[kt].h = pf.h * wf.h;          // v_pk_mul_f16
      }
      float pnv[4];
#pragma unroll
      for (int r = 0; r < 4; r++) pnv[r] = pn_sh[(t0 + lg * 4 + r) * 20 + l];
#pragma unroll
      for (int hh = 0; hh < 2; hh++) {
        int st = sp * 2 + hh;
        f32x4v acc = {0.f, 0.f, 0.f, 0.f};
#pragma unroll
        for (int kt = 0; kt < 10; kt++)
          acc = __builtin_amdgcn_mfma_f32_16x16x32_f16(af[kt].h, hf[hh][kt].h, acc, 0, 0, 0);
        float hn = hn_sh[(st * 16 + lm) * 20 + l];
#pragma unroll
        for (int r = 0; r < 4; r++) {
          float val = acc[r] * __builtin_amdgcn_rcpf(pnv[r] * hn + EPSF);
          rmax[i][r] = fmaxf(rmax[i][r], val);
        }
      }
    }
  }

  // ---- cross-lane max over s (16-lane groups) + write ----
#pragma unroll
  for (int i = 0; i < 10; i++) {
    int xt = wv + 8 * i;
    int l = xt >> 2, t0 = (xt & 3) << 4;
#pragma unroll
    for (int r = 0; r < 4; r++) {
      float v = rmax[i][r];
#pragma unroll
      for (int off = 8; off; off >>= 1) v = fmaxf(v, __shfl_down(v, off, 16));
      if (lm == 0) {
        int t = t0 + lg * 4 + r;
        m_out[((size_t)t * 128 + b) * 320 + z * 80 + 20 + l] = v;
      }
    }
  }
}

// ---------------------------------------------------------------------------
// rest: per (b,z): full / attm / maxattm for all t. W^2 staged once in LDS.
// Round-14: register-prefetch pipeline for the per-t row staging — the
// serial 64-t loop at 5 waves had the global-load latency fully exposed
// (load->barrier->compute). Now each thread (tid<300) prefetches its t+1
// elements (p-row, hmean-row, hmax-row) during t's compute; idxbuf staged
// to LDS once so t+1's hmax row address is available early. Math unchanged.
// ---------------------------------------------------------------------------
__global__ __launch_bounds__(320) void rest_kernel(
    const float* __restrict__ hs_fw, const float* __restrict__ hs_bw,
    const float* __restrict__ mp_W, const float* __restrict__ nm4,
    const float* __restrict__ hmeanbuf, const int* __restrict__ idxbuf,
    float* __restrict__ m_out)
{
  const int b = blockIdx.x, z = blockIdx.y;
  const int dir = z & 1;
  const float* HS = dir ? hs_bw : hs_fw;
  const int p_n = (z < 2) ? b : 128 + b;
  const int h_n = (z < 2) ? 128 + b : b;
  const int v_t = dir ? 0 : 63;

  __shared__ float w2f[6000], w2a[6000], w2m[6000];
  __shared__ float vsh[300], psh[300], hmsh[300], hxsh[300];
  __shared__ int idxs[64];

  const int tid = threadIdx.x;
  const int g = tid >> 4, lane = tid & 15;
  const float* Wf = mp_W + dir * 24000;
  const float* Wa = Wf + 12000;
  const float* Wma = Wf + 18000;
  for (int e = tid; e < 6000; e += 320) {
    float a = Wf[e], bb = Wa[e], c = Wma[e];
    w2f[e] = a * a; w2a[e] = bb * bb; w2m[e] = c * c;
  }
  for (int e = tid; e < 300; e += 320)
    vsh[e] = HS[((size_t)v_t * 256 + h_n) * 300 + e];
  for (int e = tid; e < 64; e += 320)
    idxs[e] = idxbuf[((size_t)z * 128 + b) * 64 + e];
  __syncthreads();

  const float* base0 = nm4 + ((size_t)dir * 4 + 0) * 327680;
  const float* base2 = nm4 + ((size_t)dir * 4 + 2) * 327680;
  const float* base3 = nm4 + ((size_t)dir * 4 + 3) * 327680;
  const float vnf = base0[((size_t)v_t * 256 + h_n) * 20 + g];

  // prologue prefetch: t=0 rows (one element per thread, tid<300)
  float pp = 0.f, hh = 0.f, xx = 0.f;
  if (tid < 300) {
    pp = HS[((size_t)0 * 256 + p_n) * 300 + tid];
    hh = hmeanbuf[(((size_t)z * 128 + b) * 64 + 0) * 300 + tid];
    xx = HS[((size_t)idxs[0] * 256 + h_n) * 300 + tid];
  }

  for (int t = 0; t < 64; t++) {
    const int idx = idxs[t];
    __syncthreads();                 // prior t's readers done with psh etc.
    if (tid < 300) {
      psh[tid] = pp;
      hmsh[tid] = hh;
      hxsh[tid] = xx;
    }
    __syncthreads();
    // prefetch t+1 rows (latency hides under the compute below)
    if (t + 1 < 64 && tid < 300) {
      pp = HS[((size_t)(t + 1) * 256 + p_n) * 300 + tid];
      hh = hmeanbuf[(((size_t)z * 128 + b) * 64 + t + 1) * 300 + tid];
      xx = HS[((size_t)idxs[t + 1] * 256 + h_n) * 300 + tid];
    }

    float nf = 0.f, na = 0.f, qa = 0.f, nm = 0.f;
#pragma unroll
    for (int c = 0; c < 5; c++) {
      int k4 = lane + 16 * c;
      if (k4 < 75) {
        float4 p = *(const float4*)&psh[4 * k4];
        float4 v = *(const float4*)&vsh[4 * k4];
        float4 hm = *(const float4*)&hmsh[4 * k4];
        float4 hx = *(const float4*)&hxsh[4 * k4];
        float4 wf = *(const float4*)&w2f[g * 300 + 4 * k4];
        float4 wa = *(const float4*)&w2a[g * 300 + 4 * k4];
        float4 wm = *(const float4*)&w2m[g * 300 + 4 * k4];
        nf += p.x * v.x * wf.x + p.y * v.y * wf.y + p.z * v.z * wf.z + p.w * v.w * wf.w;
        na += p.x * hm.x * wa.x + p.y * hm.y * wa.y + p.z * hm.z * wa.z + p.w * hm.w * wa.w;
        qa += hm.x * hm.x * wa.x + hm.y * hm.y * wa.y + hm.z * hm.z * wa.z + hm.w * hm.w * wa.w;
        nm += p.x * hx.x * wm.x + p.y * hx.y * wm.y + p.z * hx.z * wm.z + p.w * hx.w * wm.w;
      }
    }
#pragma unroll
    for (int o = 8; o; o >>= 1) {
      nf += __shfl_down(nf, o);
      na += __shfl_down(na, o);
      qa += __shfl_down(qa, o);
      nm += __shfl_down(nm, o);
    }
    if (lane == 0) {
      float pnf = base0[((size_t)t * 256 + p_n) * 20 + g];
      float pna = base2[((size_t)t * 256 + p_n) * 20 + g];
      float pnm = base3[((size_t)t * 256 + p_n) * 20 + g];
      float qnm = base3[((size_t)idx * 256 + h_n) * 20 + g];
      float* mrow = m_out + ((size_t)t * 128 + b) * 320 + z * 80;
      mrow[g] = nf / (pnf * vnf + EPSF);
      mrow[40 + g] = na / (pna * sqrtf(qa) + EPSF);
      mrow[60 + g] = nm / (pnm * qnm + EPSF);
    }
  }
}

// ---------------------------------------------------------------------------
__global__ __launch_bounds__(256) void mlp_kernel(
    const float* __restrict__ shA0, const float* __restrict__ shA1,
    const float* __restrict__ bnG, const float* __restrict__ bnB,
    const float* __restrict__ W1, const float* __restrict__ b1,
    const float* __restrict__ W2, const float* __restrict__ b2,
    const float* __restrict__ outW, const float* __restrict__ outb,
    float* __restrict__ out)
{
  const int b = blockIdx.x;
  const int tid = threadIdx.x;
  __shared__ float x0[600], x1[600];
  const float inv = 1.0f / sqrtf(1.0f + 1e-5f);
  for (int j = tid; j < 600; j += 256) {
    float v = (j < 300) ? shA0[b * 300 + j] : shA1[b * 300 + (j - 300)];
    x0[j] = bnG[j] * v * inv + bnB[j];
  }
  __syncthreads();
  for (int j = tid; j < 600; j += 256) {
    float acc = b1[j];
    const float* w = W1 + (size_t)j * 600;
    for (int k = 0; k < 600; k++) acc += x0[k] * w[k];
    float r = fmaxf(acc, 0.f);
    x1[j] = bnG[600 + j] * r * inv + bnB[600 + j];
  }
  __syncthreads();
  for (int j = tid; j < 600; j += 256) {
    float acc = b2[j];
    const float* w = W2 + (size_t)j * 600;
    for (int k = 0; k < 600; k++) acc += x1[k] * w[k];
    float r = fmaxf(acc, 0.f);
    x0[j] = bnG[1200 + j] * r * inv + bnB[1200 + j];
  }
  __syncthreads();
  if (tid < 3) {
    float acc = outb[tid];
    const float* w = outW + tid * 600;
    for (int k = 0; k < 600; k++) acc += x0[k] * w[k];
    out[b * 3 + tid] = acc;
  }
}

// ---------------------------------------------------------------------------
extern "C" void kernel_launch(void* const* d_in, const int* in_sizes, int n_in,
                              void* d_out, int out_size, void* d_ws, size_t ws_size,
                              hipStream_t stream) {
  const int* premise = (const int*)d_in[0];
  const int* hypothesis = (const int*)d_in[1];
  const float* embW = (const float*)d_in[2];
  const float* cWih = (const float*)d_in[3];
  const float* cWhh = (const float*)d_in[4];
  const float* cb = (const float*)d_in[5];
  const float* mpW = (const float*)d_in[6];
  const float* aWihF = (const float*)d_in[7];
  const float* aWhhF = (const float*)d_in[8];
  const float* abF = (const float*)d_in[9];
  const float* aWihB = (const float*)d_in[10];
  const float* aWhhB = (const float*)d_in[11];
  const float* abB = (const float*)d_in[12];
  const float* bnG = (const float*)d_in[13];
  const float* bnB = (const float*)d_in[14];
  const float* W1 = (const float*)d_in[15];
  const float* b1 = (const float*)d_in[16];
  const float* W2 = (const float*)d_in[17];
  const float* b2 = (const float*)d_in[18];
  const float* outW = (const float*)d_in[19];
  const float* outb = (const float*)d_in[20];
  float* out = (float*)d_out;

  float* ws = (float*)d_ws;
  // workspace layout (floats)
  float* comb  = ws + 0;           // 4,915,200  (T,256,300); WB packs + aWih perms overlay after ctx-gates GEMM
  float* gates = ws + 4915200;     // 19,660,800 (T,256,1200); overlaid after ctx LSTM
  float* hsfw  = ws + 24576000;    // 4,915,200  (cWih perm overlays here pre-LSTM)
  float* hsbw  = ws + 29491200;    // 4,915,200
  float* pnorm = ws + 34406400;    // 32,768    [2][64][256]
  float* mbuf  = ws + 35094528;    // 2,621,440 (T,128,320)
  float* sha   = ws + 38023168;    // 76,800    agg final h [2][128][300]

  // packed MFMA B-fragment weights overlay in comb region (dead after ctx-gates GEMM)
  uint4* WBctx = (uint4*)comb;
  uint4* WBaf  = (uint4*)(comb + 192000);
  uint4* WBab  = (uint4*)(comb + 384000);
  // gate-interleaved agg input weights (dead comb region, after WB packs)
  float* aWihFP = comb + 576000;   // 384,000
  float* aWihBP = comb + 960000;   // 384,000
  float* abFP   = comb + 1344000;  // 1,200
  float* abBP   = comb + 1345200;  // 1,200

  // gate-interleaved ctx input weights: hsfw region is dead until ctx LSTM
  float* cWihP = hsfw;             // 360,000
  float* cbP   = hsfw + 360000;    // 1,200

  // overlays inside the dead ctx-gates region (valid between ctx LSTM and agg GEMMs)
  float* watt     = gates;                 // 2,097,152 [4][128][64][64]
  float* hmeanbuf = gates + 2097152;       // 9,830,400 [4][128][64][300]
  int*   idxbuf   = (int*)(gates + 11927552); // 32,768 [4][128][64]
  float* nm4      = gates + 11960320;      // 2,621,440 [2][4][64][256][20]

  // allow >64KB dynamic LDS (gfx950 pool = 160KB/WG)
  hipFuncSetAttribute((const void*)lstm_res,
                      hipFuncAttributeMaxDynamicSharedMemorySize, LSTM_LDS_BYTES);
  hipFuncSetAttribute((const void*)maxp_mfma,
                      hipFuncAttributeMaxDynamicSharedMemorySize, MAXP_LDS_BYTES);
  hipFuncSetAttribute((const void*)gemm_mfma_nt,
                      hipFuncAttributeMaxDynamicSharedMemorySize, GMM_LDS_BYTES);

  // 1) embed + ctx input-weight gate-interleave
  embed_kernel<<<dim3(4800), dim3(256), 0, stream>>>(premise, hypothesis, embW, comb);
  permW_kernel<<<dim3(1200), dim3(256), 0, stream>>>(cWih, cb, cWihP, cbP, 300);

  // 2) ctx input gates (consumes comb) — split-f16 MFMA, fp32-grade accuracy
  gemm_mfma_nt<<<dim3(5, 128, 1), dim3(512), GMM_LDS_BYTES, stream>>>(
      comb, cWihP, cbP, gates, nullptr, nullptr, nullptr, 16384, 300);

  // 3) pack recurrent weights into MFMA B-fragment stream (dead comb region)
  //    + gate-interleave the agg input weights
  packB_kernel<<<dim3(188, 3), dim3(256), 0, stream>>>(
      cWhh, aWhhF, aWhhB, WBctx, WBaf, WBab);
  permW_kernel<<<dim3(1200), dim3(256), 0, stream>>>(aWihF, abF, aWihFP, abFP, 320);
  permW_kernel<<<dim3(1200), dim3(256), 0, stream>>>(aWihB, abB, aWihBP, abBP, 320);

  // 4) context LSTM: 16 reg + 11 LDS tiles resident, 48 streamed (r6 config)
  lstm_res<<<dim3(64), dim3(512), LSTM_LDS_BYTES, stream>>>(
      WBctx, WBctx, gates, gates, hsfw, hsbw, nullptr, 256);

  // 5) norms — v3 + register prefetch pipeline
  norm4_kernel<<<dim3(256, 2), dim3(320), 0, stream>>>(hsfw, hsbw, mpW, nm4, pnorm);

  // 6) matching pipeline
  att_kernel<<<dim3(128, 4), dim3(256), 0, stream>>>(hsfw, hsbw, pnorm, watt, idxbuf);
  hmean_kernel<<<dim3(128, 4), dim3(256), 0, stream>>>(hsfw, hsbw, watt, hmeanbuf);
  maxp_mfma<<<dim3(128, 4), dim3(512), MAXP_LDS_BYTES, stream>>>(
      hsfw, hsbw, mpW, nm4, mbuf);
  rest_kernel<<<dim3(128, 4), dim3(320), 0, stream>>>(hsfw, hsbw, mpW, nm4, hmeanbuf, idxbuf, mbuf);

  // 7) agg input gates — split-f16 MFMA, BOTH directions in ONE launch (z)
  float* gaf = gates;
  float* gab = gates + 9830400;
  gemm_mfma_nt<<<dim3(5, 64, 2), dim3(512), GMM_LDS_BYTES, stream>>>(
      mbuf, aWihFP, abFP, gaf, aWihBP, abBP, gab, 8192, 320);

  // 8) aggregation LSTM: 32 blocks (16/dir), 8 waves
  lstm_res<<<dim3(32), dim3(512), LSTM_LDS_BYTES, stream>>>(
      WBaf, WBab, gaf, gab, nullptr, nullptr, sha, 128);

  // 9) MLP head
  mlp_kernel<<<dim3(128), dim3(256), 0, stream>>>(
      sha, sha + 38400, bnG, bnB, W1, b1, W2, b2, outW, outb, out);
}